// Round 1
// baseline (3738.126 us; speedup 1.0000x reference)
//
#include <hip/hip_runtime.h>
#include <math.h>

#define NN 20000
#define NE 200000
#define NT 40000

// ---------------- utility kernels ----------------
__global__ void k_fill_f32(float* __restrict__ p, float v, int n) {
  int i = blockIdx.x * 256 + threadIdx.x;
  if (i < n) p[i] = v;
}

__global__ void k_edge_mlp(const float* __restrict__ ea,
                           const float* __restrict__ w1, const float* __restrict__ b1,
                           const float* __restrict__ w2, const float* __restrict__ b2,
                           const float* __restrict__ w3, const float* __restrict__ b3,
                           float* __restrict__ out) {
  int e = blockIdx.x * 256 + threadIdx.x;
  if (e >= NE) return;
  float a[7];
#pragma unroll
  for (int i = 0; i < 7; i++) a[i] = ea[e * 7 + i];
  float t1[28];
#pragma unroll
  for (int j = 0; j < 28; j++) {
    float s = b1[j];
#pragma unroll
    for (int k = 0; k < 7; k++) s = fmaf(a[k], w1[k * 28 + j], s);
    t1[j] = fmaxf(s, 0.f);
  }
  float t2[28];
  for (int j = 0; j < 28; j++) {
    float s = b2[j];
    for (int k = 0; k < 28; k++) s = fmaf(t1[k], w2[k * 28 + j], s);
    t2[j] = fmaxf(s, 0.f);
  }
  float s = b3[0];
  for (int k = 0; k < 28; k++) s = fmaf(t2[k], w3[k], s);
  out[e] = 1.f / (1.f + expf(-s));
}

// deg[i][c] += w_i(e); deg buffer pre-filled with 1.0 (self-loop weight)
__global__ void k_deg_accum(const float* __restrict__ ea, const float* __restrict__ ew,
                            const int* __restrict__ col, float* __restrict__ deg) {
  int e = blockIdx.x * 256 + threadIdx.x;
  if (e >= NE) return;
  int c = col[e];
#pragma unroll
  for (int i = 0; i < 7; i++) atomicAdd(&deg[i * NN + c], ea[e * 7 + i]);
  atomicAdd(&deg[7 * NN + c], ew[e]);
}

__global__ void k_rsqrt(float* __restrict__ p, int n) {
  int i = blockIdx.x * 256 + threadIdx.x;
  if (i < n) { float d = p[i]; p[i] = d > 0.f ? rsqrtf(d) : 0.f; }
}

__global__ void k_count(const int* __restrict__ col, int* __restrict__ cnt) {
  int e = blockIdx.x * 256 + threadIdx.x;
  if (e < NE) atomicAdd(&cnt[col[e]], 1);
}

__global__ void k_scan(const int* __restrict__ cnt, int* __restrict__ rowptr) {
  __shared__ int sums[256];
  __shared__ int offs[256];
  int t = threadIdx.x;
  const int CH = (NN + 255) / 256;
  int base = t * CH;
  int s = 0;
  for (int i = 0; i < CH; i++) { int idx = base + i; if (idx < NN) s += cnt[idx]; }
  sums[t] = s;
  __syncthreads();
  if (t == 0) {
    int acc = 0;
    for (int i = 0; i < 256; i++) { offs[i] = acc; acc += sums[i]; }
    rowptr[NN] = acc;
  }
  __syncthreads();
  int acc = offs[t];
  for (int i = 0; i < CH; i++) {
    int idx = base + i;
    if (idx < NN) { rowptr[idx] = acc; acc += cnt[idx]; }
  }
}

__global__ void k_copy_i32(const int* __restrict__ src, int* __restrict__ dst, int n) {
  int i = blockIdx.x * 256 + threadIdx.x;
  if (i < n) dst[i] = src[i];
}

__global__ void k_fill_csr(const int* __restrict__ col, int* __restrict__ cursor,
                           int* __restrict__ eid) {
  int e = blockIdx.x * 256 + threadIdx.x;
  if (e >= NE) return;
  int pos = atomicAdd(&cursor[col[e]], 1);
  eid[pos] = e;
}

// For CSR slot p (edge eid[p]): src node, and per-edge-type norms in CSR order
__global__ void k_csr_norms(const int* __restrict__ eid, const int* __restrict__ row,
                            const int* __restrict__ col, const float* __restrict__ ea,
                            const float* __restrict__ ew, const float* __restrict__ dis,
                            int* __restrict__ csr_src, float* __restrict__ csr_norm) {
  int p = blockIdx.x * 256 + threadIdx.x;
  if (p >= NE) return;
  int e = eid[p];
  int r = row[e], c = col[e];
  csr_src[p] = r;
#pragma unroll
  for (int i = 0; i < 7; i++)
    csr_norm[i * NE + p] = dis[i * NN + r] * ea[e * 7 + i] * dis[i * NN + c];
  csr_norm[7 * NE + p] = dis[7 * NN + r] * ew[e] * dis[7 * NN + c];
}

// ---------------- GEMM: C[M,128] = A[M,K] @ B[K,128] (+bias)(+relu) ----------------
// TM=128, TN=64, TK=16, 256 threads, 8x4 micro-tile
template <bool RELU>
__global__ __launch_bounds__(256) void k_gemm(const float* __restrict__ A,
                                              const float* __restrict__ B,
                                              const float* __restrict__ bias,
                                              float* __restrict__ C, int M, int K) {
  __shared__ float As[16][129];
  __shared__ float Bs[16][65];
  int tid = threadIdx.x;
  int tx = tid & 15;   // n dim: 16 x 4 = 64
  int ty = tid >> 4;   // m dim: 16 x 8 = 128
  int bm = blockIdx.x * 128, bn = blockIdx.y * 64;
  float acc[8][4] = {};
  for (int k0 = 0; k0 < K; k0 += 16) {
#pragma unroll
    for (int l = 0; l < 8; l++) {
      int idx = tid + l * 256;          // 0..2047
      int r = idx >> 4, c = idx & 15;   // r: m-row, c: k
      int gm = bm + r, gk = k0 + c;
      As[c][r] = (gm < M && gk < K) ? A[(size_t)gm * K + gk] : 0.f;
    }
#pragma unroll
    for (int l = 0; l < 4; l++) {
      int idx = tid + l * 256;          // 0..1023
      int rr = idx >> 6, cc = idx & 63; // rr: k, cc: n
      int gk = k0 + rr;
      Bs[rr][cc] = (gk < K) ? B[(size_t)gk * 128 + bn + cc] : 0.f;
    }
    __syncthreads();
#pragma unroll
    for (int k = 0; k < 16; k++) {
      float av[8], bv[4];
#pragma unroll
      for (int i = 0; i < 8; i++) av[i] = As[k][ty * 8 + i];
#pragma unroll
      for (int j = 0; j < 4; j++) bv[j] = Bs[k][tx * 4 + j];
#pragma unroll
      for (int i = 0; i < 8; i++)
#pragma unroll
        for (int j = 0; j < 4; j++) acc[i][j] = fmaf(av[i], bv[j], acc[i][j]);
    }
    __syncthreads();
  }
#pragma unroll
  for (int i = 0; i < 8; i++) {
    int gm = bm + ty * 8 + i;
    if (gm >= M) continue;
#pragma unroll
    for (int j = 0; j < 4; j++) {
      int gn = bn + tx * 4 + j;
      float v = acc[i][j];
      if (bias) v += bias[gn];
      if (RELU) v = fmaxf(v, 0.f);
      C[(size_t)gm * 128 + gn] = v;
    }
  }
}

// ---------------- aggregation: out[n, col_off+f] = relu(b[f] + dis^2*hW[n,f] + sum_p norm*hW[src,f]) ----
__global__ __launch_bounds__(128) void k_agg(const float* __restrict__ hW,
                                             const float* __restrict__ csr_norm_i,
                                             const float* __restrict__ dis_i,
                                             const int* __restrict__ rowptr,
                                             const int* __restrict__ csr_src,
                                             const float* __restrict__ bias,
                                             float* __restrict__ out, int out_stride,
                                             int col_off) {
  int n = blockIdx.x;
  int f = threadIdx.x;
  float d = dis_i[n];
  float acc = d * d * hW[(size_t)n * 128 + f];
  int s = rowptr[n], e2 = rowptr[n + 1];
  for (int p = s; p < e2; p++) {
    acc = fmaf(csr_norm_i[p], hW[(size_t)csr_src[p] * 128 + f], acc);
  }
  out[(size_t)n * out_stride + col_off + f] = fmaxf(acc + bias[f], 0.f);
}

// ---------------- link MLP ----------------
__global__ __launch_bounds__(128) void k_link_gather(const float* __restrict__ U,
                                                     const float* __restrict__ V,
                                                     const int* __restrict__ eit,
                                                     const float* __restrict__ lb0,
                                                     float* __restrict__ H1,
                                                     float* __restrict__ H2) {
  int t = blockIdx.x;
  int f = threadIdx.x;
  int s = eit[t], d = eit[NT + t];
  float b = lb0[f];
  H1[(size_t)t * 128 + f] = fmaxf(U[(size_t)s * 128 + f] + V[(size_t)d * 128 + f] + b, 0.f);
  H2[(size_t)t * 128 + f] = fmaxf(U[(size_t)d * 128 + f] + V[(size_t)s * 128 + f] + b, 0.f);
}

__global__ void k_link_out(const float* __restrict__ H1, const float* __restrict__ H2,
                           const float* __restrict__ lw4, const float* __restrict__ lb4,
                           float* __restrict__ out) {
  int t = blockIdx.x * 256 + threadIdx.x;
  if (t >= NT) return;
  float o1[4] = {lb4[0], lb4[1], lb4[2], lb4[3]};
  float o2[4] = {o1[0], o1[1], o1[2], o1[3]};
  for (int k = 0; k < 128; k++) {
    float h1 = H1[(size_t)t * 128 + k];
    float h2 = H2[(size_t)t * 128 + k];
#pragma unroll
    for (int j = 0; j < 4; j++) {
      float w = lw4[k * 4 + j];
      o1[j] = fmaf(h1, w, o1[j]);
      o2[j] = fmaf(h2, w, o2[j]);
    }
  }
  // t2 columns permuted by [0,2,1,3]
  out[t * 4 + 0] = 0.5f * (o1[0] + o2[0]);
  out[t * 4 + 1] = 0.5f * (o1[1] + o2[2]);
  out[t * 4 + 2] = 0.5f * (o1[2] + o2[1]);
  out[t * 4 + 3] = 0.5f * (o1[3] + o2[3]);
}

// ---------------- host ----------------
extern "C" void kernel_launch(void* const* d_in, const int* in_sizes, int n_in,
                              void* d_out, int out_size, void* d_ws, size_t ws_size,
                              hipStream_t stream) {
  const float* x   = (const float*)d_in[0];
  const int*   ei  = (const int*)d_in[1];
  const float* ea  = (const float*)d_in[2];
  const int*   eit = (const int*)d_in[3];
  const float* W0  = (const float*)d_in[4];
  const float* b0  = (const float*)d_in[5];
  const float* W1  = (const float*)d_in[6];
  const float* b1  = (const float*)d_in[7];
  const float* W2  = (const float*)d_in[8];
  const float* b2  = (const float*)d_in[9];
  const float* W3  = (const float*)d_in[10];
  const float* b3  = (const float*)d_in[11];
  const float* ew1 = (const float*)d_in[12];
  const float* eb1 = (const float*)d_in[13];
  const float* ew2 = (const float*)d_in[14];
  const float* eb2 = (const float*)d_in[15];
  const float* ew3 = (const float*)d_in[16];
  const float* eb3 = (const float*)d_in[17];
  const float* lw0 = (const float*)d_in[18];
  const float* lb0 = (const float*)d_in[19];
  const float* lwh = (const float*)d_in[20];
  const float* lbh = (const float*)d_in[21];
  const float* lw4 = (const float*)d_in[22];
  const float* lb4 = (const float*)d_in[23];
  const int* row = ei;
  const int* col = ei + NE;
  float* out = (float*)d_out;

  char* ws = (char*)d_ws;
  size_t off = 0;
  auto alloc = [&](size_t bytes) -> char* {
    char* p = ws + off;
    off += (bytes + 255) & ~(size_t)255;
    return p;
  };
  // NOTE: xB and x2 must stay adjacent — the 4 link ping-pong buffers (81.92MB)
  // overlay [xB | x2] (both dead by link phase).
  float* xA      = (float*)alloc((size_t)NN * 896 * 4);  // x1, then x3, then U|V
  float* xB      = (float*)alloc((size_t)NN * 896 * 4);  // x4, then H buffers
  float* x2buf   = (float*)alloc((size_t)NN * 128 * 4);  // x2 (tail of H overlay)
  float* hW      = (float*)alloc((size_t)NN * 128 * 4);  // per-i GEMM output
  float* csr_nrm = (float*)alloc((size_t)8 * NE * 4);    // norms in CSR order
  float* dis     = (float*)alloc((size_t)8 * NN * 4);    // deg -> rsqrt in place
  float* ewb     = (float*)alloc((size_t)NE * 4);        // learned edge weight
  int*   rowptr  = (int*)alloc((size_t)(NN + 1) * 4);
  int*   cursor  = (int*)alloc((size_t)NN * 4);          // counts, then cursors
  int*   eid     = (int*)alloc((size_t)NE * 4);
  int*   csr_src = (int*)alloc((size_t)NE * 4);
  (void)ws_size; (void)in_sizes; (void)n_in; (void)out_size;

  const int EB = (NE + 255) / 256;
  const int NB = (NN + 255) / 256;

  // 1) learned edge weight
  k_edge_mlp<<<EB, 256, 0, stream>>>(ea, ew1, eb1, ew2, eb2, ew3, eb3, ewb);
  // 2) weighted degrees (init 1.0 = self-loop) -> dis
  k_fill_f32<<<(8 * NN + 255) / 256, 256, 0, stream>>>(dis, 1.f, 8 * NN);
  k_deg_accum<<<EB, 256, 0, stream>>>(ea, ewb, col, dis);
  k_rsqrt<<<(8 * NN + 255) / 256, 256, 0, stream>>>(dis, 8 * NN);
  // 3) CSR by destination
  hipMemsetAsync(cursor, 0, (size_t)NN * 4, stream);
  k_count<<<EB, 256, 0, stream>>>(col, cursor);
  k_scan<<<1, 256, 0, stream>>>(cursor, rowptr);
  k_copy_i32<<<NB, 256, 0, stream>>>(rowptr, cursor, NN);
  k_fill_csr<<<EB, 256, 0, stream>>>(col, cursor, eid);
  k_csr_norms<<<EB, 256, 0, stream>>>(eid, row, col, ea, ewb, dis, csr_src, csr_nrm);

  dim3 gg((NN + 127) / 128, 2);
  // Layer 0: x [N,8] @ W0[i] -> agg -> x1 (xA)
  for (int i = 0; i < 7; i++) {
    k_gemm<false><<<gg, 256, 0, stream>>>(x, W0 + (size_t)i * 8 * 128, nullptr, hW, NN, 8);
    k_agg<<<NN, 128, 0, stream>>>(hW, csr_nrm + (size_t)i * NE, dis + (size_t)i * NN,
                                  rowptr, csr_src, b0 + i * 128, xA, 896, i * 128);
  }
  // Layer 1: x1 [N,896] @ W1 -> agg (ew norm, idx 7) -> x2
  k_gemm<false><<<gg, 256, 0, stream>>>(xA, W1, nullptr, hW, NN, 896);
  k_agg<<<NN, 128, 0, stream>>>(hW, csr_nrm + (size_t)7 * NE, dis + (size_t)7 * NN,
                                rowptr, csr_src, b1, x2buf, 128, 0);
  // Layer 2: x2 [N,128] @ W2[i] -> agg -> x3 (xA, x1 dead)
  for (int i = 0; i < 7; i++) {
    k_gemm<false><<<gg, 256, 0, stream>>>(x2buf, W2 + (size_t)i * 128 * 128, nullptr, hW, NN, 128);
    k_agg<<<NN, 128, 0, stream>>>(hW, csr_nrm + (size_t)i * NE, dis + (size_t)i * NN,
                                  rowptr, csr_src, b2 + i * 128, xA, 896, i * 128);
  }
  // Layer 3: x3 [N,896] @ W3[i] -> agg -> x4 (xB)
  for (int i = 0; i < 7; i++) {
    k_gemm<false><<<gg, 256, 0, stream>>>(xA, W3 + (size_t)i * 896 * 128, nullptr, hW, NN, 896);
    k_agg<<<NN, 128, 0, stream>>>(hW, csr_nrm + (size_t)i * NE, dis + (size_t)i * NN,
                                  rowptr, csr_src, b3 + i * 128, xB, 896, i * 128);
  }
  // Link: U = x4 @ lw0_top, V = x4 @ lw0_bot (into xA; x3 dead)
  float* U = xA;
  float* V = xA + (size_t)NN * 128;
  k_gemm<false><<<gg, 256, 0, stream>>>(xB, lw0, nullptr, U, NN, 896);
  k_gemm<false><<<gg, 256, 0, stream>>>(xB, lw0 + (size_t)896 * 128, nullptr, V, NN, 896);
  // H buffers overlay [xB | x2buf] (x4 and x2 dead now)
  float* H1a = xB;
  float* H1b = H1a + (size_t)NT * 128;
  float* H2a = H1b + (size_t)NT * 128;
  float* H2b = H2a + (size_t)NT * 128;
  k_link_gather<<<NT, 128, 0, stream>>>(U, V, eit, lb0, H1a, H2a);
  dim3 gl((NT + 127) / 128, 2);
  for (int i = 0; i < 3; i++) {
    const float* w  = lwh + (size_t)i * 128 * 128;
    const float* bb = lbh + (size_t)i * 128;
    k_gemm<true><<<gl, 256, 0, stream>>>(i % 2 == 0 ? H1a : H1b, w, bb,
                                         i % 2 == 0 ? H1b : H1a, NT, 128);
    k_gemm<true><<<gl, 256, 0, stream>>>(i % 2 == 0 ? H2a : H2b, w, bb,
                                         i % 2 == 0 ? H2b : H2a, NT, 128);
  }
  // after 3 ping-pongs final states are H1b / H2b
  k_link_out<<<(NT + 255) / 256, 256, 0, stream>>>(H1b, H2b, lw4, lb4, out);
}

// Round 2
// 1705.224 us; speedup vs baseline: 2.1922x; 2.1922x over previous
//
#include <hip/hip_runtime.h>
#include <math.h>

#define NN 20000
#define NE 200000
#define NT 40000

// ---------------- utility kernels ----------------
__global__ void k_fill_f32(float* __restrict__ p, float v, int n) {
  int i = blockIdx.x * 256 + threadIdx.x;
  if (i < n) p[i] = v;
}

__global__ void k_edge_mlp(const float* __restrict__ ea,
                           const float* __restrict__ w1, const float* __restrict__ b1,
                           const float* __restrict__ w2, const float* __restrict__ b2,
                           const float* __restrict__ w3, const float* __restrict__ b3,
                           float* __restrict__ out) {
  int e = blockIdx.x * 256 + threadIdx.x;
  if (e >= NE) return;
  float a[7];
#pragma unroll
  for (int i = 0; i < 7; i++) a[i] = ea[e * 7 + i];
  float t1[28];
#pragma unroll
  for (int j = 0; j < 28; j++) {
    float s = b1[j];
#pragma unroll
    for (int k = 0; k < 7; k++) s = fmaf(a[k], w1[k * 28 + j], s);
    t1[j] = fmaxf(s, 0.f);
  }
  float t2[28];
  for (int j = 0; j < 28; j++) {
    float s = b2[j];
    for (int k = 0; k < 28; k++) s = fmaf(t1[k], w2[k * 28 + j], s);
    t2[j] = fmaxf(s, 0.f);
  }
  float s = b3[0];
  for (int k = 0; k < 28; k++) s = fmaf(t2[k], w3[k], s);
  out[e] = 1.f / (1.f + expf(-s));
}

__global__ void k_deg_accum(const float* __restrict__ ea, const float* __restrict__ ew,
                            const int* __restrict__ col, float* __restrict__ deg) {
  int e = blockIdx.x * 256 + threadIdx.x;
  if (e >= NE) return;
  int c = col[e];
#pragma unroll
  for (int i = 0; i < 7; i++) atomicAdd(&deg[i * NN + c], ea[e * 7 + i]);
  atomicAdd(&deg[7 * NN + c], ew[e]);
}

__global__ void k_rsqrt(float* __restrict__ p, int n) {
  int i = blockIdx.x * 256 + threadIdx.x;
  if (i < n) { float d = p[i]; p[i] = d > 0.f ? rsqrtf(d) : 0.f; }
}

__global__ void k_count(const int* __restrict__ col, int* __restrict__ cnt) {
  int e = blockIdx.x * 256 + threadIdx.x;
  if (e < NE) atomicAdd(&cnt[col[e]], 1);
}

__global__ void k_scan(const int* __restrict__ cnt, int* __restrict__ rowptr) {
  __shared__ int sums[256];
  __shared__ int offs[256];
  int t = threadIdx.x;
  const int CH = (NN + 255) / 256;
  int base = t * CH;
  int s = 0;
  for (int i = 0; i < CH; i++) { int idx = base + i; if (idx < NN) s += cnt[idx]; }
  sums[t] = s;
  __syncthreads();
  if (t == 0) {
    int acc = 0;
    for (int i = 0; i < 256; i++) { offs[i] = acc; acc += sums[i]; }
    rowptr[NN] = acc;
  }
  __syncthreads();
  int acc = offs[t];
  for (int i = 0; i < CH; i++) {
    int idx = base + i;
    if (idx < NN) { rowptr[idx] = acc; acc += cnt[idx]; }
  }
}

__global__ void k_copy_i32(const int* __restrict__ src, int* __restrict__ dst, int n) {
  int i = blockIdx.x * 256 + threadIdx.x;
  if (i < n) dst[i] = src[i];
}

__global__ void k_fill_csr(const int* __restrict__ col, int* __restrict__ cursor,
                           int* __restrict__ eid) {
  int e = blockIdx.x * 256 + threadIdx.x;
  if (e >= NE) return;
  int pos = atomicAdd(&cursor[col[e]], 1);
  eid[pos] = e;
}

__global__ void k_csr_norms(const int* __restrict__ eid, const int* __restrict__ row,
                            const int* __restrict__ col, const float* __restrict__ ea,
                            const float* __restrict__ ew, const float* __restrict__ dis,
                            int* __restrict__ csr_src, float* __restrict__ csr_norm) {
  int p = blockIdx.x * 256 + threadIdx.x;
  if (p >= NE) return;
  int e = eid[p];
  int r = row[e], c = col[e];
  csr_src[p] = r;
#pragma unroll
  for (int i = 0; i < 7; i++)
    csr_norm[i * NE + p] = dis[i * NN + r] * ea[e * 7 + i] * dis[i * NN + c];
  csr_norm[7 * NE + p] = dis[7 * NN + r] * ew[e] * dis[7 * NN + c];
}

// ---------------- GEMM ----------------
// C[M, gridDim.y*128] with per-128-column-group matrix B_g = B + g*matStride
// (B_g is [K,128] row-major). Tile: TM=64, TN=128, TK=16, 256 threads,
// micro-tile 4x8 (rows ty*4+i, cols {tx*4+j, 64+tx*4+j}).
// All LDS patterns <=2-way bank aliasing (free on gfx950 — m136).
template <bool RELU, bool BIAS>
__global__ __launch_bounds__(256) void k_gemm(const float* __restrict__ A, int ldA,
                                              const float* __restrict__ B, size_t matStride,
                                              const float* __restrict__ bias,
                                              float* __restrict__ C, int ldC,
                                              int M, int K) {
  __shared__ float As[16][68];   // [k][m], pad 68 keeps writes 2-way
  __shared__ float Bs[16][128];  // [k][n]
  const int tid = threadIdx.x;
  const int tx = tid & 15, ty = tid >> 4;
  const int bm = blockIdx.x * 64;
  const int g = blockIdx.y;
  const float* Bg = B + (size_t)g * matStride;
  float acc[4][8] = {};
  // A stage: thread -> (row ar, k-offset akb..akb+3), one float4
  const int ar = tid >> 2, akb = (tid & 3) * 4;
  // B stage: thread -> (k bk & bk+8, cols bc..bc+3), two float4
  const int bc = (tid & 31) * 4, bk = tid >> 5;
  const int agm = bm + ar;

  for (int k0 = 0; k0 < K; k0 += 16) {
    float4 a4;
    if (agm < M && akb + k0 < K)  // K%4==0, akb%4==0 -> full float4 in range
      a4 = *(const float4*)(A + (size_t)agm * ldA + k0 + akb);
    else
      a4 = make_float4(0.f, 0.f, 0.f, 0.f);
    As[akb + 0][ar] = a4.x;
    As[akb + 1][ar] = a4.y;
    As[akb + 2][ar] = a4.z;
    As[akb + 3][ar] = a4.w;
#pragma unroll
    for (int l = 0; l < 2; l++) {
      int gk = k0 + bk + l * 8;
      float4 b4 = (gk < K) ? *(const float4*)(Bg + (size_t)gk * 128 + bc)
                           : make_float4(0.f, 0.f, 0.f, 0.f);
      *(float4*)&Bs[bk + l * 8][bc] = b4;
    }
    __syncthreads();
#pragma unroll
    for (int k = 0; k < 16; k++) {
      float av[4], bv[8];
      *(float4*)av = *(const float4*)&As[k][ty * 4];
      *(float4*)bv = *(const float4*)&Bs[k][tx * 4];
      *(float4*)(bv + 4) = *(const float4*)&Bs[k][64 + tx * 4];
#pragma unroll
      for (int i = 0; i < 4; i++)
#pragma unroll
        for (int j = 0; j < 8; j++) acc[i][j] = fmaf(av[i], bv[j], acc[i][j]);
    }
    __syncthreads();
  }

  const int cb = g * 128;
  float bload[8];
  if (BIAS) {
#pragma unroll
    for (int j = 0; j < 4; j++) {
      bload[j] = bias[cb + tx * 4 + j];
      bload[j + 4] = bias[cb + 64 + tx * 4 + j];
    }
  }
#pragma unroll
  for (int i = 0; i < 4; i++) {
    int gm = bm + ty * 4 + i;
    if (gm >= M) continue;
    float v[8];
#pragma unroll
    for (int j = 0; j < 8; j++) {
      v[j] = acc[i][j];
      if (BIAS) v[j] += bload[j];
      if (RELU) v[j] = fmaxf(v[j], 0.f);
    }
    *(float4*)(C + (size_t)gm * ldC + cb + tx * 4) = *(float4*)v;
    *(float4*)(C + (size_t)gm * ldC + cb + 64 + tx * 4) = *(float4*)(v + 4);
  }
}

// ---------------- fused 7-relation aggregation ----------------
// out[n, f] = relu(b[f] + dis_i(n)^2*hW[n,f] + sum_p norm_i(p)*hW[src_p, f]),
// f in [0,896), i = f>>7. hW is [NN,896] (relation i in cols i*128..).
__global__ __launch_bounds__(896) void k_agg7(const float* __restrict__ hW,
                                              const float* __restrict__ csr_norm,
                                              const float* __restrict__ dis,
                                              const int* __restrict__ rowptr,
                                              const int* __restrict__ csr_src,
                                              const float* __restrict__ bias,
                                              float* __restrict__ out) {
  int n = blockIdx.x;
  int f = threadIdx.x;
  int i = f >> 7;
  float d = dis[i * NN + n];
  float acc = d * d * hW[(size_t)n * 896 + f];
  int s = rowptr[n], e = rowptr[n + 1];
  for (int p = s; p < e; p++) {
    acc = fmaf(csr_norm[i * NE + p], hW[(size_t)csr_src[p] * 896 + f], acc);
  }
  out[(size_t)n * 896 + f] = fmaxf(acc + bias[f], 0.f);
}

// single-relation aggregation (layer 1, learned edge weight)
__global__ __launch_bounds__(128) void k_agg1(const float* __restrict__ hW,
                                              const float* __restrict__ csr_norm_i,
                                              const float* __restrict__ dis_i,
                                              const int* __restrict__ rowptr,
                                              const int* __restrict__ csr_src,
                                              const float* __restrict__ bias,
                                              float* __restrict__ out) {
  int n = blockIdx.x;
  int f = threadIdx.x;
  float d = dis_i[n];
  float acc = d * d * hW[(size_t)n * 128 + f];
  int s = rowptr[n], e2 = rowptr[n + 1];
  for (int p = s; p < e2; p++) {
    acc = fmaf(csr_norm_i[p], hW[(size_t)csr_src[p] * 128 + f], acc);
  }
  out[(size_t)n * 128 + f] = fmaxf(acc + bias[f], 0.f);
}

// ---------------- link MLP ----------------
// UV is [NN,256]: cols 0..127 = U, 128..255 = V
__global__ __launch_bounds__(128) void k_link_gather(const float* __restrict__ UV,
                                                     const int* __restrict__ eit,
                                                     const float* __restrict__ lb0,
                                                     float* __restrict__ H1,
                                                     float* __restrict__ H2) {
  int t = blockIdx.x;
  int f = threadIdx.x;
  int s = eit[t], d = eit[NT + t];
  float b = lb0[f];
  H1[(size_t)t * 128 + f] = fmaxf(UV[(size_t)s * 256 + f] + UV[(size_t)d * 256 + 128 + f] + b, 0.f);
  H2[(size_t)t * 128 + f] = fmaxf(UV[(size_t)d * 256 + f] + UV[(size_t)s * 256 + 128 + f] + b, 0.f);
}

__global__ void k_link_out(const float* __restrict__ H1, const float* __restrict__ H2,
                           const float* __restrict__ lw4, const float* __restrict__ lb4,
                           float* __restrict__ out) {
  int t = blockIdx.x * 256 + threadIdx.x;
  if (t >= NT) return;
  float o1[4] = {lb4[0], lb4[1], lb4[2], lb4[3]};
  float o2[4] = {o1[0], o1[1], o1[2], o1[3]};
  for (int k = 0; k < 128; k++) {
    float h1 = H1[(size_t)t * 128 + k];
    float h2 = H2[(size_t)t * 128 + k];
#pragma unroll
    for (int j = 0; j < 4; j++) {
      float w = lw4[k * 4 + j];
      o1[j] = fmaf(h1, w, o1[j]);
      o2[j] = fmaf(h2, w, o2[j]);
    }
  }
  out[t * 4 + 0] = 0.5f * (o1[0] + o2[0]);
  out[t * 4 + 1] = 0.5f * (o1[1] + o2[2]);
  out[t * 4 + 2] = 0.5f * (o1[2] + o2[1]);
  out[t * 4 + 3] = 0.5f * (o1[3] + o2[3]);
}

// ---------------- host ----------------
extern "C" void kernel_launch(void* const* d_in, const int* in_sizes, int n_in,
                              void* d_out, int out_size, void* d_ws, size_t ws_size,
                              hipStream_t stream) {
  const float* x   = (const float*)d_in[0];
  const int*   ei  = (const int*)d_in[1];
  const float* ea  = (const float*)d_in[2];
  const int*   eit = (const int*)d_in[3];
  const float* W0  = (const float*)d_in[4];
  const float* b0  = (const float*)d_in[5];
  const float* W1  = (const float*)d_in[6];
  const float* b1  = (const float*)d_in[7];
  const float* W2  = (const float*)d_in[8];
  const float* b2  = (const float*)d_in[9];
  const float* W3  = (const float*)d_in[10];
  const float* b3  = (const float*)d_in[11];
  const float* ew1 = (const float*)d_in[12];
  const float* eb1 = (const float*)d_in[13];
  const float* ew2 = (const float*)d_in[14];
  const float* eb2 = (const float*)d_in[15];
  const float* ew3 = (const float*)d_in[16];
  const float* eb3 = (const float*)d_in[17];
  const float* lw0 = (const float*)d_in[18];
  const float* lb0 = (const float*)d_in[19];
  const float* lwh = (const float*)d_in[20];
  const float* lbh = (const float*)d_in[21];
  const float* lw4 = (const float*)d_in[22];
  const float* lb4 = (const float*)d_in[23];
  const int* row = ei;
  const int* col = ei + NE;
  float* out = (float*)d_out;

  char* ws = (char*)d_ws;
  size_t off = 0;
  auto alloc = [&](size_t bytes) -> char* {
    char* p = ws + off;
    off += (bytes + 255) & ~(size_t)255;
    return p;
  };
  // Layout (xB and x2 MUST be adjacent: the link H buffers overlay [xB|x2],
  // 4*NT*128*4 = 81.92MB == 71.68MB + 10.24MB exactly).
  float* xA      = (float*)alloc((size_t)NN * 896 * 4);  // x1 -> x3 -> x4
  float* xB      = (float*)alloc((size_t)NN * 896 * 4);  // hW per layer -> H overlay
  float* x2buf   = (float*)alloc((size_t)NN * 128 * 4);  // x2 -> H overlay tail
  float* UV      = (float*)alloc((size_t)NN * 256 * 4);
  float* csr_nrm = (float*)alloc((size_t)8 * NE * 4);
  float* dis     = (float*)alloc((size_t)8 * NN * 4);
  float* ewb     = (float*)alloc((size_t)NE * 4);
  int*   rowptr  = (int*)alloc((size_t)(NN + 1) * 4);
  int*   cursor  = (int*)alloc((size_t)NN * 4);
  int*   eid     = (int*)alloc((size_t)NE * 4);
  int*   csr_src = (int*)alloc((size_t)NE * 4);
  (void)ws_size; (void)in_sizes; (void)n_in; (void)out_size;

  const int EB = (NE + 255) / 256;
  const int NB = (NN + 255) / 256;
  const int MB = (NN + 63) / 64;  // 313

  // 1) learned edge weight
  k_edge_mlp<<<EB, 256, 0, stream>>>(ea, ew1, eb1, ew2, eb2, ew3, eb3, ewb);
  // 2) weighted degrees (init 1.0 = self-loop) -> dis (rsqrt in place)
  k_fill_f32<<<(8 * NN + 255) / 256, 256, 0, stream>>>(dis, 1.f, 8 * NN);
  k_deg_accum<<<EB, 256, 0, stream>>>(ea, ewb, col, dis);
  k_rsqrt<<<(8 * NN + 255) / 256, 256, 0, stream>>>(dis, 8 * NN);
  // 3) CSR by destination + norms in CSR order
  hipMemsetAsync(cursor, 0, (size_t)NN * 4, stream);
  k_count<<<EB, 256, 0, stream>>>(col, cursor);
  k_scan<<<1, 256, 0, stream>>>(cursor, rowptr);
  k_copy_i32<<<NB, 256, 0, stream>>>(rowptr, cursor, NN);
  k_fill_csr<<<EB, 256, 0, stream>>>(col, cursor, eid);
  k_csr_norms<<<EB, 256, 0, stream>>>(eid, row, col, ea, ewb, dis, csr_src, csr_nrm);

  // Layer 0: fused GEMM x[N,8] @ W0 (7 mats) -> hW [N,896]; fused agg -> x1 (xA)
  k_gemm<false, false><<<dim3(MB, 7), 256, 0, stream>>>(x, 8, W0, (size_t)8 * 128, nullptr,
                                                        xB, 896, NN, 8);
  k_agg7<<<NN, 896, 0, stream>>>(xB, csr_nrm, dis, rowptr, csr_src, b0, xA);

  // Layer 1: x1 @ W1 -> hW1 [N,128]; agg (learned ew, idx 7) -> x2
  k_gemm<false, false><<<dim3(MB, 1), 256, 0, stream>>>(xA, 896, W1, 0, nullptr,
                                                        xB, 128, NN, 896);
  k_agg1<<<NN, 128, 0, stream>>>(xB, csr_nrm + (size_t)7 * NE, dis + (size_t)7 * NN,
                                 rowptr, csr_src, b1, x2buf);

  // Layer 2: x2 @ W2 (7 mats) -> hW; fused agg -> x3 (xA, x1 dead)
  k_gemm<false, false><<<dim3(MB, 7), 256, 0, stream>>>(x2buf, 128, W2, (size_t)128 * 128,
                                                        nullptr, xB, 896, NN, 128);
  k_agg7<<<NN, 896, 0, stream>>>(xB, csr_nrm, dis, rowptr, csr_src, b2, xA);

  // Layer 3: x3 @ W3 (7 mats) -> hW; fused agg -> x4 (back into xA; x3 dead)
  k_gemm<false, false><<<dim3(MB, 7), 256, 0, stream>>>(xA, 896, W3, (size_t)896 * 128,
                                                        nullptr, xB, 896, NN, 896);
  k_agg7<<<NN, 896, 0, stream>>>(xB, csr_nrm, dis, rowptr, csr_src, b3, xA);

  // Link precompute: UV = x4 @ [lw0_top | lw0_bot]  (N=256 fused)
  k_gemm<false, false><<<dim3(MB, 2), 256, 0, stream>>>(xA, 896, lw0, (size_t)896 * 128,
                                                        nullptr, UV, 256, NN, 896);

  // H buffers overlay [xB | x2buf]; H1/H2 adjacent so link GEMMs run M=2*NT
  float* Ha = xB;                         // [H1a | H2a]
  float* Hb = xB + (size_t)2 * NT * 128;  // [H1b | H2b] (tail lands in x2buf)
  k_link_gather<<<NT, 128, 0, stream>>>(UV, eit, lb0, Ha, Ha + (size_t)NT * 128);
  const int LB = (2 * NT + 63) / 64;  // 1250
  for (int i = 0; i < 3; i++) {
    const float* w  = lwh + (size_t)i * 128 * 128;
    const float* bb = lbh + (size_t)i * 128;
    float* src = (i % 2 == 0) ? Ha : Hb;
    float* dst = (i % 2 == 0) ? Hb : Ha;
    k_gemm<true, true><<<dim3(LB, 1), 256, 0, stream>>>(src, 128, w, 0, bb, dst, 128,
                                                        2 * NT, 128);
  }
  // after 3 ping-pongs final state is Hb
  k_link_out<<<(NT + 255) / 256, 256, 0, stream>>>(Hb, Hb + (size_t)NT * 128, lw4, lb4, out);
}

// Round 4
// 1053.778 us; speedup vs baseline: 3.5474x; 1.6182x over previous
//
#include <hip/hip_runtime.h>
#include <math.h>

#define NN 20000
#define NE 200000
#define NT 40000

typedef unsigned short u16;
typedef __attribute__((ext_vector_type(8))) short short8;
typedef __attribute__((ext_vector_type(4))) float f32x4;

__device__ __forceinline__ u16 f2bf(float x) {
  unsigned int u = __float_as_uint(x);
  u += 0x7FFF + ((u >> 16) & 1);  // RNE
  return (u16)(u >> 16);
}
__device__ __forceinline__ float bf2f(u16 h) {
  return __uint_as_float((unsigned int)h << 16);
}
__device__ __forceinline__ void split_store(float v, u16* hi, u16* lo, size_t idx) {
  u16 h = f2bf(v);
  hi[idx] = h;
  lo[idx] = f2bf(v - bf2f(h));
}

// ---------------- edge weight MLP ----------------
__global__ void k_edge_mlp(const float* __restrict__ ea,
                           const float* __restrict__ w1, const float* __restrict__ b1,
                           const float* __restrict__ w2, const float* __restrict__ b2,
                           const float* __restrict__ w3, const float* __restrict__ b3,
                           float* __restrict__ out) {
  int e = blockIdx.x * 256 + threadIdx.x;
  if (e >= NE) return;
  float a[7];
#pragma unroll
  for (int i = 0; i < 7; i++) a[i] = ea[e * 7 + i];
  float t1[28];
#pragma unroll
  for (int j = 0; j < 28; j++) {
    float s = b1[j];
#pragma unroll
    for (int k = 0; k < 7; k++) s = fmaf(a[k], w1[k * 28 + j], s);
    t1[j] = fmaxf(s, 0.f);
  }
  float t2[28];
  for (int j = 0; j < 28; j++) {
    float s = b2[j];
    for (int k = 0; k < 28; k++) s = fmaf(t1[k], w2[k * 28 + j], s);
    t2[j] = fmaxf(s, 0.f);
  }
  float s = b3[0];
  for (int k = 0; k < 28; k++) s = fmaf(t2[k], w3[k], s);
  out[e] = 1.f / (1.f + expf(-s));
}

// ---------------- CSR build ----------------
__global__ void k_count(const int* __restrict__ col, int* __restrict__ cnt) {
  int e = blockIdx.x * 256 + threadIdx.x;
  if (e < NE) atomicAdd(&cnt[col[e]], 1);
}

__global__ void k_scan(const int* __restrict__ cnt, int* __restrict__ rowptr) {
  __shared__ int sums[256];
  __shared__ int offs[256];
  int t = threadIdx.x;
  const int CH = (NN + 255) / 256;
  int base = t * CH;
  int s = 0;
  for (int i = 0; i < CH; i++) { int idx = base + i; if (idx < NN) s += cnt[idx]; }
  sums[t] = s;
  __syncthreads();
  if (t == 0) {
    int acc = 0;
    for (int i = 0; i < 256; i++) { offs[i] = acc; acc += sums[i]; }
    rowptr[NN] = acc;
  }
  __syncthreads();
  int acc = offs[t];
  for (int i = 0; i < CH; i++) {
    int idx = base + i;
    if (idx < NN) { rowptr[idx] = acc; acc += cnt[idx]; }
  }
}

__global__ void k_copy_i32(const int* __restrict__ src, int* __restrict__ dst, int n) {
  int i = blockIdx.x * 256 + threadIdx.x;
  if (i < n) dst[i] = src[i];
}

__global__ void k_fill_csr(const int* __restrict__ col, int* __restrict__ cursor,
                           int* __restrict__ eid) {
  int e = blockIdx.x * 256 + threadIdx.x;
  if (e >= NE) return;
  int pos = atomicAdd(&cursor[col[e]], 1);
  eid[pos] = e;
}

// degrees from CSR (no float atomics). 8 nodes x 8 relations per 64-thread block.
__global__ __launch_bounds__(64) void k_deg_csr(const int* __restrict__ rowptr,
                                                const int* __restrict__ eid,
                                                const float* __restrict__ ea,
                                                const float* __restrict__ ewb,
                                                float* __restrict__ dis) {
  int t = threadIdx.x;
  int n = blockIdx.x * 8 + (t >> 3);
  int i = t & 7;
  if (n >= NN) return;
  float deg = 1.f;  // self-loop weight
  int s = rowptr[n], e2 = rowptr[n + 1];
  for (int p = s; p < e2; p++) {
    int e = eid[p];
    deg += (i < 7) ? ea[e * 7 + i] : ewb[e];
  }
  dis[i * NN + n] = rsqrtf(deg);  // deg >= 1 always
}

__global__ void k_csr_norms(const int* __restrict__ eid, const int* __restrict__ row,
                            const int* __restrict__ col, const float* __restrict__ ea,
                            const float* __restrict__ ew, const float* __restrict__ dis,
                            int* __restrict__ csr_src, float* __restrict__ csr_norm) {
  int p = blockIdx.x * 256 + threadIdx.x;
  if (p >= NE) return;
  int e = eid[p];
  int r = row[e], c = col[e];
  csr_src[p] = r;
#pragma unroll
  for (int i = 0; i < 7; i++)
    csr_norm[i * NE + p] = dis[i * NN + r] * ea[e * 7 + i] * dis[i * NN + c];
  csr_norm[7 * NE + p] = dis[7 * NN + r] * ew[e] * dis[7 * NN + c];
}

// ---------------- weight prep: transpose + bf16 hi/lo split ----------------
// W[g][k][n] (ldW cols, mats matOff apart) -> WT[g][n][k] hi/lo
__global__ void k_wprep(const float* __restrict__ W, int ldW, size_t matOff, int K,
                        u16* __restrict__ WThi, u16* __restrict__ WTlo) {
  int g = blockIdx.y;
  int idx = blockIdx.x * 256 + threadIdx.x;
  if (idx >= K * 128) return;
  int k = idx >> 7, n = idx & 127;
  float v = W[(size_t)g * matOff + (size_t)k * ldW + n];
  size_t o = (size_t)g * 128 * K + (size_t)n * K + k;
  split_store(v, WThi, WTlo, o);
}

// ---------------- split-bf16 MFMA GEMM ----------------
// C[M, gridDim.y*128]; B group g = BT + g*128*K, BT is [n][k] (transposed).
// A given as hi/lo bf16 [M][K]. 3-term: Ahi*Bhi + Ahi*Blo + Alo*Bhi, fp32 acc.
// Tile 128x128, 4 waves of 64x64, mfma_f32_16x16x32_bf16, K%32==0.
template <bool RELU, bool BIAS, bool SPLIT_OUT>
__global__ __launch_bounds__(256) void k_mgemm(
    const u16* __restrict__ Ahi, const u16* __restrict__ Alo,
    const u16* __restrict__ BThi, const u16* __restrict__ BTlo,
    const float* __restrict__ bias,
    float* __restrict__ Cf, u16* __restrict__ Chi, u16* __restrict__ Clo,
    int M, int K) {
  __shared__ u16 smem[16384];  // 4 tiles [128 rows][32 k] bf16: Ahi,Alo,Bhi,Blo
  const int tid = threadIdx.x;
  const int w = tid >> 6, lane = tid & 63;
  const int quad = lane >> 4, lc = lane & 15;
  const int wr = w >> 1, wc = w & 1;
  const int bm = blockIdx.x * 128;
  const int ldC = gridDim.y * 128;
  const int cb = blockIdx.y * 128;
  const u16* Bhi = BThi + (size_t)blockIdx.y * 128 * K;
  const u16* Blo = BTlo + (size_t)blockIdx.y * 128 * K;
  const int srow = lane >> 2, skoff = (lane & 3) * 8;

  f32x4 acc[4][4] = {};

  for (int k0 = 0; k0 < K; k0 += 32) {
    // stage 32KB: 32 chunks of 1024B (16 rows x 64B), 8 per wave
#pragma unroll
    for (int l = 0; l < 8; l++) {
      int c = w + l * 4;
      int t = c >> 3, r16 = c & 7;
      int rowi = r16 * 16 + srow;
      u16* ldst = smem + t * 4096 + r16 * 512;  // +lane*16B implicit
      const u16* src;
      if (t < 2) {
        int gm = bm + rowi;
        if (gm > M - 1) gm = M - 1;  // clamp; guarded at store
        src = (t == 0 ? Ahi : Alo) + (size_t)gm * K + k0 + skoff;
      } else {
        src = (t == 2 ? Bhi : Blo) + (size_t)rowi * K + k0 + skoff;
      }
      __builtin_amdgcn_global_load_lds(
          (const __attribute__((address_space(1))) void*)src,
          (__attribute__((address_space(3))) void*)ldst, 16, 0, 0);
    }
    __syncthreads();
    short8 bh[4], bl[4];
#pragma unroll
    for (int nt = 0; nt < 4; nt++) {
      int r = wc * 64 + nt * 16 + lc;
      bh[nt] = *(const short8*)(smem + 2 * 4096 + r * 32 + quad * 8);
      bl[nt] = *(const short8*)(smem + 3 * 4096 + r * 32 + quad * 8);
    }
#pragma unroll
    for (int mt = 0; mt < 4; mt++) {
      int r = wr * 64 + mt * 16 + lc;
      short8 ah = *(const short8*)(smem + 0 * 4096 + r * 32 + quad * 8);
      short8 al = *(const short8*)(smem + 1 * 4096 + r * 32 + quad * 8);
#pragma unroll
      for (int nt = 0; nt < 4; nt++) {
        acc[mt][nt] = __builtin_amdgcn_mfma_f32_16x16x32_bf16(ah, bh[nt], acc[mt][nt], 0, 0, 0);
        acc[mt][nt] = __builtin_amdgcn_mfma_f32_16x16x32_bf16(ah, bl[nt], acc[mt][nt], 0, 0, 0);
        acc[mt][nt] = __builtin_amdgcn_mfma_f32_16x16x32_bf16(al, bh[nt], acc[mt][nt], 0, 0, 0);
      }
    }
    __syncthreads();
  }

  float bv[4];
  if (BIAS) {
#pragma unroll
    for (int nt = 0; nt < 4; nt++) bv[nt] = bias[cb + wc * 64 + nt * 16 + lc];
  }
#pragma unroll
  for (int mt = 0; mt < 4; mt++) {
#pragma unroll
    for (int r = 0; r < 4; r++) {
      int gm = bm + wr * 64 + mt * 16 + quad * 4 + r;
      if (gm >= M) continue;
#pragma unroll
      for (int nt = 0; nt < 4; nt++) {
        float v = acc[mt][nt][r];
        if (BIAS) v += bv[nt];
        if (RELU) v = fmaxf(v, 0.f);
        size_t idx = (size_t)gm * ldC + cb + wc * 64 + nt * 16 + lc;
        if (SPLIT_OUT) {
          u16 h = f2bf(v);
          Chi[idx] = h;
          Clo[idx] = f2bf(v - bf2f(h));
        } else {
          Cf[idx] = v;
        }
      }
    }
  }
}

// ---------------- aggregation (fp32 in, bf16 hi/lo out) ----------------
__global__ __launch_bounds__(896) void k_agg7(const float* __restrict__ hW,
                                              const float* __restrict__ csr_norm,
                                              const float* __restrict__ dis,
                                              const int* __restrict__ rowptr,
                                              const int* __restrict__ csr_src,
                                              const float* __restrict__ bias,
                                              u16* __restrict__ outhi,
                                              u16* __restrict__ outlo) {
  int n = blockIdx.x;
  int f = threadIdx.x;
  int i = f >> 7;
  float d = dis[i * NN + n];
  float acc = d * d * hW[(size_t)n * 896 + f];
  int s = rowptr[n], e = rowptr[n + 1];
  for (int p = s; p < e; p++)
    acc = fmaf(csr_norm[i * NE + p], hW[(size_t)csr_src[p] * 896 + f], acc);
  float v = fmaxf(acc + bias[f], 0.f);
  split_store(v, outhi, outlo, (size_t)n * 896 + f);
}

__global__ __launch_bounds__(128) void k_agg1(const float* __restrict__ hW,
                                              const float* __restrict__ csr_norm_i,
                                              const float* __restrict__ dis_i,
                                              const int* __restrict__ rowptr,
                                              const int* __restrict__ csr_src,
                                              const float* __restrict__ bias,
                                              u16* __restrict__ outhi,
                                              u16* __restrict__ outlo) {
  int n = blockIdx.x;
  int f = threadIdx.x;
  float d = dis_i[n];
  float acc = d * d * hW[(size_t)n * 128 + f];
  int s = rowptr[n], e2 = rowptr[n + 1];
  for (int p = s; p < e2; p++)
    acc = fmaf(csr_norm_i[p], hW[(size_t)csr_src[p] * 128 + f], acc);
  float v = fmaxf(acc + bias[f], 0.f);
  split_store(v, outhi, outlo, (size_t)n * 128 + f);
}

// ---------------- layer 0: aggregate-first (x is only [N,8]) ----------------
__global__ __launch_bounds__(64) void k_agg_x(const float* __restrict__ x,
                                              const float* __restrict__ csr_norm,
                                              const float* __restrict__ dis,
                                              const int* __restrict__ rowptr,
                                              const int* __restrict__ csr_src,
                                              float* __restrict__ xagg) {
  int n = blockIdx.x;
  int f = threadIdx.x;
  if (f >= 56) return;
  int i = f >> 3, c = f & 7;
  float d = dis[i * NN + n];
  float acc = d * d * x[(size_t)n * 8 + c];
  int s = rowptr[n], e = rowptr[n + 1];
  for (int p = s; p < e; p++)
    acc = fmaf(csr_norm[i * NE + p], x[(size_t)csr_src[p] * 8 + c], acc);
  xagg[(size_t)n * 56 + f] = acc;
}

// x1[n, i*128+h] = relu(b0[i][h] + sum_c xagg[n][i*8+c] * W0[i][c][h]), hi/lo out
__global__ __launch_bounds__(896) void k_gemm0(const float* __restrict__ xagg,
                                               const float* __restrict__ W0,
                                               const float* __restrict__ b0,
                                               u16* __restrict__ outhi,
                                               u16* __restrict__ outlo) {
  int n = blockIdx.x;
  int f = threadIdx.x;
  int i = f >> 7, h = f & 127;
  float s = b0[i * 128 + h];
#pragma unroll
  for (int c = 0; c < 8; c++)
    s = fmaf(xagg[(size_t)n * 56 + i * 8 + c], W0[(i * 8 + c) * 128 + h], s);
  float v = fmaxf(s, 0.f);
  split_store(v, outhi, outlo, (size_t)n * 896 + f);
}

// ---------------- link MLP ----------------
__global__ __launch_bounds__(128) void k_link_gather(const float* __restrict__ UV,
                                                     const int* __restrict__ eit,
                                                     const float* __restrict__ lb0,
                                                     u16* __restrict__ Hhi,
                                                     u16* __restrict__ Hlo) {
  int t = blockIdx.x;
  int f = threadIdx.x;
  int s = eit[t], d = eit[NT + t];
  float b = lb0[f];
  float v1 = fmaxf(UV[(size_t)s * 256 + f] + UV[(size_t)d * 256 + 128 + f] + b, 0.f);
  float v2 = fmaxf(UV[(size_t)d * 256 + f] + UV[(size_t)s * 256 + 128 + f] + b, 0.f);
  split_store(v1, Hhi, Hlo, (size_t)t * 128 + f);
  split_store(v2, Hhi, Hlo, (size_t)(NT + t) * 128 + f);
}

__global__ void k_link_out(const u16* __restrict__ Hhi, const u16* __restrict__ Hlo,
                           const float* __restrict__ lw4, const float* __restrict__ lb4,
                           float* __restrict__ out) {
  int t = blockIdx.x * 256 + threadIdx.x;
  if (t >= NT) return;
  float o1[4] = {lb4[0], lb4[1], lb4[2], lb4[3]};
  float o2[4] = {o1[0], o1[1], o1[2], o1[3]};
  for (int k = 0; k < 128; k++) {
    size_t i1 = (size_t)t * 128 + k, i2 = (size_t)(NT + t) * 128 + k;
    float h1 = bf2f(Hhi[i1]) + bf2f(Hlo[i1]);
    float h2 = bf2f(Hhi[i2]) + bf2f(Hlo[i2]);
#pragma unroll
    for (int j = 0; j < 4; j++) {
      float w = lw4[k * 4 + j];
      o1[j] = fmaf(h1, w, o1[j]);
      o2[j] = fmaf(h2, w, o2[j]);
    }
  }
  out[t * 4 + 0] = 0.5f * (o1[0] + o2[0]);
  out[t * 4 + 1] = 0.5f * (o1[1] + o2[2]);
  out[t * 4 + 2] = 0.5f * (o1[2] + o2[1]);
  out[t * 4 + 3] = 0.5f * (o1[3] + o2[3]);
}

// ---------------- host ----------------
extern "C" void kernel_launch(void* const* d_in, const int* in_sizes, int n_in,
                              void* d_out, int out_size, void* d_ws, size_t ws_size,
                              hipStream_t stream) {
  const float* x   = (const float*)d_in[0];
  const int*   ei  = (const int*)d_in[1];
  const float* ea  = (const float*)d_in[2];
  const int*   eit = (const int*)d_in[3];
  const float* W0  = (const float*)d_in[4];
  const float* b0  = (const float*)d_in[5];
  const float* W1  = (const float*)d_in[6];
  const float* b1  = (const float*)d_in[7];
  const float* W2  = (const float*)d_in[8];
  const float* b2  = (const float*)d_in[9];
  const float* W3  = (const float*)d_in[10];
  const float* b3  = (const float*)d_in[11];
  const float* ew1 = (const float*)d_in[12];
  const float* eb1 = (const float*)d_in[13];
  const float* ew2 = (const float*)d_in[14];
  const float* eb2 = (const float*)d_in[15];
  const float* ew3 = (const float*)d_in[16];
  const float* eb3 = (const float*)d_in[17];
  const float* lw0 = (const float*)d_in[18];
  const float* lb0 = (const float*)d_in[19];
  const float* lwh = (const float*)d_in[20];
  const float* lbh = (const float*)d_in[21];
  const float* lw4 = (const float*)d_in[22];
  const float* lb4 = (const float*)d_in[23];
  const int* row = ei;
  const int* col = ei + NE;
  float* out = (float*)d_out;

  char* ws = (char*)d_ws;
  size_t off = 0;
  auto alloc = [&](size_t bytes) -> char* {
    char* p = ws + off;
    off += (bytes + 255) & ~(size_t)255;
    return p;
  };
  // xA hi/lo: x1 -> x3 -> x4. xB: hW fp32, later H overlay (xB+x2 = 81.92MB exact,
  // sizes are 256B-multiples so no padding breaks adjacency).
  u16*   xAhi   = (u16*)alloc((size_t)NN * 896 * 2);
  u16*   xAlo   = (u16*)alloc((size_t)NN * 896 * 2);
  float* xB     = (float*)alloc((size_t)NN * 896 * 4);
  u16*   x2hi   = (u16*)alloc((size_t)NN * 128 * 2);
  u16*   x2lo   = (u16*)alloc((size_t)NN * 128 * 2);
  float* UV     = (float*)alloc((size_t)NN * 256 * 4);  // xagg overlays front
  float* csr_nrm= (float*)alloc((size_t)8 * NE * 4);
  float* dis    = (float*)alloc((size_t)8 * NN * 4);
  float* ewb    = (float*)alloc((size_t)NE * 4);
  int*   rowptr = (int*)alloc((size_t)(NN + 1) * 4);
  int*   cursor = (int*)alloc((size_t)NN * 4);
  int*   eid    = (int*)alloc((size_t)NE * 4);
  int*   csr_src= (int*)alloc((size_t)NE * 4);
  u16* w1thi  = (u16*)alloc((size_t)128 * 896 * 2);
  u16* w1tlo  = (u16*)alloc((size_t)128 * 896 * 2);
  u16* w2thi  = (u16*)alloc((size_t)7 * 128 * 128 * 2);
  u16* w2tlo  = (u16*)alloc((size_t)7 * 128 * 128 * 2);
  u16* w3thi  = (u16*)alloc((size_t)7 * 128 * 896 * 2);
  u16* w3tlo  = (u16*)alloc((size_t)7 * 128 * 896 * 2);
  u16* lw0thi = (u16*)alloc((size_t)2 * 128 * 896 * 2);
  u16* lw0tlo = (u16*)alloc((size_t)2 * 128 * 896 * 2);
  u16* lwhthi = (u16*)alloc((size_t)3 * 128 * 128 * 2);
  u16* lwhtlo = (u16*)alloc((size_t)3 * 128 * 128 * 2);
  float* xagg = UV;  // [NN][56] fp32, dead before UV written
  (void)ws_size; (void)in_sizes; (void)n_in; (void)out_size;

  const int EB = (NE + 255) / 256;
  const int NB = (NN + 255) / 256;
  const int GX = (NN + 127) / 128;  // 157

  // weight prep (independent)
  k_wprep<<<dim3(448, 1), 256, 0, stream>>>(W1, 128, 0, 896, w1thi, w1tlo);
  k_wprep<<<dim3(64, 7), 256, 0, stream>>>(W2, 128, (size_t)128 * 128, 128, w2thi, w2tlo);
  k_wprep<<<dim3(448, 7), 256, 0, stream>>>(W3, 128, (size_t)896 * 128, 896, w3thi, w3tlo);
  // lw0 is [1792][128]: U = rows 0..895, V = rows 896..1791  (R3 bug: was ldW=256, matOff=128)
  k_wprep<<<dim3(448, 2), 256, 0, stream>>>(lw0, 128, (size_t)896 * 128, 896, lw0thi, lw0tlo);
  k_wprep<<<dim3(64, 3), 256, 0, stream>>>(lwh, 128, (size_t)128 * 128, 128, lwhthi, lwhtlo);

  // edge weight + CSR + degrees + norms
  k_edge_mlp<<<EB, 256, 0, stream>>>(ea, ew1, eb1, ew2, eb2, ew3, eb3, ewb);
  hipMemsetAsync(cursor, 0, (size_t)NN * 4, stream);
  k_count<<<EB, 256, 0, stream>>>(col, cursor);
  k_scan<<<1, 256, 0, stream>>>(cursor, rowptr);
  k_copy_i32<<<NB, 256, 0, stream>>>(rowptr, cursor, NN);
  k_fill_csr<<<EB, 256, 0, stream>>>(col, cursor, eid);
  k_deg_csr<<<(NN + 7) / 8, 64, 0, stream>>>(rowptr, eid, ea, ewb, dis);
  k_csr_norms<<<EB, 256, 0, stream>>>(eid, row, col, ea, ewb, dis, csr_src, csr_nrm);

  // Layer 0 (aggregate-first): xagg [N,7,8] -> x1 hi/lo
  k_agg_x<<<NN, 64, 0, stream>>>(x, csr_nrm, dis, rowptr, csr_src, xagg);
  k_gemm0<<<NN, 896, 0, stream>>>(xagg, W0, b0, xAhi, xAlo);

  // Layer 1: x1 @ W1 -> hW [N,128]; agg (learned ew) -> x2 hi/lo
  k_mgemm<false, false, false><<<dim3(GX, 1), 256, 0, stream>>>(
      xAhi, xAlo, w1thi, w1tlo, nullptr, xB, nullptr, nullptr, NN, 896);
  k_agg1<<<NN, 128, 0, stream>>>(xB, csr_nrm + (size_t)7 * NE, dis + (size_t)7 * NN,
                                 rowptr, csr_src, b1, x2hi, x2lo);

  // Layer 2: x2 @ W2 (7 mats, K=128) -> hW [N,896]; agg7 -> x3 hi/lo (xA)
  k_mgemm<false, false, false><<<dim3(GX, 7), 256, 0, stream>>>(
      x2hi, x2lo, w2thi, w2tlo, nullptr, xB, nullptr, nullptr, NN, 128);
  k_agg7<<<NN, 896, 0, stream>>>(xB, csr_nrm, dis, rowptr, csr_src, b2, xAhi, xAlo);

  // Layer 3: x3 @ W3 (7 mats, K=896) -> hW; agg7 -> x4 hi/lo (xA)
  k_mgemm<false, false, false><<<dim3(GX, 7), 256, 0, stream>>>(
      xAhi, xAlo, w3thi, w3tlo, nullptr, xB, nullptr, nullptr, NN, 896);
  k_agg7<<<NN, 896, 0, stream>>>(xB, csr_nrm, dis, rowptr, csr_src, b3, xAhi, xAlo);

  // Link precompute: UV = x4 @ [lw0_top | lw0_bot]
  k_mgemm<false, false, false><<<dim3(GX, 2), 256, 0, stream>>>(
      xAhi, xAlo, lw0thi, lw0tlo, nullptr, UV, nullptr, nullptr, NN, 896);

  // H overlay on [xB | x2hi | x2lo]: 4 arrays of 2NT*128 u16 = 81.92MB
  u16* Hahi = (u16*)xB;
  u16* Halo = Hahi + (size_t)2 * NT * 128;
  u16* Hbhi = Halo + (size_t)2 * NT * 128;
  u16* Hblo = Hbhi + (size_t)2 * NT * 128;
  k_link_gather<<<NT, 128, 0, stream>>>(UV, eit, lb0, Hahi, Halo);
  const int LGX = (2 * NT + 127) / 128;  // 625
  for (int i = 0; i < 3; i++) {
    const u16* whi = lwhthi + (size_t)i * 128 * 128;
    const u16* wlo = lwhtlo + (size_t)i * 128 * 128;
    const float* bb = lbh + (size_t)i * 128;
    u16* shi = (i % 2 == 0) ? Hahi : Hbhi;
    u16* slo = (i % 2 == 0) ? Halo : Hblo;
    u16* dhi = (i % 2 == 0) ? Hbhi : Hahi;
    u16* dlo = (i % 2 == 0) ? Hblo : Halo;
    k_mgemm<true, true, true><<<dim3(LGX, 1), 256, 0, stream>>>(
        shi, slo, whi, wlo, bb, nullptr, dhi, dlo, 2 * NT, 128);
  }
  // after 3 ping-pongs final state is Hb
  k_link_out<<<(NT + 255) / 256, 256, 0, stream>>>(Hbhi, Hblo, lw4, lb4, out);
}

// Round 5
// 826.670 us; speedup vs baseline: 4.5219x; 1.2747x over previous
//
#include <hip/hip_runtime.h>
#include <math.h>

#define NN 20000
#define NE 200000
#define NT 40000

typedef unsigned short u16;
typedef __attribute__((ext_vector_type(8))) short short8;
typedef __attribute__((ext_vector_type(4))) float f32x4;

__device__ __forceinline__ u16 f2bf(float x) {
  unsigned int u = __float_as_uint(x);
  u += 0x7FFF + ((u >> 16) & 1);  // RNE
  return (u16)(u >> 16);
}
__device__ __forceinline__ float bf2f(u16 h) {
  return __uint_as_float((unsigned int)h << 16);
}
__device__ __forceinline__ void split_store(float v, u16* hi, u16* lo, size_t idx) {
  u16 h = f2bf(v);
  hi[idx] = h;
  lo[idx] = f2bf(v - bf2f(h));
}

// ---------------- edge weight MLP ----------------
__global__ void k_edge_mlp(const float* __restrict__ ea,
                           const float* __restrict__ w1, const float* __restrict__ b1,
                           const float* __restrict__ w2, const float* __restrict__ b2,
                           const float* __restrict__ w3, const float* __restrict__ b3,
                           float* __restrict__ out) {
  int e = blockIdx.x * 256 + threadIdx.x;
  if (e >= NE) return;
  float a[7];
#pragma unroll
  for (int i = 0; i < 7; i++) a[i] = ea[e * 7 + i];
  float t1[28];
#pragma unroll
  for (int j = 0; j < 28; j++) {
    float s = b1[j];
#pragma unroll
    for (int k = 0; k < 7; k++) s = fmaf(a[k], w1[k * 28 + j], s);
    t1[j] = fmaxf(s, 0.f);
  }
  float t2[28];
  for (int j = 0; j < 28; j++) {
    float s = b2[j];
    for (int k = 0; k < 28; k++) s = fmaf(t1[k], w2[k * 28 + j], s);
    t2[j] = fmaxf(s, 0.f);
  }
  float s = b3[0];
  for (int k = 0; k < 28; k++) s = fmaf(t2[k], w3[k], s);
  out[e] = 1.f / (1.f + expf(-s));
}

// ---------------- CSR build ----------------
__global__ void k_count(const int* __restrict__ col, int* __restrict__ cnt) {
  int e = blockIdx.x * 256 + threadIdx.x;
  if (e < NE) atomicAdd(&cnt[col[e]], 1);
}

__global__ void k_scan(const int* __restrict__ cnt, int* __restrict__ rowptr) {
  __shared__ int sums[256];
  __shared__ int offs[256];
  int t = threadIdx.x;
  const int CH = (NN + 255) / 256;
  int base = t * CH;
  int s = 0;
  for (int i = 0; i < CH; i++) { int idx = base + i; if (idx < NN) s += cnt[idx]; }
  sums[t] = s;
  __syncthreads();
  if (t == 0) {
    int acc = 0;
    for (int i = 0; i < 256; i++) { offs[i] = acc; acc += sums[i]; }
    rowptr[NN] = acc;
  }
  __syncthreads();
  int acc = offs[t];
  for (int i = 0; i < CH; i++) {
    int idx = base + i;
    if (idx < NN) { rowptr[idx] = acc; acc += cnt[idx]; }
  }
}

__global__ void k_copy_i32(const int* __restrict__ src, int* __restrict__ dst, int n) {
  int i = blockIdx.x * 256 + threadIdx.x;
  if (i < n) dst[i] = src[i];
}

__global__ void k_fill_csr(const int* __restrict__ col, int* __restrict__ cursor,
                           int* __restrict__ eid) {
  int e = blockIdx.x * 256 + threadIdx.x;
  if (e >= NE) return;
  int pos = atomicAdd(&cursor[col[e]], 1);
  eid[pos] = e;
}

// degrees from CSR (no float atomics). 8 nodes x 8 relations per 64-thread block.
__global__ __launch_bounds__(64) void k_deg_csr(const int* __restrict__ rowptr,
                                                const int* __restrict__ eid,
                                                const float* __restrict__ ea,
                                                const float* __restrict__ ewb,
                                                float* __restrict__ dis) {
  int t = threadIdx.x;
  int n = blockIdx.x * 8 + (t >> 3);
  int i = t & 7;
  if (n >= NN) return;
  float deg = 1.f;  // self-loop weight
  int s = rowptr[n], e2 = rowptr[n + 1];
  for (int p = s; p < e2; p++) {
    int e = eid[p];
    deg += (i < 7) ? ea[e * 7 + i] : ewb[e];
  }
  dis[i * NN + n] = rsqrtf(deg);  // deg >= 1 always
}

__global__ void k_csr_norms(const int* __restrict__ eid, const int* __restrict__ row,
                            const int* __restrict__ col, const float* __restrict__ ea,
                            const float* __restrict__ ew, const float* __restrict__ dis,
                            int* __restrict__ csr_src, float* __restrict__ csr_norm) {
  int p = blockIdx.x * 256 + threadIdx.x;
  if (p >= NE) return;
  int e = eid[p];
  int r = row[e], c = col[e];
  csr_src[p] = r;
#pragma unroll
  for (int i = 0; i < 7; i++)
    csr_norm[i * NE + p] = dis[i * NN + r] * ea[e * 7 + i] * dis[i * NN + c];
  csr_norm[7 * NE + p] = dis[7 * NN + r] * ew[e] * dis[7 * NN + c];
}

// ---------------- weight prep: transpose + bf16 hi/lo split ----------------
// W[g][k][n] (ldW cols, mats matOff apart) -> WT[g][n][k] hi/lo
__global__ void k_wprep(const float* __restrict__ W, int ldW, size_t matOff, int K,
                        u16* __restrict__ WThi, u16* __restrict__ WTlo) {
  int g = blockIdx.y;
  int idx = blockIdx.x * 256 + threadIdx.x;
  if (idx >= K * 128) return;
  int k = idx >> 7, n = idx & 127;
  float v = W[(size_t)g * matOff + (size_t)k * ldW + n];
  size_t o = (size_t)g * 128 * K + (size_t)n * K + k;
  split_store(v, WThi, WTlo, o);
}

// ---------------- split-bf16 MFMA GEMM ----------------
// C[M, gridDim.y*128]; B group g = BT + g*128*K, BT is [n][k] (transposed).
// A hi/lo bf16, row stride ldA; if GROUP_A, group g reads A cols g*K..g*K+K-1.
// 3-term: Ahi*Bhi + Ahi*Blo + Alo*Bhi, fp32 acc. Tile 128x128, 4 waves 64x64.
template <bool RELU, bool BIAS, bool SPLIT_OUT, bool GROUP_A>
__global__ __launch_bounds__(256) void k_mgemm(
    const u16* __restrict__ Ahi, const u16* __restrict__ Alo,
    const u16* __restrict__ BThi, const u16* __restrict__ BTlo,
    const float* __restrict__ bias,
    float* __restrict__ Cf, u16* __restrict__ Chi, u16* __restrict__ Clo,
    int ldA, int M, int K) {
  __shared__ u16 smem[16384];  // 4 tiles [128 rows][32 k] bf16: Ahi,Alo,Bhi,Blo
  const int tid = threadIdx.x;
  const int w = tid >> 6, lane = tid & 63;
  const int quad = lane >> 4, lc = lane & 15;
  const int wr = w >> 1, wc = w & 1;
  const int bm = blockIdx.x * 128;
  const int ldC = gridDim.y * 128;
  const int cb = blockIdx.y * 128;
  const int aoff = GROUP_A ? blockIdx.y * K : 0;
  const u16* Bhi = BThi + (size_t)blockIdx.y * 128 * K;
  const u16* Blo = BTlo + (size_t)blockIdx.y * 128 * K;
  const int srow = lane >> 2, skoff = (lane & 3) * 8;

  f32x4 acc[4][4] = {};

  for (int k0 = 0; k0 < K; k0 += 32) {
    // stage 32KB: 32 chunks of 1024B (16 rows x 64B), 8 per wave
#pragma unroll
    for (int l = 0; l < 8; l++) {
      int c = w + l * 4;
      int t = c >> 3, r16 = c & 7;
      int rowi = r16 * 16 + srow;
      u16* ldst = smem + t * 4096 + r16 * 512;  // +lane*16B implicit
      const u16* src;
      if (t < 2) {
        int gm = bm + rowi;
        if (gm > M - 1) gm = M - 1;  // clamp; guarded at store
        src = (t == 0 ? Ahi : Alo) + (size_t)gm * ldA + aoff + k0 + skoff;
      } else {
        src = (t == 2 ? Bhi : Blo) + (size_t)rowi * K + k0 + skoff;
      }
      __builtin_amdgcn_global_load_lds(
          (const __attribute__((address_space(1))) void*)src,
          (__attribute__((address_space(3))) void*)ldst, 16, 0, 0);
    }
    __syncthreads();
    short8 bh[4], bl[4];
#pragma unroll
    for (int nt = 0; nt < 4; nt++) {
      int r = wc * 64 + nt * 16 + lc;
      bh[nt] = *(const short8*)(smem + 2 * 4096 + r * 32 + quad * 8);
      bl[nt] = *(const short8*)(smem + 3 * 4096 + r * 32 + quad * 8);
    }
#pragma unroll
    for (int mt = 0; mt < 4; mt++) {
      int r = wr * 64 + mt * 16 + lc;
      short8 ah = *(const short8*)(smem + 0 * 4096 + r * 32 + quad * 8);
      short8 al = *(const short8*)(smem + 1 * 4096 + r * 32 + quad * 8);
#pragma unroll
      for (int nt = 0; nt < 4; nt++) {
        acc[mt][nt] = __builtin_amdgcn_mfma_f32_16x16x32_bf16(ah, bh[nt], acc[mt][nt], 0, 0, 0);
        acc[mt][nt] = __builtin_amdgcn_mfma_f32_16x16x32_bf16(ah, bl[nt], acc[mt][nt], 0, 0, 0);
        acc[mt][nt] = __builtin_amdgcn_mfma_f32_16x16x32_bf16(al, bh[nt], acc[mt][nt], 0, 0, 0);
      }
    }
    __syncthreads();
  }

  float bv[4];
  if (BIAS) {
#pragma unroll
    for (int nt = 0; nt < 4; nt++) bv[nt] = bias[cb + wc * 64 + nt * 16 + lc];
  }
#pragma unroll
  for (int mt = 0; mt < 4; mt++) {
#pragma unroll
    for (int r = 0; r < 4; r++) {
      int gm = bm + wr * 64 + mt * 16 + quad * 4 + r;
      if (gm >= M) continue;
#pragma unroll
      for (int nt = 0; nt < 4; nt++) {
        float v = acc[mt][nt][r];
        if (BIAS) v += bv[nt];
        if (RELU) v = fmaxf(v, 0.f);
        size_t idx = (size_t)gm * ldC + cb + wc * 64 + nt * 16 + lc;
        if (SPLIT_OUT) {
          u16 h = f2bf(v);
          Chi[idx] = h;
          Clo[idx] = f2bf(v - bf2f(h));
        } else {
          Cf[idx] = v;
        }
      }
    }
  }
}

// ---------------- layer-3 aggregation: 896-wide gather, float2 + unroll-4 ----------------
// x4[n,f] = relu(b[f] + dis_i(n)^2*hW[n,f] + sum_p norm_i(p)*hW[src_p,f]), i=f>>7
__global__ __launch_bounds__(448) void k_agg7(const float* __restrict__ hW,
                                              const float* __restrict__ csr_norm,
                                              const float* __restrict__ dis,
                                              const int* __restrict__ rowptr,
                                              const int* __restrict__ csr_src,
                                              const float* __restrict__ bias,
                                              u16* __restrict__ outhi,
                                              u16* __restrict__ outlo) {
  int n = blockIdx.x;
  int f2 = threadIdx.x;   // handles cols 2*f2, 2*f2+1
  int i = f2 >> 6;        // wave-uniform
  const float2* hw2 = (const float2*)hW;
  const float* nrm = csr_norm + (size_t)i * NE;
  float d = dis[i * NN + n];
  float2 sv = hw2[(size_t)n * 448 + f2];
  float ax = d * d * sv.x, ay = d * d * sv.y;
  int s = rowptr[n], e = rowptr[n + 1];
  int p = s;
  for (; p + 4 <= e; p += 4) {
    int s0 = csr_src[p], s1 = csr_src[p + 1], s2 = csr_src[p + 2], s3 = csr_src[p + 3];
    float n0 = nrm[p], n1 = nrm[p + 1], n2 = nrm[p + 2], n3 = nrm[p + 3];
    float2 v0 = hw2[(size_t)s0 * 448 + f2];
    float2 v1 = hw2[(size_t)s1 * 448 + f2];
    float2 v2 = hw2[(size_t)s2 * 448 + f2];
    float2 v3 = hw2[(size_t)s3 * 448 + f2];
    ax = fmaf(n0, v0.x, ax); ay = fmaf(n0, v0.y, ay);
    ax = fmaf(n1, v1.x, ax); ay = fmaf(n1, v1.y, ay);
    ax = fmaf(n2, v2.x, ax); ay = fmaf(n2, v2.y, ay);
    ax = fmaf(n3, v3.x, ax); ay = fmaf(n3, v3.y, ay);
  }
  for (; p < e; p++) {
    int s0 = csr_src[p];
    float n0 = nrm[p];
    float2 v0 = hw2[(size_t)s0 * 448 + f2];
    ax = fmaf(n0, v0.x, ax); ay = fmaf(n0, v0.y, ay);
  }
  float vx = fmaxf(ax + bias[2 * f2], 0.f);
  float vy = fmaxf(ay + bias[2 * f2 + 1], 0.f);
  split_store(vx, outhi, outlo, (size_t)n * 896 + 2 * f2);
  split_store(vy, outhi, outlo, (size_t)n * 896 + 2 * f2 + 1);
}

// ---------------- layer-1 aggregation: 128-wide, fp32 out, bias+relu ----------------
__global__ __launch_bounds__(256) void k_agg1(const float* __restrict__ hW,
                                              const float* __restrict__ nrm,
                                              const float* __restrict__ dis_i,
                                              const int* __restrict__ rowptr,
                                              const int* __restrict__ csr_src,
                                              const float* __restrict__ bias,
                                              float* __restrict__ x2f) {
  int t = threadIdx.x;
  int n = blockIdx.x * 4 + (t >> 6);
  int f2 = t & 63;
  if (n >= NN) return;
  const float2* hw2 = (const float2*)hW;
  float d = dis_i[n];
  float2 sv = hw2[(size_t)n * 64 + f2];
  float ax = d * d * sv.x, ay = d * d * sv.y;
  int s = rowptr[n], e = rowptr[n + 1];
  int p = s;
  for (; p + 4 <= e; p += 4) {
    int s0 = csr_src[p], s1 = csr_src[p + 1], s2 = csr_src[p + 2], s3 = csr_src[p + 3];
    float n0 = nrm[p], n1 = nrm[p + 1], n2 = nrm[p + 2], n3 = nrm[p + 3];
    float2 v0 = hw2[(size_t)s0 * 64 + f2];
    float2 v1 = hw2[(size_t)s1 * 64 + f2];
    float2 v2 = hw2[(size_t)s2 * 64 + f2];
    float2 v3 = hw2[(size_t)s3 * 64 + f2];
    ax = fmaf(n0, v0.x, ax); ay = fmaf(n0, v0.y, ay);
    ax = fmaf(n1, v1.x, ax); ay = fmaf(n1, v1.y, ay);
    ax = fmaf(n2, v2.x, ax); ay = fmaf(n2, v2.y, ay);
    ax = fmaf(n3, v3.x, ax); ay = fmaf(n3, v3.y, ay);
  }
  for (; p < e; p++) {
    int s0 = csr_src[p];
    float n0 = nrm[p];
    float2 v0 = hw2[(size_t)s0 * 64 + f2];
    ax = fmaf(n0, v0.x, ax); ay = fmaf(n0, v0.y, ay);
  }
  x2f[(size_t)n * 128 + 2 * f2] = fmaxf(ax + bias[2 * f2], 0.f);
  x2f[(size_t)n * 128 + 2 * f2 + 1] = fmaxf(ay + bias[2 * f2 + 1], 0.f);
}

// ---------------- layer-2 aggregate-first: gather x2 once, 7 norms ----------------
// xagg2[n, i*128+c] = dis_i^2*x2[n,c] + sum_p norm_i(p)*x2[src_p,c]  (hi/lo bf16 out)
__global__ __launch_bounds__(256) void k_agg2(const float* __restrict__ x2f,
                                              const float* __restrict__ csr_norm,
                                              const float* __restrict__ dis,
                                              const int* __restrict__ rowptr,
                                              const int* __restrict__ csr_src,
                                              u16* __restrict__ ohi,
                                              u16* __restrict__ olo) {
  int t = threadIdx.x;
  int n = blockIdx.x * 4 + (t >> 6);
  int f2 = t & 63;
  if (n >= NN) return;
  const float2* x2 = (const float2*)x2f;
  float2 sv = x2[(size_t)n * 64 + f2];
  float ax[7], ay[7];
#pragma unroll
  for (int i = 0; i < 7; i++) {
    float d = dis[i * NN + n];
    ax[i] = d * d * sv.x;
    ay[i] = d * d * sv.y;
  }
  int s = rowptr[n], e = rowptr[n + 1];
  int p = s;
  for (; p + 2 <= e; p += 2) {
    int s0 = csr_src[p], s1 = csr_src[p + 1];
    float2 v0 = x2[(size_t)s0 * 64 + f2];
    float2 v1 = x2[(size_t)s1 * 64 + f2];
#pragma unroll
    for (int i = 0; i < 7; i++) {
      float n0 = csr_norm[(size_t)i * NE + p];
      float n1 = csr_norm[(size_t)i * NE + p + 1];
      ax[i] = fmaf(n0, v0.x, ax[i]); ay[i] = fmaf(n0, v0.y, ay[i]);
      ax[i] = fmaf(n1, v1.x, ax[i]); ay[i] = fmaf(n1, v1.y, ay[i]);
    }
  }
  for (; p < e; p++) {
    int s0 = csr_src[p];
    float2 v0 = x2[(size_t)s0 * 64 + f2];
#pragma unroll
    for (int i = 0; i < 7; i++) {
      float n0 = csr_norm[(size_t)i * NE + p];
      ax[i] = fmaf(n0, v0.x, ax[i]); ay[i] = fmaf(n0, v0.y, ay[i]);
    }
  }
#pragma unroll
  for (int i = 0; i < 7; i++) {
    split_store(ax[i], ohi, olo, (size_t)n * 896 + i * 128 + 2 * f2);
    split_store(ay[i], ohi, olo, (size_t)n * 896 + i * 128 + 2 * f2 + 1);
  }
}

// ---------------- layer 0: aggregate-first (x is only [N,8]) ----------------
__global__ __launch_bounds__(64) void k_agg_x(const float* __restrict__ x,
                                              const float* __restrict__ csr_norm,
                                              const float* __restrict__ dis,
                                              const int* __restrict__ rowptr,
                                              const int* __restrict__ csr_src,
                                              float* __restrict__ xagg) {
  int n = blockIdx.x;
  int f = threadIdx.x;
  if (f >= 56) return;
  int i = f >> 3, c = f & 7;
  float d = dis[i * NN + n];
  float acc = d * d * x[(size_t)n * 8 + c];
  int s = rowptr[n], e = rowptr[n + 1];
  for (int p = s; p < e; p++)
    acc = fmaf(csr_norm[i * NE + p], x[(size_t)csr_src[p] * 8 + c], acc);
  xagg[(size_t)n * 56 + f] = acc;
}

// x1[n, i*128+h] = relu(b0[i][h] + sum_c xagg[n][i*8+c] * W0[i][c][h]), hi/lo out
__global__ __launch_bounds__(896) void k_gemm0(const float* __restrict__ xagg,
                                               const float* __restrict__ W0,
                                               const float* __restrict__ b0,
                                               u16* __restrict__ outhi,
                                               u16* __restrict__ outlo) {
  int n = blockIdx.x;
  int f = threadIdx.x;
  int i = f >> 7, h = f & 127;
  float s = b0[i * 128 + h];
#pragma unroll
  for (int c = 0; c < 8; c++)
    s = fmaf(xagg[(size_t)n * 56 + i * 8 + c], W0[(i * 8 + c) * 128 + h], s);
  float v = fmaxf(s, 0.f);
  split_store(v, outhi, outlo, (size_t)n * 896 + f);
}

// ---------------- link MLP ----------------
__global__ __launch_bounds__(128) void k_link_gather(const float* __restrict__ UV,
                                                     const int* __restrict__ eit,
                                                     const float* __restrict__ lb0,
                                                     u16* __restrict__ Hhi,
                                                     u16* __restrict__ Hlo) {
  int t = blockIdx.x;
  int f = threadIdx.x;
  int s = eit[t], d = eit[NT + t];
  float b = lb0[f];
  float v1 = fmaxf(UV[(size_t)s * 256 + f] + UV[(size_t)d * 256 + 128 + f] + b, 0.f);
  float v2 = fmaxf(UV[(size_t)d * 256 + f] + UV[(size_t)s * 256 + 128 + f] + b, 0.f);
  split_store(v1, Hhi, Hlo, (size_t)t * 128 + f);
  split_store(v2, Hhi, Hlo, (size_t)(NT + t) * 128 + f);
}

__global__ void k_link_out(const u16* __restrict__ Hhi, const u16* __restrict__ Hlo,
                           const float* __restrict__ lw4, const float* __restrict__ lb4,
                           float* __restrict__ out) {
  int t = blockIdx.x * 256 + threadIdx.x;
  if (t >= NT) return;
  float o1[4] = {lb4[0], lb4[1], lb4[2], lb4[3]};
  float o2[4] = {o1[0], o1[1], o1[2], o1[3]};
  for (int k = 0; k < 128; k++) {
    size_t i1 = (size_t)t * 128 + k, i2 = (size_t)(NT + t) * 128 + k;
    float h1 = bf2f(Hhi[i1]) + bf2f(Hlo[i1]);
    float h2 = bf2f(Hhi[i2]) + bf2f(Hlo[i2]);
#pragma unroll
    for (int j = 0; j < 4; j++) {
      float w = lw4[k * 4 + j];
      o1[j] = fmaf(h1, w, o1[j]);
      o2[j] = fmaf(h2, w, o2[j]);
    }
  }
  out[t * 4 + 0] = 0.5f * (o1[0] + o2[0]);
  out[t * 4 + 1] = 0.5f * (o1[1] + o2[2]);
  out[t * 4 + 2] = 0.5f * (o1[2] + o2[1]);
  out[t * 4 + 3] = 0.5f * (o1[3] + o2[3]);
}

// ---------------- host ----------------
extern "C" void kernel_launch(void* const* d_in, const int* in_sizes, int n_in,
                              void* d_out, int out_size, void* d_ws, size_t ws_size,
                              hipStream_t stream) {
  const float* x   = (const float*)d_in[0];
  const int*   ei  = (const int*)d_in[1];
  const float* ea  = (const float*)d_in[2];
  const int*   eit = (const int*)d_in[3];
  const float* W0  = (const float*)d_in[4];
  const float* b0  = (const float*)d_in[5];
  const float* W1  = (const float*)d_in[6];
  const float* b1  = (const float*)d_in[7];
  const float* W2  = (const float*)d_in[8];
  const float* b2  = (const float*)d_in[9];
  const float* W3  = (const float*)d_in[10];
  const float* b3  = (const float*)d_in[11];
  const float* ew1 = (const float*)d_in[12];
  const float* eb1 = (const float*)d_in[13];
  const float* ew2 = (const float*)d_in[14];
  const float* eb2 = (const float*)d_in[15];
  const float* ew3 = (const float*)d_in[16];
  const float* eb3 = (const float*)d_in[17];
  const float* lw0 = (const float*)d_in[18];
  const float* lb0 = (const float*)d_in[19];
  const float* lwh = (const float*)d_in[20];
  const float* lbh = (const float*)d_in[21];
  const float* lw4 = (const float*)d_in[22];
  const float* lb4 = (const float*)d_in[23];
  const int* row = ei;
  const int* col = ei + NE;
  float* out = (float*)d_out;

  char* ws = (char*)d_ws;
  size_t off = 0;
  auto alloc = [&](size_t bytes) -> char* {
    char* p = ws + off;
    off += (bytes + 255) & ~(size_t)255;
    return p;
  };
  // xA hi/lo: x1 -> x3 -> x4. xB: hW1 -> xagg2 hi/lo -> hW3 -> H overlay.
  // [xB | x2f] = 71.68 + 10.24 = 81.92 MB exactly holds the 4 link H planes.
  u16*   xAhi   = (u16*)alloc((size_t)NN * 896 * 2);
  u16*   xAlo   = (u16*)alloc((size_t)NN * 896 * 2);
  float* xB     = (float*)alloc((size_t)NN * 896 * 4);
  float* x2f    = (float*)alloc((size_t)NN * 128 * 4);
  float* UV     = (float*)alloc((size_t)NN * 256 * 4);  // xagg overlays front
  float* csr_nrm= (float*)alloc((size_t)8 * NE * 4);
  float* dis    = (float*)alloc((size_t)8 * NN * 4);
  float* ewb    = (float*)alloc((size_t)NE * 4);
  int*   rowptr = (int*)alloc((size_t)(NN + 1) * 4);
  int*   cursor = (int*)alloc((size_t)NN * 4);
  int*   eid    = (int*)alloc((size_t)NE * 4);
  int*   csr_src= (int*)alloc((size_t)NE * 4);
  u16* w1thi  = (u16*)alloc((size_t)128 * 896 * 2);
  u16* w1tlo  = (u16*)alloc((size_t)128 * 896 * 2);
  u16* w2thi  = (u16*)alloc((size_t)7 * 128 * 128 * 2);
  u16* w2tlo  = (u16*)alloc((size_t)7 * 128 * 128 * 2);
  u16* w3thi  = (u16*)alloc((size_t)7 * 128 * 896 * 2);
  u16* w3tlo  = (u16*)alloc((size_t)7 * 128 * 896 * 2);
  u16* lw0thi = (u16*)alloc((size_t)2 * 128 * 896 * 2);
  u16* lw0tlo = (u16*)alloc((size_t)2 * 128 * 896 * 2);
  u16* lwhthi = (u16*)alloc((size_t)3 * 128 * 128 * 2);
  u16* lwhtlo = (u16*)alloc((size_t)3 * 128 * 128 * 2);
  float* xagg = UV;  // [NN][56] fp32, dead before UV written
  (void)ws_size; (void)in_sizes; (void)n_in; (void)out_size;

  const int EB = (NE + 255) / 256;
  const int NB = (NN + 255) / 256;
  const int GX = (NN + 127) / 128;  // 157

  // weight prep (independent)
  k_wprep<<<dim3(448, 1), 256, 0, stream>>>(W1, 128, 0, 896, w1thi, w1tlo);
  k_wprep<<<dim3(64, 7), 256, 0, stream>>>(W2, 128, (size_t)128 * 128, 128, w2thi, w2tlo);
  k_wprep<<<dim3(448, 7), 256, 0, stream>>>(W3, 128, (size_t)896 * 128, 896, w3thi, w3tlo);
  // lw0 is [1792][128]: U = rows 0..895, V = rows 896..1791
  k_wprep<<<dim3(448, 2), 256, 0, stream>>>(lw0, 128, (size_t)896 * 128, 896, lw0thi, lw0tlo);
  k_wprep<<<dim3(64, 3), 256, 0, stream>>>(lwh, 128, (size_t)128 * 128, 128, lwhthi, lwhtlo);

  // edge weight + CSR + degrees + norms
  k_edge_mlp<<<EB, 256, 0, stream>>>(ea, ew1, eb1, ew2, eb2, ew3, eb3, ewb);
  hipMemsetAsync(cursor, 0, (size_t)NN * 4, stream);
  k_count<<<EB, 256, 0, stream>>>(col, cursor);
  k_scan<<<1, 256, 0, stream>>>(cursor, rowptr);
  k_copy_i32<<<NB, 256, 0, stream>>>(rowptr, cursor, NN);
  k_fill_csr<<<EB, 256, 0, stream>>>(col, cursor, eid);
  k_deg_csr<<<(NN + 7) / 8, 64, 0, stream>>>(rowptr, eid, ea, ewb, dis);
  k_csr_norms<<<EB, 256, 0, stream>>>(eid, row, col, ea, ewb, dis, csr_src, csr_nrm);

  // Layer 0 (aggregate-first): xagg [N,7,8] -> x1 hi/lo (xA)
  k_agg_x<<<NN, 64, 0, stream>>>(x, csr_nrm, dis, rowptr, csr_src, xagg);
  k_gemm0<<<NN, 896, 0, stream>>>(xagg, W0, b0, xAhi, xAlo);

  // Layer 1: x1 @ W1 -> hW1 fp32 (xB); agg1 (learned ew, bias+relu) -> x2f
  k_mgemm<false, false, false, false><<<dim3(GX, 1), 256, 0, stream>>>(
      xAhi, xAlo, w1thi, w1tlo, nullptr, xB, nullptr, nullptr, 896, NN, 896);
  k_agg1<<<(NN + 3) / 4, 256, 0, stream>>>(xB, csr_nrm + (size_t)7 * NE,
                                           dis + (size_t)7 * NN, rowptr, csr_src, b1, x2f);

  // Layer 2 (aggregate-first): xagg2 = A_i * x2 (7 relations, hi/lo into xB),
  // then x3 = relu(xagg2_i @ W2_i + b2_i) via GROUP_A GEMM -> xA hi/lo
  u16* xagg2hi = (u16*)xB;
  u16* xagg2lo = xagg2hi + (size_t)NN * 896;
  k_agg2<<<(NN + 3) / 4, 256, 0, stream>>>(x2f, csr_nrm, dis, rowptr, csr_src,
                                           xagg2hi, xagg2lo);
  k_mgemm<true, true, true, true><<<dim3(GX, 7), 256, 0, stream>>>(
      xagg2hi, xagg2lo, w2thi, w2tlo, b2, nullptr, xAhi, xAlo, 896, NN, 128);

  // Layer 3: x3 @ W3 (7 mats, K=896) -> hW3 fp32 (xB; xagg2 dead); agg7 -> x4 hi/lo (xA)
  k_mgemm<false, false, false, false><<<dim3(GX, 7), 256, 0, stream>>>(
      xAhi, xAlo, w3thi, w3tlo, nullptr, xB, nullptr, nullptr, 896, NN, 896);
  k_agg7<<<NN, 448, 0, stream>>>(xB, csr_nrm, dis, rowptr, csr_src, b3, xAhi, xAlo);

  // Link precompute: UV = x4 @ [lw0_top | lw0_bot]
  k_mgemm<false, false, false, false><<<dim3(GX, 2), 256, 0, stream>>>(
      xAhi, xAlo, lw0thi, lw0tlo, nullptr, UV, nullptr, nullptr, 896, NN, 896);

  // H overlay on [xB | x2f]: 4 planes of 2NT*128 u16 = 81.92MB
  u16* Hahi = (u16*)xB;
  u16* Halo = Hahi + (size_t)2 * NT * 128;
  u16* Hbhi = Halo + (size_t)2 * NT * 128;
  u16* Hblo = Hbhi + (size_t)2 * NT * 128;
  k_link_gather<<<NT, 128, 0, stream>>>(UV, eit, lb0, Hahi, Halo);
  const int LGX = (2 * NT + 127) / 128;  // 625
  for (int i = 0; i < 3; i++) {
    const u16* whi = lwhthi + (size_t)i * 128 * 128;
    const u16* wlo = lwhtlo + (size_t)i * 128 * 128;
    const float* bb = lbh + (size_t)i * 128;
    u16* shi = (i % 2 == 0) ? Hahi : Hbhi;
    u16* slo = (i % 2 == 0) ? Halo : Hblo;
    u16* dhi = (i % 2 == 0) ? Hbhi : Hahi;
    u16* dlo = (i % 2 == 0) ? Hblo : Halo;
    k_mgemm<true, true, true, false><<<dim3(LGX, 1), 256, 0, stream>>>(
        shi, slo, whi, wlo, bb, nullptr, dhi, dlo, 128, 2 * NT, 128);
  }
  // after 3 ping-pongs final state is Hb
  k_link_out<<<(NT + 255) / 256, 256, 0, stream>>>(Hbhi, Hblo, lw4, lb4, out);
}

// Round 6
// 750.248 us; speedup vs baseline: 4.9825x; 1.1019x over previous
//
#include <hip/hip_runtime.h>
#include <math.h>

#define NN 20000
#define NE 200000
#define NT 40000

typedef unsigned short u16;
typedef _Float16 f16;
typedef __attribute__((ext_vector_type(8))) short short8;
typedef __attribute__((ext_vector_type(4))) float f32x4;
typedef __attribute__((ext_vector_type(2))) _Float16 h2;

__device__ __forceinline__ u16 f2bf(float x) {
  unsigned int u = __float_as_uint(x);
  u += 0x7FFF + ((u >> 16) & 1);  // RNE
  return (u16)(u >> 16);
}
__device__ __forceinline__ float bf2f(u16 h) {
  return __uint_as_float((unsigned int)h << 16);
}
__device__ __forceinline__ void split_store(float v, u16* hi, u16* lo, size_t idx) {
  u16 h = f2bf(v);
  hi[idx] = h;
  lo[idx] = f2bf(v - bf2f(h));
}

// ---------------- edge weight MLP ----------------
__global__ void k_edge_mlp(const float* __restrict__ ea,
                           const float* __restrict__ w1, const float* __restrict__ b1,
                           const float* __restrict__ w2, const float* __restrict__ b2,
                           const float* __restrict__ w3, const float* __restrict__ b3,
                           float* __restrict__ out) {
  int e = blockIdx.x * 256 + threadIdx.x;
  if (e >= NE) return;
  float a[7];
#pragma unroll
  for (int i = 0; i < 7; i++) a[i] = ea[e * 7 + i];
  float t1[28];
#pragma unroll
  for (int j = 0; j < 28; j++) {
    float s = b1[j];
#pragma unroll
    for (int k = 0; k < 7; k++) s = fmaf(a[k], w1[k * 28 + j], s);
    t1[j] = fmaxf(s, 0.f);
  }
  float t2[28];
  for (int j = 0; j < 28; j++) {
    float s = b2[j];
    for (int k = 0; k < 28; k++) s = fmaf(t1[k], w2[k * 28 + j], s);
    t2[j] = fmaxf(s, 0.f);
  }
  float s = b3[0];
  for (int k = 0; k < 28; k++) s = fmaf(t2[k], w3[k], s);
  out[e] = 1.f / (1.f + expf(-s));
}

// ---------------- CSR build ----------------
__global__ void k_count(const int* __restrict__ col, int* __restrict__ cnt) {
  int e = blockIdx.x * 256 + threadIdx.x;
  if (e < NE) atomicAdd(&cnt[col[e]], 1);
}

__global__ void k_scan(const int* __restrict__ cnt, int* __restrict__ rowptr) {
  __shared__ int sums[256];
  __shared__ int offs[256];
  int t = threadIdx.x;
  const int CH = (NN + 255) / 256;
  int base = t * CH;
  int s = 0;
  for (int i = 0; i < CH; i++) { int idx = base + i; if (idx < NN) s += cnt[idx]; }
  sums[t] = s;
  __syncthreads();
  if (t == 0) {
    int acc = 0;
    for (int i = 0; i < 256; i++) { offs[i] = acc; acc += sums[i]; }
    rowptr[NN] = acc;
  }
  __syncthreads();
  int acc = offs[t];
  for (int i = 0; i < CH; i++) {
    int idx = base + i;
    if (idx < NN) { rowptr[idx] = acc; acc += cnt[idx]; }
  }
}

__global__ void k_copy_i32(const int* __restrict__ src, int* __restrict__ dst, int n) {
  int i = blockIdx.x * 256 + threadIdx.x;
  if (i < n) dst[i] = src[i];
}

__global__ void k_fill_csr(const int* __restrict__ col, int* __restrict__ cursor,
                           int* __restrict__ eid) {
  int e = blockIdx.x * 256 + threadIdx.x;
  if (e >= NE) return;
  int pos = atomicAdd(&cursor[col[e]], 1);
  eid[pos] = e;
}

// degrees from CSR (no float atomics). 8 nodes x 8 relations per 64-thread block.
__global__ __launch_bounds__(64) void k_deg_csr(const int* __restrict__ rowptr,
                                                const int* __restrict__ eid,
                                                const float* __restrict__ ea,
                                                const float* __restrict__ ewb,
                                                float* __restrict__ dis) {
  int t = threadIdx.x;
  int n = blockIdx.x * 8 + (t >> 3);
  int i = t & 7;
  if (n >= NN) return;
  float deg = 1.f;  // self-loop weight
  int s = rowptr[n], e2 = rowptr[n + 1];
  for (int p = s; p < e2; p++) {
    int e = eid[p];
    deg += (i < 7) ? ea[e * 7 + i] : ewb[e];
  }
  dis[i * NN + n] = rsqrtf(deg);  // deg >= 1 always
}

__global__ void k_csr_norms(const int* __restrict__ eid, const int* __restrict__ row,
                            const int* __restrict__ col, const float* __restrict__ ea,
                            const float* __restrict__ ew, const float* __restrict__ dis,
                            int* __restrict__ csr_src, float* __restrict__ csr_norm) {
  int p = blockIdx.x * 256 + threadIdx.x;
  if (p >= NE) return;
  int e = eid[p];
  int r = row[e], c = col[e];
  csr_src[p] = r;
#pragma unroll
  for (int i = 0; i < 7; i++)
    csr_norm[i * NE + p] = dis[i * NN + r] * ea[e * 7 + i] * dis[i * NN + c];
  csr_norm[7 * NE + p] = dis[7 * NN + r] * ew[e] * dis[7 * NN + c];
}

// ---------------- weight prep: transpose + bf16 hi/lo split ----------------
__global__ void k_wprep(const float* __restrict__ W, int ldW, size_t matOff, int K,
                        u16* __restrict__ WThi, u16* __restrict__ WTlo) {
  int g = blockIdx.y;
  int idx = blockIdx.x * 256 + threadIdx.x;
  if (idx >= K * 128) return;
  int k = idx >> 7, n = idx & 127;
  float v = W[(size_t)g * matOff + (size_t)k * ldW + n];
  size_t o = (size_t)g * 128 * K + (size_t)n * K + k;
  split_store(v, WThi, WTlo, o);
}

// ---------------- split-bf16 MFMA GEMM ----------------
// OUTM: 0 = fp32, 1 = bf16 hi/lo split, 2 = fp16.
// If SWIZZLE: 1-D grid, XCD-aware decode — all NG column-groups of one
// 128-row A-panel run consecutively on the same XCD (b&7) so the panel
// stays L2-resident (A fetched ~once instead of NG times). Heuristic only;
// wrong mapping costs speed, never correctness.
template <int OUTM, bool RELU, bool BIAS, bool GROUP_A, bool SWIZZLE>
__global__ __launch_bounds__(256) void k_mgemm(
    const u16* __restrict__ Ahi, const u16* __restrict__ Alo,
    const u16* __restrict__ BThi, const u16* __restrict__ BTlo,
    const float* __restrict__ bias,
    float* __restrict__ Cf, u16* __restrict__ Chi, u16* __restrict__ Clo,
    f16* __restrict__ Ch,
    int ldA, int M, int K, int NG, int GXp) {
  int rowT, g;
  if (SWIZZLE) {
    int b = blockIdx.x;
    int xcd = b & 7, s = b >> 3;
    g = s % NG;
    int lr = s / NG;
    rowT = lr * 8 + xcd;
    if (rowT >= GXp) return;  // uniform early-out (padded grid)
  } else {
    rowT = blockIdx.x;
    g = blockIdx.y;
  }
  __shared__ u16 smem[16384];  // 4 tiles [128 rows][32 k] bf16: Ahi,Alo,Bhi,Blo
  const int tid = threadIdx.x;
  const int w = tid >> 6, lane = tid & 63;
  const int quad = lane >> 4, lc = lane & 15;
  const int wr = w >> 1, wc = w & 1;
  const int bm = rowT * 128;
  const int ldC = NG * 128;
  const int cb = g * 128;
  const int aoff = GROUP_A ? g * K : 0;
  const u16* Bhi = BThi + (size_t)g * 128 * K;
  const u16* Blo = BTlo + (size_t)g * 128 * K;
  const int srow = lane >> 2, skoff = (lane & 3) * 8;

  f32x4 acc[4][4] = {};

  for (int k0 = 0; k0 < K; k0 += 32) {
    // stage 32KB: 32 chunks of 1024B (16 rows x 64B), 8 per wave
#pragma unroll
    for (int l = 0; l < 8; l++) {
      int c = w + l * 4;
      int t = c >> 3, r16 = c & 7;
      int rowi = r16 * 16 + srow;
      u16* ldst = smem + t * 4096 + r16 * 512;  // +lane*16B implicit
      const u16* src;
      if (t < 2) {
        int gm = bm + rowi;
        if (gm > M - 1) gm = M - 1;  // clamp; guarded at store
        src = (t == 0 ? Ahi : Alo) + (size_t)gm * ldA + aoff + k0 + skoff;
      } else {
        src = (t == 2 ? Bhi : Blo) + (size_t)rowi * K + k0 + skoff;
      }
      __builtin_amdgcn_global_load_lds(
          (const __attribute__((address_space(1))) void*)src,
          (__attribute__((address_space(3))) void*)ldst, 16, 0, 0);
    }
    __syncthreads();
    short8 bh[4], bl[4];
#pragma unroll
    for (int nt = 0; nt < 4; nt++) {
      int r = wc * 64 + nt * 16 + lc;
      bh[nt] = *(const short8*)(smem + 2 * 4096 + r * 32 + quad * 8);
      bl[nt] = *(const short8*)(smem + 3 * 4096 + r * 32 + quad * 8);
    }
#pragma unroll
    for (int mt = 0; mt < 4; mt++) {
      int r = wr * 64 + mt * 16 + lc;
      short8 ah = *(const short8*)(smem + 0 * 4096 + r * 32 + quad * 8);
      short8 al = *(const short8*)(smem + 1 * 4096 + r * 32 + quad * 8);
#pragma unroll
      for (int nt = 0; nt < 4; nt++) {
        acc[mt][nt] = __builtin_amdgcn_mfma_f32_16x16x32_bf16(ah, bh[nt], acc[mt][nt], 0, 0, 0);
        acc[mt][nt] = __builtin_amdgcn_mfma_f32_16x16x32_bf16(ah, bl[nt], acc[mt][nt], 0, 0, 0);
        acc[mt][nt] = __builtin_amdgcn_mfma_f32_16x16x32_bf16(al, bh[nt], acc[mt][nt], 0, 0, 0);
      }
    }
    __syncthreads();
  }

  float bv[4];
  if (BIAS) {
#pragma unroll
    for (int nt = 0; nt < 4; nt++) bv[nt] = bias[cb + wc * 64 + nt * 16 + lc];
  }
#pragma unroll
  for (int mt = 0; mt < 4; mt++) {
#pragma unroll
    for (int r = 0; r < 4; r++) {
      int gm = bm + wr * 64 + mt * 16 + quad * 4 + r;
      if (gm >= M) continue;
#pragma unroll
      for (int nt = 0; nt < 4; nt++) {
        float v = acc[mt][nt][r];
        if (BIAS) v += bv[nt];
        if (RELU) v = fmaxf(v, 0.f);
        size_t idx = (size_t)gm * ldC + cb + wc * 64 + nt * 16 + lc;
        if (OUTM == 1) {
          u16 h = f2bf(v);
          Chi[idx] = h;
          Clo[idx] = f2bf(v - bf2f(h));
        } else if (OUTM == 2) {
          Ch[idx] = (f16)v;
        } else {
          Cf[idx] = v;
        }
      }
    }
  }
}

// ---------------- layer-3 aggregation: fp16 gather, half2 + unroll-4 ----------------
// x4[n,f] = relu(b[f] + dis_i(n)^2*hW[n,f] + sum_p norm_i(p)*hW[src_p,f]), i=f>>7
__global__ __launch_bounds__(448) void k_agg7(const f16* __restrict__ hW,
                                              const float* __restrict__ csr_norm,
                                              const float* __restrict__ dis,
                                              const int* __restrict__ rowptr,
                                              const int* __restrict__ csr_src,
                                              const float* __restrict__ bias,
                                              u16* __restrict__ outhi,
                                              u16* __restrict__ outlo) {
  int n = blockIdx.x;
  int f2 = threadIdx.x;   // handles cols 2*f2, 2*f2+1
  int i = f2 >> 6;        // wave-uniform
  const h2* hw2 = (const h2*)hW;
  const float* nrm = csr_norm + (size_t)i * NE;
  float d = dis[i * NN + n];
  h2 sv = hw2[(size_t)n * 448 + f2];
  float ax = d * d * (float)sv.x, ay = d * d * (float)sv.y;
  int s = rowptr[n], e = rowptr[n + 1];
  int p = s;
  for (; p + 4 <= e; p += 4) {
    int s0 = csr_src[p], s1 = csr_src[p + 1], s2 = csr_src[p + 2], s3 = csr_src[p + 3];
    float n0 = nrm[p], n1 = nrm[p + 1], n2 = nrm[p + 2], n3 = nrm[p + 3];
    h2 v0 = hw2[(size_t)s0 * 448 + f2];
    h2 v1 = hw2[(size_t)s1 * 448 + f2];
    h2 v2 = hw2[(size_t)s2 * 448 + f2];
    h2 v3 = hw2[(size_t)s3 * 448 + f2];
    ax = fmaf(n0, (float)v0.x, ax); ay = fmaf(n0, (float)v0.y, ay);
    ax = fmaf(n1, (float)v1.x, ax); ay = fmaf(n1, (float)v1.y, ay);
    ax = fmaf(n2, (float)v2.x, ax); ay = fmaf(n2, (float)v2.y, ay);
    ax = fmaf(n3, (float)v3.x, ax); ay = fmaf(n3, (float)v3.y, ay);
  }
  for (; p < e; p++) {
    int s0 = csr_src[p];
    float n0 = nrm[p];
    h2 v0 = hw2[(size_t)s0 * 448 + f2];
    ax = fmaf(n0, (float)v0.x, ax); ay = fmaf(n0, (float)v0.y, ay);
  }
  float vx = fmaxf(ax + bias[2 * f2], 0.f);
  float vy = fmaxf(ay + bias[2 * f2 + 1], 0.f);
  split_store(vx, outhi, outlo, (size_t)n * 896 + 2 * f2);
  split_store(vy, outhi, outlo, (size_t)n * 896 + 2 * f2 + 1);
}

// ---------------- layer-1 aggregation: fp16 gather, fp32 out, bias+relu ----------------
__global__ __launch_bounds__(256) void k_agg1(const f16* __restrict__ hW,
                                              const float* __restrict__ nrm,
                                              const float* __restrict__ dis_i,
                                              const int* __restrict__ rowptr,
                                              const int* __restrict__ csr_src,
                                              const float* __restrict__ bias,
                                              float* __restrict__ x2f) {
  int t = threadIdx.x;
  int n = blockIdx.x * 4 + (t >> 6);
  int f2 = t & 63;
  if (n >= NN) return;
  const h2* hw2 = (const h2*)hW;
  float d = dis_i[n];
  h2 sv = hw2[(size_t)n * 64 + f2];
  float ax = d * d * (float)sv.x, ay = d * d * (float)sv.y;
  int s = rowptr[n], e = rowptr[n + 1];
  int p = s;
  for (; p + 4 <= e; p += 4) {
    int s0 = csr_src[p], s1 = csr_src[p + 1], s2 = csr_src[p + 2], s3 = csr_src[p + 3];
    float n0 = nrm[p], n1 = nrm[p + 1], n2 = nrm[p + 2], n3 = nrm[p + 3];
    h2 v0 = hw2[(size_t)s0 * 64 + f2];
    h2 v1 = hw2[(size_t)s1 * 64 + f2];
    h2 v2 = hw2[(size_t)s2 * 64 + f2];
    h2 v3 = hw2[(size_t)s3 * 64 + f2];
    ax = fmaf(n0, (float)v0.x, ax); ay = fmaf(n0, (float)v0.y, ay);
    ax = fmaf(n1, (float)v1.x, ax); ay = fmaf(n1, (float)v1.y, ay);
    ax = fmaf(n2, (float)v2.x, ax); ay = fmaf(n2, (float)v2.y, ay);
    ax = fmaf(n3, (float)v3.x, ax); ay = fmaf(n3, (float)v3.y, ay);
  }
  for (; p < e; p++) {
    int s0 = csr_src[p];
    float n0 = nrm[p];
    h2 v0 = hw2[(size_t)s0 * 64 + f2];
    ax = fmaf(n0, (float)v0.x, ax); ay = fmaf(n0, (float)v0.y, ay);
  }
  x2f[(size_t)n * 128 + 2 * f2] = fmaxf(ax + bias[2 * f2], 0.f);
  x2f[(size_t)n * 128 + 2 * f2 + 1] = fmaxf(ay + bias[2 * f2 + 1], 0.f);
}

// ---------------- layer-2 aggregate-first: gather x2 once, 7 norms ----------------
__global__ __launch_bounds__(256) void k_agg2(const float* __restrict__ x2f,
                                              const float* __restrict__ csr_norm,
                                              const float* __restrict__ dis,
                                              const int* __restrict__ rowptr,
                                              const int* __restrict__ csr_src,
                                              u16* __restrict__ ohi,
                                              u16* __restrict__ olo) {
  int t = threadIdx.x;
  int n = blockIdx.x * 4 + (t >> 6);
  int f2 = t & 63;
  if (n >= NN) return;
  const float2* x2 = (const float2*)x2f;
  float2 sv = x2[(size_t)n * 64 + f2];
  float ax[7], ay[7];
#pragma unroll
  for (int i = 0; i < 7; i++) {
    float d = dis[i * NN + n];
    ax[i] = d * d * sv.x;
    ay[i] = d * d * sv.y;
  }
  int s = rowptr[n], e = rowptr[n + 1];
  int p = s;
  for (; p + 2 <= e; p += 2) {
    int s0 = csr_src[p], s1 = csr_src[p + 1];
    float2 v0 = x2[(size_t)s0 * 64 + f2];
    float2 v1 = x2[(size_t)s1 * 64 + f2];
#pragma unroll
    for (int i = 0; i < 7; i++) {
      float n0 = csr_norm[(size_t)i * NE + p];
      float n1 = csr_norm[(size_t)i * NE + p + 1];
      ax[i] = fmaf(n0, v0.x, ax[i]); ay[i] = fmaf(n0, v0.y, ay[i]);
      ax[i] = fmaf(n1, v1.x, ax[i]); ay[i] = fmaf(n1, v1.y, ay[i]);
    }
  }
  for (; p < e; p++) {
    int s0 = csr_src[p];
    float2 v0 = x2[(size_t)s0 * 64 + f2];
#pragma unroll
    for (int i = 0; i < 7; i++) {
      float n0 = csr_norm[(size_t)i * NE + p];
      ax[i] = fmaf(n0, v0.x, ax[i]); ay[i] = fmaf(n0, v0.y, ay[i]);
    }
  }
#pragma unroll
  for (int i = 0; i < 7; i++) {
    split_store(ax[i], ohi, olo, (size_t)n * 896 + i * 128 + 2 * f2);
    split_store(ay[i], ohi, olo, (size_t)n * 896 + i * 128 + 2 * f2 + 1);
  }
}

// ---------------- layer 0: aggregate-first (x is only [N,8]) ----------------
__global__ __launch_bounds__(64) void k_agg_x(const float* __restrict__ x,
                                              const float* __restrict__ csr_norm,
                                              const float* __restrict__ dis,
                                              const int* __restrict__ rowptr,
                                              const int* __restrict__ csr_src,
                                              float* __restrict__ xagg) {
  int n = blockIdx.x;
  int f = threadIdx.x;
  if (f >= 56) return;
  int i = f >> 3, c = f & 7;
  float d = dis[i * NN + n];
  float acc = d * d * x[(size_t)n * 8 + c];
  int s = rowptr[n], e = rowptr[n + 1];
  for (int p = s; p < e; p++)
    acc = fmaf(csr_norm[i * NE + p], x[(size_t)csr_src[p] * 8 + c], acc);
  xagg[(size_t)n * 56 + f] = acc;
}

// x1[n, i*128+h] = relu(b0[i][h] + sum_c xagg[n][i*8+c] * W0[i][c][h]), hi/lo out
__global__ __launch_bounds__(896) void k_gemm0(const float* __restrict__ xagg,
                                               const float* __restrict__ W0,
                                               const float* __restrict__ b0,
                                               u16* __restrict__ outhi,
                                               u16* __restrict__ outlo) {
  int n = blockIdx.x;
  int f = threadIdx.x;
  int i = f >> 7, h = f & 127;
  float s = b0[i * 128 + h];
#pragma unroll
  for (int c = 0; c < 8; c++)
    s = fmaf(xagg[(size_t)n * 56 + i * 8 + c], W0[(i * 8 + c) * 128 + h], s);
  float v = fmaxf(s, 0.f);
  split_store(v, outhi, outlo, (size_t)n * 896 + f);
}

// ---------------- link MLP ----------------
__global__ __launch_bounds__(128) void k_link_gather(const float* __restrict__ UV,
                                                     const int* __restrict__ eit,
                                                     const float* __restrict__ lb0,
                                                     u16* __restrict__ Hhi,
                                                     u16* __restrict__ Hlo) {
  int t = blockIdx.x;
  int f = threadIdx.x;
  int s = eit[t], d = eit[NT + t];
  float b = lb0[f];
  float v1 = fmaxf(UV[(size_t)s * 256 + f] + UV[(size_t)d * 256 + 128 + f] + b, 0.f);
  float v2 = fmaxf(UV[(size_t)d * 256 + f] + UV[(size_t)s * 256 + 128 + f] + b, 0.f);
  split_store(v1, Hhi, Hlo, (size_t)t * 128 + f);
  split_store(v2, Hhi, Hlo, (size_t)(NT + t) * 128 + f);
}

__global__ void k_link_out(const u16* __restrict__ Hhi, const u16* __restrict__ Hlo,
                           const float* __restrict__ lw4, const float* __restrict__ lb4,
                           float* __restrict__ out) {
  int t = blockIdx.x * 256 + threadIdx.x;
  if (t >= NT) return;
  float o1[4] = {lb4[0], lb4[1], lb4[2], lb4[3]};
  float o2[4] = {o1[0], o1[1], o1[2], o1[3]};
  for (int k = 0; k < 128; k++) {
    size_t i1 = (size_t)t * 128 + k, i2 = (size_t)(NT + t) * 128 + k;
    float h1 = bf2f(Hhi[i1]) + bf2f(Hlo[i1]);
    float h2v = bf2f(Hhi[i2]) + bf2f(Hlo[i2]);
#pragma unroll
    for (int j = 0; j < 4; j++) {
      float w = lw4[k * 4 + j];
      o1[j] = fmaf(h1, w, o1[j]);
      o2[j] = fmaf(h2v, w, o2[j]);
    }
  }
  out[t * 4 + 0] = 0.5f * (o1[0] + o2[0]);
  out[t * 4 + 1] = 0.5f * (o1[1] + o2[2]);
  out[t * 4 + 2] = 0.5f * (o1[2] + o2[1]);
  out[t * 4 + 3] = 0.5f * (o1[3] + o2[3]);
}

// ---------------- host ----------------
extern "C" void kernel_launch(void* const* d_in, const int* in_sizes, int n_in,
                              void* d_out, int out_size, void* d_ws, size_t ws_size,
                              hipStream_t stream) {
  const float* x   = (const float*)d_in[0];
  const int*   ei  = (const int*)d_in[1];
  const float* ea  = (const float*)d_in[2];
  const int*   eit = (const int*)d_in[3];
  const float* W0  = (const float*)d_in[4];
  const float* b0  = (const float*)d_in[5];
  const float* W1  = (const float*)d_in[6];
  const float* b1  = (const float*)d_in[7];
  const float* W2  = (const float*)d_in[8];
  const float* b2  = (const float*)d_in[9];
  const float* W3  = (const float*)d_in[10];
  const float* b3  = (const float*)d_in[11];
  const float* ew1 = (const float*)d_in[12];
  const float* eb1 = (const float*)d_in[13];
  const float* ew2 = (const float*)d_in[14];
  const float* eb2 = (const float*)d_in[15];
  const float* ew3 = (const float*)d_in[16];
  const float* eb3 = (const float*)d_in[17];
  const float* lw0 = (const float*)d_in[18];
  const float* lb0 = (const float*)d_in[19];
  const float* lwh = (const float*)d_in[20];
  const float* lbh = (const float*)d_in[21];
  const float* lw4 = (const float*)d_in[22];
  const float* lb4 = (const float*)d_in[23];
  const int* row = ei;
  const int* col = ei + NE;
  float* out = (float*)d_out;

  char* ws = (char*)d_ws;
  size_t off = 0;
  auto alloc = [&](size_t bytes) -> char* {
    char* p = ws + off;
    off += (bytes + 255) & ~(size_t)255;
    return p;
  };
  // xA hi/lo: x1 -> x3 -> x4. xB: hW1(f16) -> xagg2 hi/lo -> hW3(f16) -> H overlay.
  // [xB | x2f] = 71.68 + 10.24 = 81.92 MB exactly holds the 4 link H planes.
  u16*   xAhi   = (u16*)alloc((size_t)NN * 896 * 2);
  u16*   xAlo   = (u16*)alloc((size_t)NN * 896 * 2);
  float* xB     = (float*)alloc((size_t)NN * 896 * 4);
  float* x2f    = (float*)alloc((size_t)NN * 128 * 4);
  float* UV     = (float*)alloc((size_t)NN * 256 * 4);  // xagg overlays front
  float* csr_nrm= (float*)alloc((size_t)8 * NE * 4);
  float* dis    = (float*)alloc((size_t)8 * NN * 4);
  float* ewb    = (float*)alloc((size_t)NE * 4);
  int*   rowptr = (int*)alloc((size_t)(NN + 1) * 4);
  int*   cursor = (int*)alloc((size_t)NN * 4);
  int*   eid    = (int*)alloc((size_t)NE * 4);
  int*   csr_src= (int*)alloc((size_t)NE * 4);
  u16* w1thi  = (u16*)alloc((size_t)128 * 896 * 2);
  u16* w1tlo  = (u16*)alloc((size_t)128 * 896 * 2);
  u16* w2thi  = (u16*)alloc((size_t)7 * 128 * 128 * 2);
  u16* w2tlo  = (u16*)alloc((size_t)7 * 128 * 128 * 2);
  u16* w3thi  = (u16*)alloc((size_t)7 * 128 * 896 * 2);
  u16* w3tlo  = (u16*)alloc((size_t)7 * 128 * 896 * 2);
  u16* lw0thi = (u16*)alloc((size_t)2 * 128 * 896 * 2);
  u16* lw0tlo = (u16*)alloc((size_t)2 * 128 * 896 * 2);
  u16* lwhthi = (u16*)alloc((size_t)3 * 128 * 128 * 2);
  u16* lwhtlo = (u16*)alloc((size_t)3 * 128 * 128 * 2);
  float* xagg = UV;  // [NN][56] fp32, dead before UV written
  (void)ws_size; (void)in_sizes; (void)n_in; (void)out_size;

  const int EB = (NE + 255) / 256;
  const int NB = (NN + 255) / 256;
  const int GX = (NN + 127) / 128;   // 157
  const int MC = (GX + 7) / 8;       // 20 row-tiles max per XCD

  // weight prep (independent)
  k_wprep<<<dim3(448, 1), 256, 0, stream>>>(W1, 128, 0, 896, w1thi, w1tlo);
  k_wprep<<<dim3(64, 7), 256, 0, stream>>>(W2, 128, (size_t)128 * 128, 128, w2thi, w2tlo);
  k_wprep<<<dim3(448, 7), 256, 0, stream>>>(W3, 128, (size_t)896 * 128, 896, w3thi, w3tlo);
  // lw0 is [1792][128]: U = rows 0..895, V = rows 896..1791
  k_wprep<<<dim3(448, 2), 256, 0, stream>>>(lw0, 128, (size_t)896 * 128, 896, lw0thi, lw0tlo);
  k_wprep<<<dim3(64, 3), 256, 0, stream>>>(lwh, 128, (size_t)128 * 128, 128, lwhthi, lwhtlo);

  // edge weight + CSR + degrees + norms
  k_edge_mlp<<<EB, 256, 0, stream>>>(ea, ew1, eb1, ew2, eb2, ew3, eb3, ewb);
  hipMemsetAsync(cursor, 0, (size_t)NN * 4, stream);
  k_count<<<EB, 256, 0, stream>>>(col, cursor);
  k_scan<<<1, 256, 0, stream>>>(cursor, rowptr);
  k_copy_i32<<<NB, 256, 0, stream>>>(rowptr, cursor, NN);
  k_fill_csr<<<EB, 256, 0, stream>>>(col, cursor, eid);
  k_deg_csr<<<(NN + 7) / 8, 64, 0, stream>>>(rowptr, eid, ea, ewb, dis);
  k_csr_norms<<<EB, 256, 0, stream>>>(eid, row, col, ea, ewb, dis, csr_src, csr_nrm);

  // Layer 0 (aggregate-first): xagg [N,7,8] -> x1 hi/lo (xA)
  k_agg_x<<<NN, 64, 0, stream>>>(x, csr_nrm, dis, rowptr, csr_src, xagg);
  k_gemm0<<<NN, 896, 0, stream>>>(xagg, W0, b0, xAhi, xAlo);

  // Layer 1: x1 @ W1 -> hW1 fp16 (xB); agg1 (learned ew, bias+relu) -> x2f
  f16* hW1 = (f16*)xB;
  k_mgemm<2, false, false, false, false><<<dim3(GX, 1), 256, 0, stream>>>(
      xAhi, xAlo, w1thi, w1tlo, nullptr, nullptr, nullptr, nullptr, hW1,
      896, NN, 896, 1, GX);
  k_agg1<<<(NN + 3) / 4, 256, 0, stream>>>(hW1, csr_nrm + (size_t)7 * NE,
                                           dis + (size_t)7 * NN, rowptr, csr_src, b1, x2f);

  // Layer 2 (aggregate-first): xagg2 = A_i * x2 (7 relations, hi/lo into xB),
  // then x3 = relu(xagg2_i @ W2_i + b2_i) via GROUP_A GEMM -> xA hi/lo
  u16* xagg2hi = (u16*)xB;
  u16* xagg2lo = xagg2hi + (size_t)NN * 896;
  k_agg2<<<(NN + 3) / 4, 256, 0, stream>>>(x2f, csr_nrm, dis, rowptr, csr_src,
                                           xagg2hi, xagg2lo);
  k_mgemm<1, true, true, true, false><<<dim3(GX, 7), 256, 0, stream>>>(
      xagg2hi, xagg2lo, w2thi, w2tlo, b2, nullptr, xAhi, xAlo, nullptr,
      896, NN, 128, 7, GX);

  // Layer 3: x3 @ W3 (7 mats, K=896, XCD-swizzled) -> hW3 fp16 (xB);
  // agg7 -> x4 hi/lo (xA)
  f16* hW3 = (f16*)xB;
  k_mgemm<2, false, false, false, true><<<dim3(8 * MC * 7), 256, 0, stream>>>(
      xAhi, xAlo, w3thi, w3tlo, nullptr, nullptr, nullptr, nullptr, hW3,
      896, NN, 896, 7, GX);
  k_agg7<<<NN, 448, 0, stream>>>(hW3, csr_nrm, dis, rowptr, csr_src, b3, xAhi, xAlo);

  // Link precompute: UV = x4 @ [lw0_top | lw0_bot]  (XCD-swizzled, NG=2)
  k_mgemm<0, false, false, false, true><<<dim3(8 * MC * 2), 256, 0, stream>>>(
      xAhi, xAlo, lw0thi, lw0tlo, nullptr, UV, nullptr, nullptr, nullptr,
      896, NN, 896, 2, GX);

  // H overlay on [xB | x2f]: 4 planes of 2NT*128 u16 = 81.92MB
  u16* Hahi = (u16*)xB;
  u16* Halo = Hahi + (size_t)2 * NT * 128;
  u16* Hbhi = Halo + (size_t)2 * NT * 128;
  u16* Hblo = Hbhi + (size_t)2 * NT * 128;
  k_link_gather<<<NT, 128, 0, stream>>>(UV, eit, lb0, Hahi, Halo);
  const int LGX = (2 * NT + 127) / 128;  // 625
  for (int i = 0; i < 3; i++) {
    const u16* whi = lwhthi + (size_t)i * 128 * 128;
    const u16* wlo = lwhtlo + (size_t)i * 128 * 128;
    const float* bb = lbh + (size_t)i * 128;
    u16* shi = (i % 2 == 0) ? Hahi : Hbhi;
    u16* slo = (i % 2 == 0) ? Halo : Hblo;
    u16* dhi = (i % 2 == 0) ? Hbhi : Hahi;
    u16* dlo = (i % 2 == 0) ? Hblo : Halo;
    k_mgemm<1, true, true, false, false><<<dim3(LGX, 1), 256, 0, stream>>>(
        shi, slo, whi, wlo, bb, nullptr, dhi, dlo, nullptr,
        128, 2 * NT, 128, 1, LGX);
  }
  // after 3 ping-pongs final state is Hb
  k_link_out<<<(NT + 255) / 256, 256, 0, stream>>>(Hbhi, Hblo, lw4, lb4, out);
}

// Round 7
// 702.799 us; speedup vs baseline: 5.3189x; 1.0675x over previous
//
#include <hip/hip_runtime.h>
#include <math.h>

#define NN 20000
#define NE 200000
#define NT 40000

typedef _Float16 f16;
typedef __attribute__((ext_vector_type(8))) _Float16 f16x8;
typedef __attribute__((ext_vector_type(4))) float f32x4;
typedef __attribute__((ext_vector_type(2))) _Float16 h2;

// activation split: v = hi + lo exactly to ~2^-22 relative
__device__ __forceinline__ void split_store_h(float v, f16* hi, f16* lo, size_t idx) {
  f16 h = (f16)v;
  hi[idx] = h;
  lo[idx] = (f16)(v - (float)h);
}

// ---------------- edge weight MLP ----------------
__global__ void k_edge_mlp(const float* __restrict__ ea,
                           const float* __restrict__ w1, const float* __restrict__ b1,
                           const float* __restrict__ w2, const float* __restrict__ b2,
                           const float* __restrict__ w3, const float* __restrict__ b3,
                           float* __restrict__ out) {
  int e = blockIdx.x * 256 + threadIdx.x;
  if (e >= NE) return;
  float a[7];
#pragma unroll
  for (int i = 0; i < 7; i++) a[i] = ea[e * 7 + i];
  float t1[28];
#pragma unroll
  for (int j = 0; j < 28; j++) {
    float s = b1[j];
#pragma unroll
    for (int k = 0; k < 7; k++) s = fmaf(a[k], w1[k * 28 + j], s);
    t1[j] = fmaxf(s, 0.f);
  }
  float t2[28];
  for (int j = 0; j < 28; j++) {
    float s = b2[j];
    for (int k = 0; k < 28; k++) s = fmaf(t1[k], w2[k * 28 + j], s);
    t2[j] = fmaxf(s, 0.f);
  }
  float s = b3[0];
  for (int k = 0; k < 28; k++) s = fmaf(t2[k], w3[k], s);
  out[e] = 1.f / (1.f + expf(-s));
}

// ---------------- CSR build ----------------
__global__ void k_count(const int* __restrict__ col, int* __restrict__ cnt) {
  int e = blockIdx.x * 256 + threadIdx.x;
  if (e < NE) atomicAdd(&cnt[col[e]], 1);
}

__global__ void k_scan(const int* __restrict__ cnt, int* __restrict__ rowptr) {
  __shared__ int sums[256];
  __shared__ int offs[256];
  int t = threadIdx.x;
  const int CH = (NN + 255) / 256;
  int base = t * CH;
  int s = 0;
  for (int i = 0; i < CH; i++) { int idx = base + i; if (idx < NN) s += cnt[idx]; }
  sums[t] = s;
  __syncthreads();
  if (t == 0) {
    int acc = 0;
    for (int i = 0; i < 256; i++) { offs[i] = acc; acc += sums[i]; }
    rowptr[NN] = acc;
  }
  __syncthreads();
  int acc = offs[t];
  for (int i = 0; i < CH; i++) {
    int idx = base + i;
    if (idx < NN) { rowptr[idx] = acc; acc += cnt[idx]; }
  }
}

__global__ void k_copy_i32(const int* __restrict__ src, int* __restrict__ dst, int n) {
  int i = blockIdx.x * 256 + threadIdx.x;
  if (i < n) dst[i] = src[i];
}

__global__ void k_fill_csr(const int* __restrict__ col, int* __restrict__ cursor,
                           int* __restrict__ eid) {
  int e = blockIdx.x * 256 + threadIdx.x;
  if (e >= NE) return;
  int pos = atomicAdd(&cursor[col[e]], 1);
  eid[pos] = e;
}

// degrees from CSR (no float atomics). 8 nodes x 8 relations per 64-thread block.
__global__ __launch_bounds__(64) void k_deg_csr(const int* __restrict__ rowptr,
                                                const int* __restrict__ eid,
                                                const float* __restrict__ ea,
                                                const float* __restrict__ ewb,
                                                float* __restrict__ dis) {
  int t = threadIdx.x;
  int n = blockIdx.x * 8 + (t >> 3);
  int i = t & 7;
  if (n >= NN) return;
  float deg = 1.f;  // self-loop weight
  int s = rowptr[n], e2 = rowptr[n + 1];
  for (int p = s; p < e2; p++) {
    int e = eid[p];
    deg += (i < 7) ? ea[e * 7 + i] : ewb[e];
  }
  dis[i * NN + n] = rsqrtf(deg);  // deg >= 1 always
}

__global__ void k_csr_norms(const int* __restrict__ eid, const int* __restrict__ row,
                            const int* __restrict__ col, const float* __restrict__ ea,
                            const float* __restrict__ ew, const float* __restrict__ dis,
                            int* __restrict__ csr_src, float* __restrict__ csr_norm) {
  int p = blockIdx.x * 256 + threadIdx.x;
  if (p >= NE) return;
  int e = eid[p];
  int r = row[e], c = col[e];
  csr_src[p] = r;
#pragma unroll
  for (int i = 0; i < 7; i++)
    csr_norm[i * NE + p] = dis[i * NN + r] * ea[e * 7 + i] * dis[i * NN + c];
  csr_norm[7 * NE + p] = dis[7 * NN + r] * ew[e] * dis[7 * NN + c];
}

// ---------------- weight prep: transpose + fp16 quantize ----------------
// W[g][k][n] (ldW cols, mats matOff apart) -> WT[g][n][k] fp16
__global__ void k_wprep(const float* __restrict__ W, int ldW, size_t matOff, int K,
                        f16* __restrict__ WT) {
  int g = blockIdx.y;
  int idx = blockIdx.x * 256 + threadIdx.x;
  if (idx >= K * 128) return;
  int k = idx >> 7, n = idx & 127;
  float v = W[(size_t)g * matOff + (size_t)k * ldW + n];
  WT[(size_t)g * 128 * K + (size_t)n * K + k] = (f16)v;
}

// ---------------- split-fp16 MFMA GEMM (2-term) ----------------
// C = (Ahi + Alo) @ B^T_g, fp32 acc. A exact (fp16 hi/lo), B fp16-quantized.
// OUTM: 0 = fp32, 1 = fp16 hi/lo split, 2 = fp16.
// SWIZZLE: 1-D grid, XCD-aware decode — all NG column-groups of one 128-row
// A-panel run consecutively on the same XCD (b&7) -> panel L2-resident.
template <int OUTM, bool RELU, bool BIAS, bool GROUP_A, bool SWIZZLE>
__global__ __launch_bounds__(256) void k_mgemm(
    const f16* __restrict__ Ahi, const f16* __restrict__ Alo,
    const f16* __restrict__ BT,
    const float* __restrict__ bias,
    float* __restrict__ Cf, f16* __restrict__ Chi, f16* __restrict__ Clo,
    f16* __restrict__ Ch,
    int ldA, int M, int K, int NG, int GXp) {
  int rowT, g;
  if (SWIZZLE) {
    int b = blockIdx.x;
    int xcd = b & 7, s = b >> 3;
    g = s % NG;
    int lr = s / NG;
    rowT = lr * 8 + xcd;
    if (rowT >= GXp) return;  // uniform early-out (padded grid)
  } else {
    rowT = blockIdx.x;
    g = blockIdx.y;
  }
  __shared__ f16 smem[12288];  // 3 tiles [128 rows][32 k] fp16: Ahi, Alo, B
  const int tid = threadIdx.x;
  const int w = tid >> 6, lane = tid & 63;
  const int quad = lane >> 4, lc = lane & 15;
  const int wr = w >> 1, wc = w & 1;
  const int bm = rowT * 128;
  const int ldC = NG * 128;
  const int cb = g * 128;
  const int aoff = GROUP_A ? g * K : 0;
  const f16* Bg = BT + (size_t)g * 128 * K;
  const int srow = lane >> 2, skoff = (lane & 3) * 8;

  f32x4 acc[4][4] = {};

  for (int k0 = 0; k0 < K; k0 += 32) {
    // stage 24KB: 24 chunks of 1024B (16 rows x 64B), 6 per wave
#pragma unroll
    for (int l = 0; l < 6; l++) {
      int c = w + l * 4;
      int t = c >> 3, r16 = c & 7;
      int rowi = r16 * 16 + srow;
      f16* ldst = smem + t * 4096 + r16 * 512;  // +lane*16B implicit
      const f16* src;
      if (t < 2) {
        int gm = bm + rowi;
        if (gm > M - 1) gm = M - 1;  // clamp; guarded at store
        src = (t == 0 ? Ahi : Alo) + (size_t)gm * ldA + aoff + k0 + skoff;
      } else {
        src = Bg + (size_t)rowi * K + k0 + skoff;
      }
      __builtin_amdgcn_global_load_lds(
          (const __attribute__((address_space(1))) void*)src,
          (__attribute__((address_space(3))) void*)ldst, 16, 0, 0);
    }
    __syncthreads();
    f16x8 bf[4];
#pragma unroll
    for (int nt = 0; nt < 4; nt++) {
      int r = wc * 64 + nt * 16 + lc;
      bf[nt] = *(const f16x8*)(smem + 2 * 4096 + r * 32 + quad * 8);
    }
#pragma unroll
    for (int mt = 0; mt < 4; mt++) {
      int r = wr * 64 + mt * 16 + lc;
      f16x8 ah = *(const f16x8*)(smem + 0 * 4096 + r * 32 + quad * 8);
      f16x8 al = *(const f16x8*)(smem + 1 * 4096 + r * 32 + quad * 8);
#pragma unroll
      for (int nt = 0; nt < 4; nt++) {
        acc[mt][nt] = __builtin_amdgcn_mfma_f32_16x16x32_f16(ah, bf[nt], acc[mt][nt], 0, 0, 0);
        acc[mt][nt] = __builtin_amdgcn_mfma_f32_16x16x32_f16(al, bf[nt], acc[mt][nt], 0, 0, 0);
      }
    }
    __syncthreads();
  }

  float bv[4];
  if (BIAS) {
#pragma unroll
    for (int nt = 0; nt < 4; nt++) bv[nt] = bias[cb + wc * 64 + nt * 16 + lc];
  }
#pragma unroll
  for (int mt = 0; mt < 4; mt++) {
#pragma unroll
    for (int r = 0; r < 4; r++) {
      int gm = bm + wr * 64 + mt * 16 + quad * 4 + r;
      if (gm >= M) continue;
#pragma unroll
      for (int nt = 0; nt < 4; nt++) {
        float v = acc[mt][nt][r];
        if (BIAS) v += bv[nt];
        if (RELU) v = fmaxf(v, 0.f);
        size_t idx = (size_t)gm * ldC + cb + wc * 64 + nt * 16 + lc;
        if (OUTM == 1) {
          f16 h = (f16)v;
          Chi[idx] = h;
          Clo[idx] = (f16)(v - (float)h);
        } else if (OUTM == 2) {
          Ch[idx] = (f16)v;
        } else {
          Cf[idx] = v;
        }
      }
    }
  }
}

// ---------------- layer-3 aggregation: fp16 gather, half2 + unroll-4 ----------------
// x4[n,f] = relu(b[f] + dis_i(n)^2*hW[n,f] + sum_p norm_i(p)*hW[src_p,f]), i=f>>7
__global__ __launch_bounds__(448) void k_agg7(const f16* __restrict__ hW,
                                              const float* __restrict__ csr_norm,
                                              const float* __restrict__ dis,
                                              const int* __restrict__ rowptr,
                                              const int* __restrict__ csr_src,
                                              const float* __restrict__ bias,
                                              f16* __restrict__ outhi,
                                              f16* __restrict__ outlo) {
  int n = blockIdx.x;
  int f2 = threadIdx.x;   // handles cols 2*f2, 2*f2+1
  int i = f2 >> 6;        // wave-uniform
  const h2* hw2 = (const h2*)hW;
  const float* nrm = csr_norm + (size_t)i * NE;
  float d = dis[i * NN + n];
  h2 sv = hw2[(size_t)n * 448 + f2];
  float ax = d * d * (float)sv.x, ay = d * d * (float)sv.y;
  int s = rowptr[n], e = rowptr[n + 1];
  int p = s;
  for (; p + 4 <= e; p += 4) {
    int s0 = csr_src[p], s1 = csr_src[p + 1], s2 = csr_src[p + 2], s3 = csr_src[p + 3];
    float n0 = nrm[p], n1 = nrm[p + 1], n2 = nrm[p + 2], n3 = nrm[p + 3];
    h2 v0 = hw2[(size_t)s0 * 448 + f2];
    h2 v1 = hw2[(size_t)s1 * 448 + f2];
    h2 v2 = hw2[(size_t)s2 * 448 + f2];
    h2 v3 = hw2[(size_t)s3 * 448 + f2];
    ax = fmaf(n0, (float)v0.x, ax); ay = fmaf(n0, (float)v0.y, ay);
    ax = fmaf(n1, (float)v1.x, ax); ay = fmaf(n1, (float)v1.y, ay);
    ax = fmaf(n2, (float)v2.x, ax); ay = fmaf(n2, (float)v2.y, ay);
    ax = fmaf(n3, (float)v3.x, ax); ay = fmaf(n3, (float)v3.y, ay);
  }
  for (; p < e; p++) {
    int s0 = csr_src[p];
    float n0 = nrm[p];
    h2 v0 = hw2[(size_t)s0 * 448 + f2];
    ax = fmaf(n0, (float)v0.x, ax); ay = fmaf(n0, (float)v0.y, ay);
  }
  float vx = fmaxf(ax + bias[2 * f2], 0.f);
  float vy = fmaxf(ay + bias[2 * f2 + 1], 0.f);
  split_store_h(vx, outhi, outlo, (size_t)n * 896 + 2 * f2);
  split_store_h(vy, outhi, outlo, (size_t)n * 896 + 2 * f2 + 1);
}

// ---------------- layer-1 aggregation: fp16 gather, fp32 out, bias+relu ----------------
__global__ __launch_bounds__(256) void k_agg1(const f16* __restrict__ hW,
                                              const float* __restrict__ nrm,
                                              const float* __restrict__ dis_i,
                                              const int* __restrict__ rowptr,
                                              const int* __restrict__ csr_src,
                                              const float* __restrict__ bias,
                                              float* __restrict__ x2f) {
  int t = threadIdx.x;
  int n = blockIdx.x * 4 + (t >> 6);
  int f2 = t & 63;
  if (n >= NN) return;
  const h2* hw2 = (const h2*)hW;
  float d = dis_i[n];
  h2 sv = hw2[(size_t)n * 64 + f2];
  float ax = d * d * (float)sv.x, ay = d * d * (float)sv.y;
  int s = rowptr[n], e = rowptr[n + 1];
  int p = s;
  for (; p + 4 <= e; p += 4) {
    int s0 = csr_src[p], s1 = csr_src[p + 1], s2 = csr_src[p + 2], s3 = csr_src[p + 3];
    float n0 = nrm[p], n1 = nrm[p + 1], n2 = nrm[p + 2], n3 = nrm[p + 3];
    h2 v0 = hw2[(size_t)s0 * 64 + f2];
    h2 v1 = hw2[(size_t)s1 * 64 + f2];
    h2 v2 = hw2[(size_t)s2 * 64 + f2];
    h2 v3 = hw2[(size_t)s3 * 64 + f2];
    ax = fmaf(n0, (float)v0.x, ax); ay = fmaf(n0, (float)v0.y, ay);
    ax = fmaf(n1, (float)v1.x, ax); ay = fmaf(n1, (float)v1.y, ay);
    ax = fmaf(n2, (float)v2.x, ax); ay = fmaf(n2, (float)v2.y, ay);
    ax = fmaf(n3, (float)v3.x, ax); ay = fmaf(n3, (float)v3.y, ay);
  }
  for (; p < e; p++) {
    int s0 = csr_src[p];
    float n0 = nrm[p];
    h2 v0 = hw2[(size_t)s0 * 64 + f2];
    ax = fmaf(n0, (float)v0.x, ax); ay = fmaf(n0, (float)v0.y, ay);
  }
  x2f[(size_t)n * 128 + 2 * f2] = fmaxf(ax + bias[2 * f2], 0.f);
  x2f[(size_t)n * 128 + 2 * f2 + 1] = fmaxf(ay + bias[2 * f2 + 1], 0.f);
}

// ---------------- layer-2 aggregate-first: gather x2 once, 7 norms ----------------
__global__ __launch_bounds__(256) void k_agg2(const float* __restrict__ x2f,
                                              const float* __restrict__ csr_norm,
                                              const float* __restrict__ dis,
                                              const int* __restrict__ rowptr,
                                              const int* __restrict__ csr_src,
                                              f16* __restrict__ ohi,
                                              f16* __restrict__ olo) {
  int t = threadIdx.x;
  int n = blockIdx.x * 4 + (t >> 6);
  int f2 = t & 63;
  if (n >= NN) return;
  const float2* x2 = (const float2*)x2f;
  float2 sv = x2[(size_t)n * 64 + f2];
  float ax[7], ay[7];
#pragma unroll
  for (int i = 0; i < 7; i++) {
    float d = dis[i * NN + n];
    ax[i] = d * d * sv.x;
    ay[i] = d * d * sv.y;
  }
  int s = rowptr[n], e = rowptr[n + 1];
  int p = s;
  for (; p + 2 <= e; p += 2) {
    int s0 = csr_src[p], s1 = csr_src[p + 1];
    float2 v0 = x2[(size_t)s0 * 64 + f2];
    float2 v1 = x2[(size_t)s1 * 64 + f2];
#pragma unroll
    for (int i = 0; i < 7; i++) {
      float n0 = csr_norm[(size_t)i * NE + p];
      float n1 = csr_norm[(size_t)i * NE + p + 1];
      ax[i] = fmaf(n0, v0.x, ax[i]); ay[i] = fmaf(n0, v0.y, ay[i]);
      ax[i] = fmaf(n1, v1.x, ax[i]); ay[i] = fmaf(n1, v1.y, ay[i]);
    }
  }
  for (; p < e; p++) {
    int s0 = csr_src[p];
    float2 v0 = x2[(size_t)s0 * 64 + f2];
#pragma unroll
    for (int i = 0; i < 7; i++) {
      float n0 = csr_norm[(size_t)i * NE + p];
      ax[i] = fmaf(n0, v0.x, ax[i]); ay[i] = fmaf(n0, v0.y, ay[i]);
    }
  }
#pragma unroll
  for (int i = 0; i < 7; i++) {
    split_store_h(ax[i], ohi, olo, (size_t)n * 896 + i * 128 + 2 * f2);
    split_store_h(ay[i], ohi, olo, (size_t)n * 896 + i * 128 + 2 * f2 + 1);
  }
}

// ---------------- layer 0: aggregate-first (x is only [N,8]) ----------------
__global__ __launch_bounds__(64) void k_agg_x(const float* __restrict__ x,
                                              const float* __restrict__ csr_norm,
                                              const float* __restrict__ dis,
                                              const int* __restrict__ rowptr,
                                              const int* __restrict__ csr_src,
                                              float* __restrict__ xagg) {
  int n = blockIdx.x;
  int f = threadIdx.x;
  if (f >= 56) return;
  int i = f >> 3, c = f & 7;
  float d = dis[i * NN + n];
  float acc = d * d * x[(size_t)n * 8 + c];
  int s = rowptr[n], e = rowptr[n + 1];
  for (int p = s; p < e; p++)
    acc = fmaf(csr_norm[i * NE + p], x[(size_t)csr_src[p] * 8 + c], acc);
  xagg[(size_t)n * 56 + f] = acc;
}

// x1[n, i*128+h] = relu(b0[i][h] + sum_c xagg[n][i*8+c] * W0[i][c][h]), fp16 hi/lo out
__global__ __launch_bounds__(896) void k_gemm0(const float* __restrict__ xagg,
                                               const float* __restrict__ W0,
                                               const float* __restrict__ b0,
                                               f16* __restrict__ outhi,
                                               f16* __restrict__ outlo) {
  int n = blockIdx.x;
  int f = threadIdx.x;
  int i = f >> 7, h = f & 127;
  float s = b0[i * 128 + h];
#pragma unroll
  for (int c = 0; c < 8; c++)
    s = fmaf(xagg[(size_t)n * 56 + i * 8 + c], W0[(i * 8 + c) * 128 + h], s);
  float v = fmaxf(s, 0.f);
  split_store_h(v, outhi, outlo, (size_t)n * 896 + f);
}

// ---------------- link MLP ----------------
__global__ __launch_bounds__(128) void k_link_gather(const float* __restrict__ UV,
                                                     const int* __restrict__ eit,
                                                     const float* __restrict__ lb0,
                                                     f16* __restrict__ Hhi,
                                                     f16* __restrict__ Hlo) {
  int t = blockIdx.x;
  int f = threadIdx.x;
  int s = eit[t], d = eit[NT + t];
  float b = lb0[f];
  float v1 = fmaxf(UV[(size_t)s * 256 + f] + UV[(size_t)d * 256 + 128 + f] + b, 0.f);
  float v2 = fmaxf(UV[(size_t)d * 256 + f] + UV[(size_t)s * 256 + 128 + f] + b, 0.f);
  split_store_h(v1, Hhi, Hlo, (size_t)t * 128 + f);
  split_store_h(v2, Hhi, Hlo, (size_t)(NT + t) * 128 + f);
}

__global__ void k_link_out(const f16* __restrict__ Hhi, const f16* __restrict__ Hlo,
                           const float* __restrict__ lw4, const float* __restrict__ lb4,
                           float* __restrict__ out) {
  int t = blockIdx.x * 256 + threadIdx.x;
  if (t >= NT) return;
  float o1[4] = {lb4[0], lb4[1], lb4[2], lb4[3]};
  float o2[4] = {o1[0], o1[1], o1[2], o1[3]};
  for (int k = 0; k < 128; k++) {
    size_t i1 = (size_t)t * 128 + k, i2 = (size_t)(NT + t) * 128 + k;
    float h1 = (float)Hhi[i1] + (float)Hlo[i1];
    float h2v = (float)Hhi[i2] + (float)Hlo[i2];
#pragma unroll
    for (int j = 0; j < 4; j++) {
      float w = lw4[k * 4 + j];
      o1[j] = fmaf(h1, w, o1[j]);
      o2[j] = fmaf(h2v, w, o2[j]);
    }
  }
  out[t * 4 + 0] = 0.5f * (o1[0] + o2[0]);
  out[t * 4 + 1] = 0.5f * (o1[1] + o2[2]);
  out[t * 4 + 2] = 0.5f * (o1[2] + o2[1]);
  out[t * 4 + 3] = 0.5f * (o1[3] + o2[3]);
}

// ---------------- host ----------------
extern "C" void kernel_launch(void* const* d_in, const int* in_sizes, int n_in,
                              void* d_out, int out_size, void* d_ws, size_t ws_size,
                              hipStream_t stream) {
  const float* x   = (const float*)d_in[0];
  const int*   ei  = (const int*)d_in[1];
  const float* ea  = (const float*)d_in[2];
  const int*   eit = (const int*)d_in[3];
  const float* W0  = (const float*)d_in[4];
  const float* b0  = (const float*)d_in[5];
  const float* W1  = (const float*)d_in[6];
  const float* b1  = (const float*)d_in[7];
  const float* W2  = (const float*)d_in[8];
  const float* b2  = (const float*)d_in[9];
  const float* W3  = (const float*)d_in[10];
  const float* b3  = (const float*)d_in[11];
  const float* ew1 = (const float*)d_in[12];
  const float* eb1 = (const float*)d_in[13];
  const float* ew2 = (const float*)d_in[14];
  const float* eb2 = (const float*)d_in[15];
  const float* ew3 = (const float*)d_in[16];
  const float* eb3 = (const float*)d_in[17];
  const float* lw0 = (const float*)d_in[18];
  const float* lb0 = (const float*)d_in[19];
  const float* lwh = (const float*)d_in[20];
  const float* lbh = (const float*)d_in[21];
  const float* lw4 = (const float*)d_in[22];
  const float* lb4 = (const float*)d_in[23];
  const int* row = ei;
  const int* col = ei + NE;
  float* out = (float*)d_out;

  char* ws = (char*)d_ws;
  size_t off = 0;
  auto alloc = [&](size_t bytes) -> char* {
    char* p = ws + off;
    off += (bytes + 255) & ~(size_t)255;
    return p;
  };
  // xA hi/lo: x1 -> x3 -> x4 (fp16 planes). xB: hW1(f16) -> xagg2 hi/lo -> hW3(f16)
  // -> H overlay. [xB | x2f] = 71.68 + 10.24 = 81.92 MB holds the 4 link H planes.
  f16*   xAhi   = (f16*)alloc((size_t)NN * 896 * 2);
  f16*   xAlo   = (f16*)alloc((size_t)NN * 896 * 2);
  float* xB     = (float*)alloc((size_t)NN * 896 * 4);
  float* x2f    = (float*)alloc((size_t)NN * 128 * 4);
  float* UV     = (float*)alloc((size_t)NN * 256 * 4);  // xagg overlays front
  float* csr_nrm= (float*)alloc((size_t)8 * NE * 4);
  float* dis    = (float*)alloc((size_t)8 * NN * 4);
  float* ewb    = (float*)alloc((size_t)NE * 4);
  int*   rowptr = (int*)alloc((size_t)(NN + 1) * 4);
  int*   cursor = (int*)alloc((size_t)NN * 4);
  int*   eid    = (int*)alloc((size_t)NE * 4);
  int*   csr_src= (int*)alloc((size_t)NE * 4);
  f16* w1t  = (f16*)alloc((size_t)128 * 896 * 2);
  f16* w2t  = (f16*)alloc((size_t)7 * 128 * 128 * 2);
  f16* w3t  = (f16*)alloc((size_t)7 * 128 * 896 * 2);
  f16* lw0t = (f16*)alloc((size_t)2 * 128 * 896 * 2);
  f16* lwht = (f16*)alloc((size_t)3 * 128 * 128 * 2);
  float* xagg = UV;  // [NN][56] fp32, dead before UV written
  (void)ws_size; (void)in_sizes; (void)n_in; (void)out_size;

  const int EB = (NE + 255) / 256;
  const int NB = (NN + 255) / 256;
  const int GX = (NN + 127) / 128;   // 157
  const int MC = (GX + 7) / 8;       // 20 row-tiles max per XCD

  // weight prep (independent)
  k_wprep<<<dim3(448, 1), 256, 0, stream>>>(W1, 128, 0, 896, w1t);
  k_wprep<<<dim3(64, 7), 256, 0, stream>>>(W2, 128, (size_t)128 * 128, 128, w2t);
  k_wprep<<<dim3(448, 7), 256, 0, stream>>>(W3, 128, (size_t)896 * 128, 896, w3t);
  // lw0 is [1792][128]: U = rows 0..895, V = rows 896..1791
  k_wprep<<<dim3(448, 2), 256, 0, stream>>>(lw0, 128, (size_t)896 * 128, 896, lw0t);
  k_wprep<<<dim3(64, 3), 256, 0, stream>>>(lwh, 128, (size_t)128 * 128, 128, lwht);

  // edge weight + CSR + degrees + norms
  k_edge_mlp<<<EB, 256, 0, stream>>>(ea, ew1, eb1, ew2, eb2, ew3, eb3, ewb);
  hipMemsetAsync(cursor, 0, (size_t)NN * 4, stream);
  k_count<<<EB, 256, 0, stream>>>(col, cursor);
  k_scan<<<1, 256, 0, stream>>>(cursor, rowptr);
  k_copy_i32<<<NB, 256, 0, stream>>>(rowptr, cursor, NN);
  k_fill_csr<<<EB, 256, 0, stream>>>(col, cursor, eid);
  k_deg_csr<<<(NN + 7) / 8, 64, 0, stream>>>(rowptr, eid, ea, ewb, dis);
  k_csr_norms<<<EB, 256, 0, stream>>>(eid, row, col, ea, ewb, dis, csr_src, csr_nrm);

  // Layer 0 (aggregate-first): xagg [N,7,8] -> x1 hi/lo (xA)
  k_agg_x<<<NN, 64, 0, stream>>>(x, csr_nrm, dis, rowptr, csr_src, xagg);
  k_gemm0<<<NN, 896, 0, stream>>>(xagg, W0, b0, xAhi, xAlo);

  // Layer 1: x1 @ W1 -> hW1 fp16 (xB); agg1 (learned ew, bias+relu) -> x2f
  f16* hW1 = (f16*)xB;
  k_mgemm<2, false, false, false, false><<<dim3(GX, 1), 256, 0, stream>>>(
      xAhi, xAlo, w1t, nullptr, nullptr, nullptr, nullptr, hW1,
      896, NN, 896, 1, GX);
  k_agg1<<<(NN + 3) / 4, 256, 0, stream>>>(hW1, csr_nrm + (size_t)7 * NE,
                                           dis + (size_t)7 * NN, rowptr, csr_src, b1, x2f);

  // Layer 2 (aggregate-first): xagg2 = A_i * x2 (7 relations, fp16 hi/lo into xB),
  // then x3 = relu(xagg2_i @ W2_i + b2_i) via GROUP_A GEMM -> xA hi/lo
  f16* xagg2hi = (f16*)xB;
  f16* xagg2lo = xagg2hi + (size_t)NN * 896;
  k_agg2<<<(NN + 3) / 4, 256, 0, stream>>>(x2f, csr_nrm, dis, rowptr, csr_src,
                                           xagg2hi, xagg2lo);
  k_mgemm<1, true, true, true, false><<<dim3(GX, 7), 256, 0, stream>>>(
      xagg2hi, xagg2lo, w2t, b2, nullptr, xAhi, xAlo, nullptr,
      896, NN, 128, 7, GX);

  // Layer 3: x3 @ W3 (7 mats, K=896, XCD-swizzled) -> hW3 fp16 (xB);
  // agg7 -> x4 hi/lo (xA)
  f16* hW3 = (f16*)xB;
  k_mgemm<2, false, false, false, true><<<dim3(8 * MC * 7), 256, 0, stream>>>(
      xAhi, xAlo, w3t, nullptr, nullptr, nullptr, nullptr, hW3,
      896, NN, 896, 7, GX);
  k_agg7<<<NN, 448, 0, stream>>>(hW3, csr_nrm, dis, rowptr, csr_src, b3, xAhi, xAlo);

  // Link precompute: UV = x4 @ [lw0_top | lw0_bot]  (XCD-swizzled, NG=2)
  k_mgemm<0, false, false, false, true><<<dim3(8 * MC * 2), 256, 0, stream>>>(
      xAhi, xAlo, lw0t, nullptr, UV, nullptr, nullptr, nullptr,
      896, NN, 896, 2, GX);

  // H overlay on [xB | x2f]: 4 planes of 2NT*128 f16 = 81.92MB
  f16* Hahi = (f16*)xB;
  f16* Halo = Hahi + (size_t)2 * NT * 128;
  f16* Hbhi = Halo + (size_t)2 * NT * 128;
  f16* Hblo = Hbhi + (size_t)2 * NT * 128;
  k_link_gather<<<NT, 128, 0, stream>>>(UV, eit, lb0, Hahi, Halo);
  const int LGX = (2 * NT + 127) / 128;  // 625
  for (int i = 0; i < 3; i++) {
    const f16* wt = lwht + (size_t)i * 128 * 128;
    const float* bb = lbh + (size_t)i * 128;
    f16* shi = (i % 2 == 0) ? Hahi : Hbhi;
    f16* slo = (i % 2 == 0) ? Halo : Hblo;
    f16* dhi = (i % 2 == 0) ? Hbhi : Hahi;
    f16* dlo = (i % 2 == 0) ? Hblo : Halo;
    k_mgemm<1, true, true, false, false><<<dim3(LGX, 1), 256, 0, stream>>>(
        shi, slo, wt, bb, nullptr, dhi, dlo, nullptr,
        128, 2 * NT, 128, 1, LGX);
  }
  // after 3 ping-pongs final state is Hb
  k_link_out<<<(NT + 255) / 256, 256, 0, stream>>>(Hbhi, Hblo, lw4, lb4, out);
}

// Round 8
// 658.745 us; speedup vs baseline: 5.6746x; 1.0669x over previous
//
#include <hip/hip_runtime.h>
#include <math.h>

#define NN 20000
#define NE 200000
#define NT 40000
#define HP 136  // padded LDS row stride (fp16) for H/W tiles: 2-way banks only

typedef _Float16 f16;
typedef __attribute__((ext_vector_type(8))) _Float16 f16x8;
typedef __attribute__((ext_vector_type(4))) float f32x4;
typedef __attribute__((ext_vector_type(2))) _Float16 h2;

// activation split: v = hi + lo exactly to ~2^-22 relative
__device__ __forceinline__ void split_store_h(float v, f16* hi, f16* lo, size_t idx) {
  f16 h = (f16)v;
  hi[idx] = h;
  lo[idx] = (f16)(v - (float)h);
}

// ---------------- edge weight MLP (+ CSR count fused) ----------------
__global__ void k_edge_mlp(const float* __restrict__ ea,
                           const float* __restrict__ w1, const float* __restrict__ b1,
                           const float* __restrict__ w2, const float* __restrict__ b2,
                           const float* __restrict__ w3, const float* __restrict__ b3,
                           const int* __restrict__ col,
                           float* __restrict__ out, int* __restrict__ cnt) {
  int e = blockIdx.x * 256 + threadIdx.x;
  if (e >= NE) return;
  atomicAdd(&cnt[col[e]], 1);
  float a[7];
#pragma unroll
  for (int i = 0; i < 7; i++) a[i] = ea[e * 7 + i];
  float t1[28];
#pragma unroll
  for (int j = 0; j < 28; j++) {
    float s = b1[j];
#pragma unroll
    for (int k = 0; k < 7; k++) s = fmaf(a[k], w1[k * 28 + j], s);
    t1[j] = fmaxf(s, 0.f);
  }
  float t2[28];
  for (int j = 0; j < 28; j++) {
    float s = b2[j];
    for (int k = 0; k < 28; k++) s = fmaf(t1[k], w2[k * 28 + j], s);
    t2[j] = fmaxf(s, 0.f);
  }
  float s = b3[0];
  for (int k = 0; k < 28; k++) s = fmaf(t2[k], w3[k], s);
  out[e] = 1.f / (1.f + expf(-s));
}

// ---------------- CSR scan: rowptr + cursor in one pass ----------------
__global__ void k_scan(int* __restrict__ cnt, int* __restrict__ rowptr) {
  __shared__ int sums[256];
  __shared__ int offs[256];
  int t = threadIdx.x;
  const int CH = (NN + 255) / 256;
  int base = t * CH;
  int s = 0;
  for (int i = 0; i < CH; i++) { int idx = base + i; if (idx < NN) s += cnt[idx]; }
  sums[t] = s;
  __syncthreads();
  if (t == 0) {
    int acc = 0;
    for (int i = 0; i < 256; i++) { offs[i] = acc; acc += sums[i]; }
    rowptr[NN] = acc;
  }
  __syncthreads();
  int acc = offs[t];
  for (int i = 0; i < CH; i++) {
    int idx = base + i;
    if (idx < NN) {
      int cv = cnt[idx];
      rowptr[idx] = acc;
      cnt[idx] = acc;  // becomes the fill cursor
      acc += cv;
    }
  }
}

__global__ void k_fill_csr(const int* __restrict__ col, int* __restrict__ cursor,
                           int* __restrict__ eid) {
  int e = blockIdx.x * 256 + threadIdx.x;
  if (e >= NE) return;
  int pos = atomicAdd(&cursor[col[e]], 1);
  eid[pos] = e;
}

// degrees from CSR (no float atomics). 8 nodes x 8 relations per 64-thread block.
__global__ __launch_bounds__(64) void k_deg_csr(const int* __restrict__ rowptr,
                                                const int* __restrict__ eid,
                                                const float* __restrict__ ea,
                                                const float* __restrict__ ewb,
                                                float* __restrict__ dis) {
  int t = threadIdx.x;
  int n = blockIdx.x * 8 + (t >> 3);
  int i = t & 7;
  if (n >= NN) return;
  float deg = 1.f;  // self-loop weight
  int s = rowptr[n], e2 = rowptr[n + 1];
  for (int p = s; p < e2; p++) {
    int e = eid[p];
    deg += (i < 7) ? ea[e * 7 + i] : ewb[e];
  }
  dis[i * NN + n] = rsqrtf(deg);  // deg >= 1 always
}

__global__ void k_csr_norms(const int* __restrict__ eid, const int* __restrict__ row,
                            const int* __restrict__ col, const float* __restrict__ ea,
                            const float* __restrict__ ew, const float* __restrict__ dis,
                            int* __restrict__ csr_src, float* __restrict__ csr_norm) {
  int p = blockIdx.x * 256 + threadIdx.x;
  if (p >= NE) return;
  int e = eid[p];
  int r = row[e], c = col[e];
  csr_src[p] = r;
#pragma unroll
  for (int i = 0; i < 7; i++)
    csr_norm[i * NE + p] = dis[i * NN + r] * ea[e * 7 + i] * dis[i * NN + c];
  csr_norm[7 * NE + p] = dis[7 * NN + r] * ew[e] * dis[7 * NN + c];
}

// ---------------- weight prep: transpose + fp16 quantize ----------------
// W[g][k][n] (ldW cols, mats matOff apart) -> WT[g][n][k] fp16
__global__ void k_wprep(const float* __restrict__ W, int ldW, size_t matOff, int K,
                        f16* __restrict__ WT) {
  int g = blockIdx.y;
  int idx = blockIdx.x * 256 + threadIdx.x;
  if (idx >= K * 128) return;
  int k = idx >> 7, n = idx & 127;
  float v = W[(size_t)g * matOff + (size_t)k * ldW + n];
  WT[(size_t)g * 128 * K + (size_t)n * K + k] = (f16)v;
}

// ---------------- split-fp16 MFMA GEMM (2-term) ----------------
// C = (Ahi + Alo) @ B^T_g, fp32 acc. A exact (fp16 hi/lo), B fp16-quantized.
// OUTM: 0 = fp32, 1 = fp16 hi/lo split, 2 = fp16.
// SWIZZLE: 1-D grid, XCD-aware decode — all NG column-groups of one 128-row
// A-panel run consecutively on the same XCD (b&7) -> panel L2-resident.
template <int OUTM, bool RELU, bool BIAS, bool GROUP_A, bool SWIZZLE>
__global__ __launch_bounds__(256) void k_mgemm(
    const f16* __restrict__ Ahi, const f16* __restrict__ Alo,
    const f16* __restrict__ BT,
    const float* __restrict__ bias,
    float* __restrict__ Cf, f16* __restrict__ Chi, f16* __restrict__ Clo,
    f16* __restrict__ Ch,
    int ldA, int M, int K, int NG, int GXp) {
  int rowT, g;
  if (SWIZZLE) {
    int b = blockIdx.x;
    int xcd = b & 7, s = b >> 3;
    g = s % NG;
    int lr = s / NG;
    rowT = lr * 8 + xcd;
    if (rowT >= GXp) return;  // uniform early-out (padded grid)
  } else {
    rowT = blockIdx.x;
    g = blockIdx.y;
  }
  __shared__ f16 smem[12288];  // 3 tiles [128 rows][32 k] fp16: Ahi, Alo, B
  const int tid = threadIdx.x;
  const int w = tid >> 6, lane = tid & 63;
  const int quad = lane >> 4, lc = lane & 15;
  const int wr = w >> 1, wc = w & 1;
  const int bm = rowT * 128;
  const int ldC = NG * 128;
  const int cb = g * 128;
  const int aoff = GROUP_A ? g * K : 0;
  const f16* Bg = BT + (size_t)g * 128 * K;
  const int srow = lane >> 2, skoff = (lane & 3) * 8;

  f32x4 acc[4][4] = {};

  for (int k0 = 0; k0 < K; k0 += 32) {
    // stage 24KB: 24 chunks of 1024B (16 rows x 64B), 6 per wave
#pragma unroll
    for (int l = 0; l < 6; l++) {
      int c = w + l * 4;
      int t = c >> 3, r16 = c & 7;
      int rowi = r16 * 16 + srow;
      f16* ldst = smem + t * 4096 + r16 * 512;  // +lane*16B implicit
      const f16* src;
      if (t < 2) {
        int gm = bm + rowi;
        if (gm > M - 1) gm = M - 1;  // clamp; guarded at store
        src = (t == 0 ? Ahi : Alo) + (size_t)gm * ldA + aoff + k0 + skoff;
      } else {
        src = Bg + (size_t)rowi * K + k0 + skoff;
      }
      __builtin_amdgcn_global_load_lds(
          (const __attribute__((address_space(1))) void*)src,
          (__attribute__((address_space(3))) void*)ldst, 16, 0, 0);
    }
    __syncthreads();
    f16x8 bf[4];
#pragma unroll
    for (int nt = 0; nt < 4; nt++) {
      int r = wc * 64 + nt * 16 + lc;
      bf[nt] = *(const f16x8*)(smem + 2 * 4096 + r * 32 + quad * 8);
    }
#pragma unroll
    for (int mt = 0; mt < 4; mt++) {
      int r = wr * 64 + mt * 16 + lc;
      f16x8 ah = *(const f16x8*)(smem + 0 * 4096 + r * 32 + quad * 8);
      f16x8 al = *(const f16x8*)(smem + 1 * 4096 + r * 32 + quad * 8);
#pragma unroll
      for (int nt = 0; nt < 4; nt++) {
        acc[mt][nt] = __builtin_amdgcn_mfma_f32_16x16x32_f16(ah, bf[nt], acc[mt][nt], 0, 0, 0);
        acc[mt][nt] = __builtin_amdgcn_mfma_f32_16x16x32_f16(al, bf[nt], acc[mt][nt], 0, 0, 0);
      }
    }
    __syncthreads();
  }

  float bv[4];
  if (BIAS) {
#pragma unroll
    for (int nt = 0; nt < 4; nt++) bv[nt] = bias[cb + wc * 64 + nt * 16 + lc];
  }
#pragma unroll
  for (int mt = 0; mt < 4; mt++) {
#pragma unroll
    for (int r = 0; r < 4; r++) {
      int gm = bm + wr * 64 + mt * 16 + quad * 4 + r;
      if (gm >= M) continue;
#pragma unroll
      for (int nt = 0; nt < 4; nt++) {
        float v = acc[mt][nt][r];
        if (BIAS) v += bv[nt];
        if (RELU) v = fmaxf(v, 0.f);
        size_t idx = (size_t)gm * ldC + cb + wc * 64 + nt * 16 + lc;
        if (OUTM == 1) {
          f16 h = (f16)v;
          Chi[idx] = h;
          Clo[idx] = (f16)(v - (float)h);
        } else if (OUTM == 2) {
          Ch[idx] = (f16)v;
        } else {
          Cf[idx] = v;
        }
      }
    }
  }
}

// ---------------- layer-3 aggregation: fp16 gather, half2 + unroll-4 ----------------
__global__ __launch_bounds__(448) void k_agg7(const f16* __restrict__ hW,
                                              const float* __restrict__ csr_norm,
                                              const float* __restrict__ dis,
                                              const int* __restrict__ rowptr,
                                              const int* __restrict__ csr_src,
                                              const float* __restrict__ bias,
                                              f16* __restrict__ outhi,
                                              f16* __restrict__ outlo) {
  int n = blockIdx.x;
  int f2 = threadIdx.x;   // handles cols 2*f2, 2*f2+1
  int i = f2 >> 6;        // wave-uniform
  const h2* hw2 = (const h2*)hW;
  const float* nrm = csr_norm + (size_t)i * NE;
  float d = dis[i * NN + n];
  h2 sv = hw2[(size_t)n * 448 + f2];
  float ax = d * d * (float)sv.x, ay = d * d * (float)sv.y;
  int s = rowptr[n], e = rowptr[n + 1];
  int p = s;
  for (; p + 4 <= e; p += 4) {
    int s0 = csr_src[p], s1 = csr_src[p + 1], s2 = csr_src[p + 2], s3 = csr_src[p + 3];
    float n0 = nrm[p], n1 = nrm[p + 1], n2 = nrm[p + 2], n3 = nrm[p + 3];
    h2 v0 = hw2[(size_t)s0 * 448 + f2];
    h2 v1 = hw2[(size_t)s1 * 448 + f2];
    h2 v2 = hw2[(size_t)s2 * 448 + f2];
    h2 v3 = hw2[(size_t)s3 * 448 + f2];
    ax = fmaf(n0, (float)v0.x, ax); ay = fmaf(n0, (float)v0.y, ay);
    ax = fmaf(n1, (float)v1.x, ax); ay = fmaf(n1, (float)v1.y, ay);
    ax = fmaf(n2, (float)v2.x, ax); ay = fmaf(n2, (float)v2.y, ay);
    ax = fmaf(n3, (float)v3.x, ax); ay = fmaf(n3, (float)v3.y, ay);
  }
  for (; p < e; p++) {
    int s0 = csr_src[p];
    float n0 = nrm[p];
    h2 v0 = hw2[(size_t)s0 * 448 + f2];
    ax = fmaf(n0, (float)v0.x, ax); ay = fmaf(n0, (float)v0.y, ay);
  }
  float vx = fmaxf(ax + bias[2 * f2], 0.f);
  float vy = fmaxf(ay + bias[2 * f2 + 1], 0.f);
  split_store_h(vx, outhi, outlo, (size_t)n * 896 + 2 * f2);
  split_store_h(vy, outhi, outlo, (size_t)n * 896 + 2 * f2 + 1);
}

// ---------------- layer-1 aggregation: fp16 gather, fp32 out, bias+relu ----------------
__global__ __launch_bounds__(256) void k_agg1(const f16* __restrict__ hW,
                                              const float* __restrict__ nrm,
                                              const float* __restrict__ dis_i,
                                              const int* __restrict__ rowptr,
                                              const int* __restrict__ csr_src,
                                              const float* __restrict__ bias,
                                              float* __restrict__ x2f) {
  int t = threadIdx.x;
  int n = blockIdx.x * 4 + (t >> 6);
  int f2 = t & 63;
  if (n >= NN) return;
  const h2* hw2 = (const h2*)hW;
  float d = dis_i[n];
  h2 sv = hw2[(size_t)n * 64 + f2];
  float ax = d * d * (float)sv.x, ay = d * d * (float)sv.y;
  int s = rowptr[n], e = rowptr[n + 1];
  int p = s;
  for (; p + 4 <= e; p += 4) {
    int s0 = csr_src[p], s1 = csr_src[p + 1], s2 = csr_src[p + 2], s3 = csr_src[p + 3];
    float n0 = nrm[p], n1 = nrm[p + 1], n2 = nrm[p + 2], n3 = nrm[p + 3];
    h2 v0 = hw2[(size_t)s0 * 64 + f2];
    h2 v1 = hw2[(size_t)s1 * 64 + f2];
    h2 v2 = hw2[(size_t)s2 * 64 + f2];
    h2 v3 = hw2[(size_t)s3 * 64 + f2];
    ax = fmaf(n0, (float)v0.x, ax); ay = fmaf(n0, (float)v0.y, ay);
    ax = fmaf(n1, (float)v1.x, ax); ay = fmaf(n1, (float)v1.y, ay);
    ax = fmaf(n2, (float)v2.x, ax); ay = fmaf(n2, (float)v2.y, ay);
    ax = fmaf(n3, (float)v3.x, ax); ay = fmaf(n3, (float)v3.y, ay);
  }
  for (; p < e; p++) {
    int s0 = csr_src[p];
    float n0 = nrm[p];
    h2 v0 = hw2[(size_t)s0 * 64 + f2];
    ax = fmaf(n0, (float)v0.x, ax); ay = fmaf(n0, (float)v0.y, ay);
  }
  x2f[(size_t)n * 128 + 2 * f2] = fmaxf(ax + bias[2 * f2], 0.f);
  x2f[(size_t)n * 128 + 2 * f2 + 1] = fmaxf(ay + bias[2 * f2 + 1], 0.f);
}

// ---------------- layer-2 aggregate-first: gather x2 once, 7 norms ----------------
__global__ __launch_bounds__(256) void k_agg2(const float* __restrict__ x2f,
                                              const float* __restrict__ csr_norm,
                                              const float* __restrict__ dis,
                                              const int* __restrict__ rowptr,
                                              const int* __restrict__ csr_src,
                                              f16* __restrict__ ohi,
                                              f16* __restrict__ olo) {
  int t = threadIdx.x;
  int n = blockIdx.x * 4 + (t >> 6);
  int f2 = t & 63;
  if (n >= NN) return;
  const float2* x2 = (const float2*)x2f;
  float2 sv = x2[(size_t)n * 64 + f2];
  float ax[7], ay[7];
#pragma unroll
  for (int i = 0; i < 7; i++) {
    float d = dis[i * NN + n];
    ax[i] = d * d * sv.x;
    ay[i] = d * d * sv.y;
  }
  int s = rowptr[n], e = rowptr[n + 1];
  int p = s;
  for (; p + 2 <= e; p += 2) {
    int s0 = csr_src[p], s1 = csr_src[p + 1];
    float2 v0 = x2[(size_t)s0 * 64 + f2];
    float2 v1 = x2[(size_t)s1 * 64 + f2];
#pragma unroll
    for (int i = 0; i < 7; i++) {
      float n0 = csr_norm[(size_t)i * NE + p];
      float n1 = csr_norm[(size_t)i * NE + p + 1];
      ax[i] = fmaf(n0, v0.x, ax[i]); ay[i] = fmaf(n0, v0.y, ay[i]);
      ax[i] = fmaf(n1, v1.x, ax[i]); ay[i] = fmaf(n1, v1.y, ay[i]);
    }
  }
  for (; p < e; p++) {
    int s0 = csr_src[p];
    float2 v0 = x2[(size_t)s0 * 64 + f2];
#pragma unroll
    for (int i = 0; i < 7; i++) {
      float n0 = csr_norm[(size_t)i * NE + p];
      ax[i] = fmaf(n0, v0.x, ax[i]); ay[i] = fmaf(n0, v0.y, ay[i]);
    }
  }
#pragma unroll
  for (int i = 0; i < 7; i++) {
    split_store_h(ax[i], ohi, olo, (size_t)n * 896 + i * 128 + 2 * f2);
    split_store_h(ay[i], ohi, olo, (size_t)n * 896 + i * 128 + 2 * f2 + 1);
  }
}

// ---------------- layer 0: aggregate-first (x is only [N,8]) ----------------
__global__ __launch_bounds__(64) void k_agg_x(const float* __restrict__ x,
                                              const float* __restrict__ csr_norm,
                                              const float* __restrict__ dis,
                                              const int* __restrict__ rowptr,
                                              const int* __restrict__ csr_src,
                                              float* __restrict__ xagg) {
  int n = blockIdx.x;
  int f = threadIdx.x;
  if (f >= 56) return;
  int i = f >> 3, c = f & 7;
  float d = dis[i * NN + n];
  float acc = d * d * x[(size_t)n * 8 + c];
  int s = rowptr[n], e = rowptr[n + 1];
  for (int p = s; p < e; p++)
    acc = fmaf(csr_norm[i * NE + p], x[(size_t)csr_src[p] * 8 + c], acc);
  xagg[(size_t)n * 56 + f] = acc;
}

// x1[n, i*128+h] = relu(b0[i][h] + sum_c xagg[n][i*8+c] * W0[i][c][h]), fp16 hi/lo out
__global__ __launch_bounds__(896) void k_gemm0(const float* __restrict__ xagg,
                                               const float* __restrict__ W0,
                                               const float* __restrict__ b0,
                                               f16* __restrict__ outhi,
                                               f16* __restrict__ outlo) {
  int n = blockIdx.x;
  int f = threadIdx.x;
  int i = f >> 7, h = f & 127;
  float s = b0[i * 128 + h];
#pragma unroll
  for (int c = 0; c < 8; c++)
    s = fmaf(xagg[(size_t)n * 56 + i * 8 + c], W0[(i * 8 + c) * 128 + h], s);
  float v = fmaxf(s, 0.f);
  split_store_h(v, outhi, outlo, (size_t)n * 896 + f);
}

// ---------------- fused link MLP: gather + 3 MFMA layers + output, H in LDS ----
// Block: 256 threads (4 waves) owns 32 test-pairs = 64 H-rows (dir 0/1 adjacent).
// H kept as fp16 hi/lo planes in LDS (padded stride HP); per-layer W staged to
// LDS (padded). Wave w computes rows w*16..w*16+15 only (no cross-wave H deps).
__global__ __launch_bounds__(256) void k_link_fused(
    const float* __restrict__ UV, const int* __restrict__ eit,
    const float* __restrict__ lb0, const f16* __restrict__ lwht,
    const float* __restrict__ lbh, const float* __restrict__ lw4,
    const float* __restrict__ lb4, float* __restrict__ out) {
  __shared__ f16 Hhi[64 * HP];
  __shared__ f16 Hlo[64 * HP];
  __shared__ f16 Wt[128 * HP];
  __shared__ float ob[64][4];
  const int tid = threadIdx.x;
  const int t0 = blockIdx.x * 32;
  // build H0: 64 rows; rr = 2*pair + dir. Coalesced 512B UV row reads.
  {
    int c = tid & 127;
    int rbase = tid >> 7;  // 0 or 1
    for (int it = 0; it < 32; it++) {
      int rr = rbase + it * 2;
      int tp = t0 + (rr >> 1), dir = rr & 1;
      int s = eit[tp], d = eit[NT + tp];
      int a = dir ? d : s, b = dir ? s : d;
      float v = UV[(size_t)a * 256 + c] + UV[(size_t)b * 256 + 128 + c] + lb0[c];
      v = fmaxf(v, 0.f);
      f16 h = (f16)v;
      Hhi[rr * HP + c] = h;
      Hlo[rr * HP + c] = (f16)(v - (float)h);
    }
  }
  const int w = tid >> 6, lane = tid & 63;
  const int quad = lane >> 4, lc = lane & 15;
  for (int l = 0; l < 3; l++) {
    __syncthreads();  // prior Wt reads + H writes complete
    {                 // stage W(l): [n][k] fp16 -> padded LDS
      const f16* src = lwht + (size_t)l * 128 * 128;
#pragma unroll
      for (int it = 0; it < 8; it++) {
        int idx = (tid + it * 256) * 8;
        int n = idx >> 7, k = idx & 127;
        *(float4*)&Wt[n * HP + k] = *(const float4*)&src[idx];
      }
    }
    __syncthreads();
    f32x4 acc[8] = {};
    const int arow = w * 16 + lc;
#pragma unroll
    for (int k0 = 0; k0 < 128; k0 += 32) {
      f16x8 ah = *(const f16x8*)&Hhi[arow * HP + k0 + quad * 8];
      f16x8 al = *(const f16x8*)&Hlo[arow * HP + k0 + quad * 8];
#pragma unroll
      for (int nt = 0; nt < 8; nt++) {
        f16x8 bf = *(const f16x8*)&Wt[(nt * 16 + lc) * HP + k0 + quad * 8];
        acc[nt] = __builtin_amdgcn_mfma_f32_16x16x32_f16(ah, bf, acc[nt], 0, 0, 0);
        acc[nt] = __builtin_amdgcn_mfma_f32_16x16x32_f16(al, bf, acc[nt], 0, 0, 0);
      }
    }
    // write back own rows (C-layout: row=quad*4+r, col=nt*16+lc); per-wave
    // in-order LDS ops make read-before-write safe within the wave.
#pragma unroll
    for (int nt = 0; nt < 8; nt++) {
      int col = nt * 16 + lc;
      float bb = lbh[l * 128 + col];
#pragma unroll
      for (int r = 0; r < 4; r++) {
        int rrow = w * 16 + quad * 4 + r;
        float v = fmaxf(acc[nt][r] + bb, 0.f);
        f16 h = (f16)v;
        Hhi[rrow * HP + col] = h;
        Hlo[rrow * HP + col] = (f16)(v - (float)h);
      }
    }
  }
  __syncthreads();
  // final dot: o[rr][j] = lb4[j] + sum_k H[rr][k] * lw4[k*4+j]
  {
    int rr = tid >> 2, j = tid & 3;
    float o = lb4[j];
    for (int k = 0; k < 128; k++) {
      float hv = (float)Hhi[rr * HP + k] + (float)Hlo[rr * HP + k];
      o = fmaf(hv, lw4[k * 4 + j], o);
    }
    ob[rr][j] = o;
  }
  __syncthreads();
  if (tid < 128) {
    int tp = tid >> 2, j = tid & 3;
    const int perm[4] = {0, 2, 1, 3};  // t2 column permutation
    out[(size_t)(t0 + tp) * 4 + j] = 0.5f * (ob[2 * tp][j] + ob[2 * tp + 1][perm[j]]);
  }
}

// ---------------- host ----------------
extern "C" void kernel_launch(void* const* d_in, const int* in_sizes, int n_in,
                              void* d_out, int out_size, void* d_ws, size_t ws_size,
                              hipStream_t stream) {
  const float* x   = (const float*)d_in[0];
  const int*   ei  = (const int*)d_in[1];
  const float* ea  = (const float*)d_in[2];
  const int*   eit = (const int*)d_in[3];
  const float* W0  = (const float*)d_in[4];
  const float* b0  = (const float*)d_in[5];
  const float* W1  = (const float*)d_in[6];
  const float* b1  = (const float*)d_in[7];
  const float* W2  = (const float*)d_in[8];
  const float* b2  = (const float*)d_in[9];
  const float* W3  = (const float*)d_in[10];
  const float* b3  = (const float*)d_in[11];
  const float* ew1 = (const float*)d_in[12];
  const float* eb1 = (const float*)d_in[13];
  const float* ew2 = (const float*)d_in[14];
  const float* eb2 = (const float*)d_in[15];
  const float* ew3 = (const float*)d_in[16];
  const float* eb3 = (const float*)d_in[17];
  const float* lw0 = (const float*)d_in[18];
  const float* lb0 = (const float*)d_in[19];
  const float* lwh = (const float*)d_in[20];
  const float* lbh = (const float*)d_in[21];
  const float* lw4 = (const float*)d_in[22];
  const float* lb4 = (const float*)d_in[23];
  const int* row = ei;
  const int* col = ei + NE;
  float* out = (float*)d_out;

  char* ws = (char*)d_ws;
  size_t off = 0;
  auto alloc = [&](size_t bytes) -> char* {
    char* p = ws + off;
    off += (bytes + 255) & ~(size_t)255;
    return p;
  };
  f16*   xAhi   = (f16*)alloc((size_t)NN * 896 * 2);
  f16*   xAlo   = (f16*)alloc((size_t)NN * 896 * 2);
  float* xB     = (float*)alloc((size_t)NN * 896 * 4);
  float* x2f    = (float*)alloc((size_t)NN * 128 * 4);
  float* UV     = (float*)alloc((size_t)NN * 256 * 4);  // xagg overlays front
  float* csr_nrm= (float*)alloc((size_t)8 * NE * 4);
  float* dis    = (float*)alloc((size_t)8 * NN * 4);
  float* ewb    = (float*)alloc((size_t)NE * 4);
  int*   rowptr = (int*)alloc((size_t)(NN + 1) * 4);
  int*   cursor = (int*)alloc((size_t)NN * 4);
  int*   eid    = (int*)alloc((size_t)NE * 4);
  int*   csr_src= (int*)alloc((size_t)NE * 4);
  f16* w1t  = (f16*)alloc((size_t)128 * 896 * 2);
  f16* w2t  = (f16*)alloc((size_t)7 * 128 * 128 * 2);
  f16* w3t  = (f16*)alloc((size_t)7 * 128 * 896 * 2);
  f16* lw0t = (f16*)alloc((size_t)2 * 128 * 896 * 2);
  f16* lwht = (f16*)alloc((size_t)3 * 128 * 128 * 2);
  float* xagg = UV;  // [NN][56] fp32, dead before UV written
  (void)ws_size; (void)in_sizes; (void)n_in; (void)out_size;

  const int EB = (NE + 255) / 256;
  const int GX = (NN + 127) / 128;   // 157
  const int MC = (GX + 7) / 8;       // 20 row-tiles max per XCD

  // weight prep (independent)
  k_wprep<<<dim3(448, 1), 256, 0, stream>>>(W1, 128, 0, 896, w1t);
  k_wprep<<<dim3(64, 7), 256, 0, stream>>>(W2, 128, (size_t)128 * 128, 128, w2t);
  k_wprep<<<dim3(448, 7), 256, 0, stream>>>(W3, 128, (size_t)896 * 128, 896, w3t);
  // lw0 is [1792][128]: U = rows 0..895, V = rows 896..1791
  k_wprep<<<dim3(448, 2), 256, 0, stream>>>(lw0, 128, (size_t)896 * 128, 896, lw0t);
  k_wprep<<<dim3(64, 3), 256, 0, stream>>>(lwh, 128, (size_t)128 * 128, 128, lwht);

  // edge weight + CSR count (fused) -> scan (rowptr+cursor) -> fill -> degrees -> norms
  hipMemsetAsync(cursor, 0, (size_t)NN * 4, stream);
  k_edge_mlp<<<EB, 256, 0, stream>>>(ea, ew1, eb1, ew2, eb2, ew3, eb3, col, ewb, cursor);
  k_scan<<<1, 256, 0, stream>>>(cursor, rowptr);
  k_fill_csr<<<EB, 256, 0, stream>>>(col, cursor, eid);
  k_deg_csr<<<(NN + 7) / 8, 64, 0, stream>>>(rowptr, eid, ea, ewb, dis);
  k_csr_norms<<<EB, 256, 0, stream>>>(eid, row, col, ea, ewb, dis, csr_src, csr_nrm);

  // Layer 0 (aggregate-first): xagg [N,7,8] -> x1 hi/lo (xA)
  k_agg_x<<<NN, 64, 0, stream>>>(x, csr_nrm, dis, rowptr, csr_src, xagg);
  k_gemm0<<<NN, 896, 0, stream>>>(xagg, W0, b0, xAhi, xAlo);

  // Layer 1: x1 @ W1 -> hW1 fp16 (xB); agg1 (learned ew, bias+relu) -> x2f
  f16* hW1 = (f16*)xB;
  k_mgemm<2, false, false, false, false><<<dim3(GX, 1), 256, 0, stream>>>(
      xAhi, xAlo, w1t, nullptr, nullptr, nullptr, nullptr, hW1,
      896, NN, 896, 1, GX);
  k_agg1<<<(NN + 3) / 4, 256, 0, stream>>>(hW1, csr_nrm + (size_t)7 * NE,
                                           dis + (size_t)7 * NN, rowptr, csr_src, b1, x2f);

  // Layer 2 (aggregate-first): xagg2 = A_i * x2 (7 relations, fp16 hi/lo into xB),
  // then x3 = relu(xagg2_i @ W2_i + b2_i) via GROUP_A GEMM -> xA hi/lo
  f16* xagg2hi = (f16*)xB;
  f16* xagg2lo = xagg2hi + (size_t)NN * 896;
  k_agg2<<<(NN + 3) / 4, 256, 0, stream>>>(x2f, csr_nrm, dis, rowptr, csr_src,
                                           xagg2hi, xagg2lo);
  k_mgemm<1, true, true, true, false><<<dim3(GX, 7), 256, 0, stream>>>(
      xagg2hi, xagg2lo, w2t, b2, nullptr, xAhi, xAlo, nullptr,
      896, NN, 128, 7, GX);

  // Layer 3: x3 @ W3 (7 mats, K=896, XCD-swizzled) -> hW3 fp16 (xB);
  // agg7 -> x4 hi/lo (xA)
  f16* hW3 = (f16*)xB;
  k_mgemm<2, false, false, false, true><<<dim3(8 * MC * 7), 256, 0, stream>>>(
      xAhi, xAlo, w3t, nullptr, nullptr, nullptr, nullptr, hW3,
      896, NN, 896, 7, GX);
  k_agg7<<<NN, 448, 0, stream>>>(hW3, csr_nrm, dis, rowptr, csr_src, b3, xAhi, xAlo);

  // Link precompute: UV = x4 @ [lw0_top | lw0_bot]  (XCD-swizzled, NG=2)
  k_mgemm<0, false, false, false, true><<<dim3(8 * MC * 2), 256, 0, stream>>>(
      xAhi, xAlo, lw0t, nullptr, UV, nullptr, nullptr, nullptr,
      896, NN, 896, 2, GX);

  // Fused link MLP: gather + 3 layers + output dot, H resident in LDS
  k_link_fused<<<NT / 32, 256, 0, stream>>>(UV, eit, lb0, lwht, lbh, lw4, lb4, out);
}

// Round 9
// 598.589 us; speedup vs baseline: 6.2449x; 1.1005x over previous
//
#include <hip/hip_runtime.h>
#include <math.h>

#define NN 20000
#define NE 200000
#define NT 40000
#define HP 136  // padded LDS row stride (fp16) for link H/W tiles

typedef _Float16 f16;
typedef __attribute__((ext_vector_type(8))) _Float16 f16x8;
typedef __attribute__((ext_vector_type(4))) float f32x4;
typedef __attribute__((ext_vector_type(2))) _Float16 h2;

// ---------------- edge weight MLP (+ CSR count fused) ----------------
__global__ void k_edge_mlp(const float* __restrict__ ea,
                           const float* __restrict__ w1, const float* __restrict__ b1,
                           const float* __restrict__ w2, const float* __restrict__ b2,
                           const float* __restrict__ w3, const float* __restrict__ b3,
                           const int* __restrict__ col,
                           float* __restrict__ out, int* __restrict__ cnt) {
  int e = blockIdx.x * 256 + threadIdx.x;
  if (e >= NE) return;
  atomicAdd(&cnt[col[e]], 1);
  float a[7];
#pragma unroll
  for (int i = 0; i < 7; i++) a[i] = ea[e * 7 + i];
  float t1[28];
#pragma unroll
  for (int j = 0; j < 28; j++) {
    float s = b1[j];
#pragma unroll
    for (int k = 0; k < 7; k++) s = fmaf(a[k], w1[k * 28 + j], s);
    t1[j] = fmaxf(s, 0.f);
  }
  float t2[28];
  for (int j = 0; j < 28; j++) {
    float s = b2[j];
    for (int k = 0; k < 28; k++) s = fmaf(t1[k], w2[k * 28 + j], s);
    t2[j] = fmaxf(s, 0.f);
  }
  float s = b3[0];
  for (int k = 0; k < 28; k++) s = fmaf(t2[k], w3[k], s);
  out[e] = 1.f / (1.f + expf(-s));
}

// ---------------- CSR scan: rowptr + cursor in one pass ----------------
__global__ void k_scan(int* __restrict__ cnt, int* __restrict__ rowptr) {
  __shared__ int sums[256];
  __shared__ int offs[256];
  int t = threadIdx.x;
  const int CH = (NN + 255) / 256;
  int base = t * CH;
  int s = 0;
  for (int i = 0; i < CH; i++) { int idx = base + i; if (idx < NN) s += cnt[idx]; }
  sums[t] = s;
  __syncthreads();
  if (t == 0) {
    int acc = 0;
    for (int i = 0; i < 256; i++) { offs[i] = acc; acc += sums[i]; }
    rowptr[NN] = acc;
  }
  __syncthreads();
  int acc = offs[t];
  for (int i = 0; i < CH; i++) {
    int idx = base + i;
    if (idx < NN) {
      int cv = cnt[idx];
      rowptr[idx] = acc;
      cnt[idx] = acc;  // becomes the fill cursor
      acc += cv;
    }
  }
}

__global__ void k_fill_csr(const int* __restrict__ col, int* __restrict__ cursor,
                           int* __restrict__ eid) {
  int e = blockIdx.x * 256 + threadIdx.x;
  if (e >= NE) return;
  int pos = atomicAdd(&cursor[col[e]], 1);
  eid[pos] = e;
}

// degrees from CSR (no float atomics). 8 nodes x 8 relations per 64-thread block.
__global__ __launch_bounds__(64) void k_deg_csr(const int* __restrict__ rowptr,
                                                const int* __restrict__ eid,
                                                const float* __restrict__ ea,
                                                const float* __restrict__ ewb,
                                                float* __restrict__ dis) {
  int t = threadIdx.x;
  int n = blockIdx.x * 8 + (t >> 3);
  int i = t & 7;
  if (n >= NN) return;
  float deg = 1.f;  // self-loop weight
  int s = rowptr[n], e2 = rowptr[n + 1];
  for (int p = s; p < e2; p++) {
    int e = eid[p];
    deg += (i < 7) ? ea[e * 7 + i] : ewb[e];
  }
  dis[i * NN + n] = rsqrtf(deg);  // deg >= 1 always
}

__global__ void k_csr_norms(const int* __restrict__ eid, const int* __restrict__ row,
                            const int* __restrict__ col, const float* __restrict__ ea,
                            const float* __restrict__ ew, const float* __restrict__ dis,
                            int* __restrict__ csr_src, float* __restrict__ csr_norm) {
  int p = blockIdx.x * 256 + threadIdx.x;
  if (p >= NE) return;
  int e = eid[p];
  int r = row[e], c = col[e];
  csr_src[p] = r;
#pragma unroll
  for (int i = 0; i < 7; i++)
    csr_norm[i * NE + p] = dis[i * NN + r] * ea[e * 7 + i] * dis[i * NN + c];
  csr_norm[7 * NE + p] = dis[7 * NN + r] * ew[e] * dis[7 * NN + c];
}

// ---------------- weight prep: transpose + fp16 quantize ----------------
__global__ void k_wprep(const float* __restrict__ W, int ldW, size_t matOff, int K,
                        f16* __restrict__ WT) {
  int g = blockIdx.y;
  int idx = blockIdx.x * 256 + threadIdx.x;
  if (idx >= K * 128) return;
  int k = idx >> 7, n = idx & 127;
  float v = W[(size_t)g * matOff + (size_t)k * ldW + n];
  WT[(size_t)g * 128 * K + (size_t)n * K + k] = (f16)v;
}

// ---------------- fp16 MFMA GEMM (1-term) ----------------
// C = A @ B^T_g, fp32 acc; A and B fp16. OUTM: 0 = fp32 out, 1 = fp16 out.
// SWIZZLE: 1-D grid, XCD-aware decode — all NG column-groups of one 128-row
// A-panel run consecutively on the same XCD (b&7) -> panel L2-resident.
template <int OUTM, bool RELU, bool BIAS, bool GROUP_A, bool SWIZZLE>
__global__ __launch_bounds__(256) void k_mgemm(
    const f16* __restrict__ A, const f16* __restrict__ BT,
    const float* __restrict__ bias,
    float* __restrict__ Cf, f16* __restrict__ Ch,
    int ldA, int M, int K, int NG, int GXp) {
  int rowT, g;
  if (SWIZZLE) {
    int b = blockIdx.x;
    int xcd = b & 7, s = b >> 3;
    g = s % NG;
    int lr = s / NG;
    rowT = lr * 8 + xcd;
    if (rowT >= GXp) return;  // uniform early-out (padded grid)
  } else {
    rowT = blockIdx.x;
    g = blockIdx.y;
  }
  __shared__ f16 smem[8192];  // 2 tiles [128 rows][32 k] fp16: A, B
  const int tid = threadIdx.x;
  const int w = tid >> 6, lane = tid & 63;
  const int quad = lane >> 4, lc = lane & 15;
  const int wr = w >> 1, wc = w & 1;
  const int bm = rowT * 128;
  const int ldC = NG * 128;
  const int cb = g * 128;
  const int aoff = GROUP_A ? g * K : 0;
  const f16* Bg = BT + (size_t)g * 128 * K;
  const int srow = lane >> 2, skoff = (lane & 3) * 8;

  f32x4 acc[4][4] = {};

  for (int k0 = 0; k0 < K; k0 += 32) {
    // stage 16KB: 16 chunks of 1024B (16 rows x 64B), 4 per wave
#pragma unroll
    for (int l = 0; l < 4; l++) {
      int c = w + l * 4;
      int t = c >> 3, r16 = c & 7;
      int rowi = r16 * 16 + srow;
      f16* ldst = smem + t * 4096 + r16 * 512;  // +lane*16B implicit
      const f16* src;
      if (t == 0) {
        int gm = bm + rowi;
        if (gm > M - 1) gm = M - 1;  // clamp; guarded at store
        src = A + (size_t)gm * ldA + aoff + k0 + skoff;
      } else {
        src = Bg + (size_t)rowi * K + k0 + skoff;
      }
      __builtin_amdgcn_global_load_lds(
          (const __attribute__((address_space(1))) void*)src,
          (__attribute__((address_space(3))) void*)ldst, 16, 0, 0);
    }
    __syncthreads();
    f16x8 bf[4];
#pragma unroll
    for (int nt = 0; nt < 4; nt++) {
      int r = wc * 64 + nt * 16 + lc;
      bf[nt] = *(const f16x8*)(smem + 4096 + r * 32 + quad * 8);
    }
#pragma unroll
    for (int mt = 0; mt < 4; mt++) {
      int r = wr * 64 + mt * 16 + lc;
      f16x8 ah = *(const f16x8*)(smem + r * 32 + quad * 8);
#pragma unroll
      for (int nt = 0; nt < 4; nt++) {
        acc[mt][nt] = __builtin_amdgcn_mfma_f32_16x16x32_f16(ah, bf[nt], acc[mt][nt], 0, 0, 0);
      }
    }
    __syncthreads();
  }

  float bv[4];
  if (BIAS) {
#pragma unroll
    for (int nt = 0; nt < 4; nt++) bv[nt] = bias[cb + wc * 64 + nt * 16 + lc];
  }
#pragma unroll
  for (int mt = 0; mt < 4; mt++) {
#pragma unroll
    for (int r = 0; r < 4; r++) {
      int gm = bm + wr * 64 + mt * 16 + quad * 4 + r;
      if (gm >= M) continue;
#pragma unroll
      for (int nt = 0; nt < 4; nt++) {
        float v = acc[mt][nt][r];
        if (BIAS) v += bv[nt];
        if (RELU) v = fmaxf(v, 0.f);
        size_t idx = (size_t)gm * ldC + cb + wc * 64 + nt * 16 + lc;
        if (OUTM == 1) Ch[idx] = (f16)v;
        else Cf[idx] = v;
      }
    }
  }
}

// ---------------- layer-3 aggregation: fp16 gather, half2 + unroll-4 ----------------
__global__ __launch_bounds__(448) void k_agg7(const f16* __restrict__ hW,
                                              const float* __restrict__ csr_norm,
                                              const float* __restrict__ dis,
                                              const int* __restrict__ rowptr,
                                              const int* __restrict__ csr_src,
                                              const float* __restrict__ bias,
                                              f16* __restrict__ outq) {
  int n = blockIdx.x;
  int f2 = threadIdx.x;   // handles cols 2*f2, 2*f2+1
  int i = f2 >> 6;        // wave-uniform
  const h2* hw2 = (const h2*)hW;
  const float* nrm = csr_norm + (size_t)i * NE;
  float d = dis[i * NN + n];
  h2 sv = hw2[(size_t)n * 448 + f2];
  float ax = d * d * (float)sv.x, ay = d * d * (float)sv.y;
  int s = rowptr[n], e = rowptr[n + 1];
  int p = s;
  for (; p + 4 <= e; p += 4) {
    int s0 = csr_src[p], s1 = csr_src[p + 1], s2 = csr_src[p + 2], s3 = csr_src[p + 3];
    float n0 = nrm[p], n1 = nrm[p + 1], n2 = nrm[p + 2], n3 = nrm[p + 3];
    h2 v0 = hw2[(size_t)s0 * 448 + f2];
    h2 v1 = hw2[(size_t)s1 * 448 + f2];
    h2 v2 = hw2[(size_t)s2 * 448 + f2];
    h2 v3 = hw2[(size_t)s3 * 448 + f2];
    ax = fmaf(n0, (float)v0.x, ax); ay = fmaf(n0, (float)v0.y, ay);
    ax = fmaf(n1, (float)v1.x, ax); ay = fmaf(n1, (float)v1.y, ay);
    ax = fmaf(n2, (float)v2.x, ax); ay = fmaf(n2, (float)v2.y, ay);
    ax = fmaf(n3, (float)v3.x, ax); ay = fmaf(n3, (float)v3.y, ay);
  }
  for (; p < e; p++) {
    int s0 = csr_src[p];
    float n0 = nrm[p];
    h2 v0 = hw2[(size_t)s0 * 448 + f2];
    ax = fmaf(n0, (float)v0.x, ax); ay = fmaf(n0, (float)v0.y, ay);
  }
  h2 o;
  o.x = (f16)fmaxf(ax + bias[2 * f2], 0.f);
  o.y = (f16)fmaxf(ay + bias[2 * f2 + 1], 0.f);
  ((h2*)outq)[(size_t)n * 448 + f2] = o;
}

// ---------------- layer-1 aggregation: fp16 gather, fp32 out, bias+relu ----------------
__global__ __launch_bounds__(256) void k_agg1(const f16* __restrict__ hW,
                                              const float* __restrict__ nrm,
                                              const float* __restrict__ dis_i,
                                              const int* __restrict__ rowptr,
                                              const int* __restrict__ csr_src,
                                              const float* __restrict__ bias,
                                              float* __restrict__ x2f) {
  int t = threadIdx.x;
  int n = blockIdx.x * 4 + (t >> 6);
  int f2 = t & 63;
  if (n >= NN) return;
  const h2* hw2 = (const h2*)hW;
  float d = dis_i[n];
  h2 sv = hw2[(size_t)n * 64 + f2];
  float ax = d * d * (float)sv.x, ay = d * d * (float)sv.y;
  int s = rowptr[n], e = rowptr[n + 1];
  int p = s;
  for (; p + 4 <= e; p += 4) {
    int s0 = csr_src[p], s1 = csr_src[p + 1], s2 = csr_src[p + 2], s3 = csr_src[p + 3];
    float n0 = nrm[p], n1 = nrm[p + 1], n2 = nrm[p + 2], n3 = nrm[p + 3];
    h2 v0 = hw2[(size_t)s0 * 64 + f2];
    h2 v1 = hw2[(size_t)s1 * 64 + f2];
    h2 v2 = hw2[(size_t)s2 * 64 + f2];
    h2 v3 = hw2[(size_t)s3 * 64 + f2];
    ax = fmaf(n0, (float)v0.x, ax); ay = fmaf(n0, (float)v0.y, ay);
    ax = fmaf(n1, (float)v1.x, ax); ay = fmaf(n1, (float)v1.y, ay);
    ax = fmaf(n2, (float)v2.x, ax); ay = fmaf(n2, (float)v2.y, ay);
    ax = fmaf(n3, (float)v3.x, ax); ay = fmaf(n3, (float)v3.y, ay);
  }
  for (; p < e; p++) {
    int s0 = csr_src[p];
    float n0 = nrm[p];
    h2 v0 = hw2[(size_t)s0 * 64 + f2];
    ax = fmaf(n0, (float)v0.x, ax); ay = fmaf(n0, (float)v0.y, ay);
  }
  x2f[(size_t)n * 128 + 2 * f2] = fmaxf(ax + bias[2 * f2], 0.f);
  x2f[(size_t)n * 128 + 2 * f2 + 1] = fmaxf(ay + bias[2 * f2 + 1], 0.f);
}

// ---------------- layer-2 aggregate-first: gather x2 once, 7 norms ----------------
__global__ __launch_bounds__(256) void k_agg2(const float* __restrict__ x2f,
                                              const float* __restrict__ csr_norm,
                                              const float* __restrict__ dis,
                                              const int* __restrict__ rowptr,
                                              const int* __restrict__ csr_src,
                                              f16* __restrict__ oq) {
  int t = threadIdx.x;
  int n = blockIdx.x * 4 + (t >> 6);
  int f2 = t & 63;
  if (n >= NN) return;
  const float2* x2 = (const float2*)x2f;
  float2 sv = x2[(size_t)n * 64 + f2];
  float ax[7], ay[7];
#pragma unroll
  for (int i = 0; i < 7; i++) {
    float d = dis[i * NN + n];
    ax[i] = d * d * sv.x;
    ay[i] = d * d * sv.y;
  }
  int s = rowptr[n], e = rowptr[n + 1];
  int p = s;
  for (; p + 2 <= e; p += 2) {
    int s0 = csr_src[p], s1 = csr_src[p + 1];
    float2 v0 = x2[(size_t)s0 * 64 + f2];
    float2 v1 = x2[(size_t)s1 * 64 + f2];
#pragma unroll
    for (int i = 0; i < 7; i++) {
      float n0 = csr_norm[(size_t)i * NE + p];
      float n1 = csr_norm[(size_t)i * NE + p + 1];
      ax[i] = fmaf(n0, v0.x, ax[i]); ay[i] = fmaf(n0, v0.y, ay[i]);
      ax[i] = fmaf(n1, v1.x, ax[i]); ay[i] = fmaf(n1, v1.y, ay[i]);
    }
  }
  for (; p < e; p++) {
    int s0 = csr_src[p];
    float2 v0 = x2[(size_t)s0 * 64 + f2];
#pragma unroll
    for (int i = 0; i < 7; i++) {
      float n0 = csr_norm[(size_t)i * NE + p];
      ax[i] = fmaf(n0, v0.x, ax[i]); ay[i] = fmaf(n0, v0.y, ay[i]);
    }
  }
#pragma unroll
  for (int i = 0; i < 7; i++) {
    h2 o;
    o.x = (f16)ax[i];
    o.y = (f16)ay[i];
    ((h2*)oq)[(size_t)n * 448 + i * 64 + f2] = o;
  }
}

// ---------------- layer 0: aggregate-first (x is only [N,8]) ----------------
__global__ __launch_bounds__(64) void k_agg_x(const float* __restrict__ x,
                                              const float* __restrict__ csr_norm,
                                              const float* __restrict__ dis,
                                              const int* __restrict__ rowptr,
                                              const int* __restrict__ csr_src,
                                              float* __restrict__ xagg) {
  int n = blockIdx.x;
  int f = threadIdx.x;
  if (f >= 56) return;
  int i = f >> 3, c = f & 7;
  float d = dis[i * NN + n];
  float acc = d * d * x[(size_t)n * 8 + c];
  int s = rowptr[n], e = rowptr[n + 1];
  for (int p = s; p < e; p++)
    acc = fmaf(csr_norm[i * NE + p], x[(size_t)csr_src[p] * 8 + c], acc);
  xagg[(size_t)n * 56 + f] = acc;
}

// x1[n, i*128+h] = relu(b0[i][h] + sum_c xagg[n][i*8+c] * W0[i][c][h]), fp16 out
__global__ __launch_bounds__(896) void k_gemm0(const float* __restrict__ xagg,
                                               const float* __restrict__ W0,
                                               const float* __restrict__ b0,
                                               f16* __restrict__ outq) {
  int n = blockIdx.x;
  int f = threadIdx.x;
  int i = f >> 7, h = f & 127;
  float s = b0[i * 128 + h];
#pragma unroll
  for (int c = 0; c < 8; c++)
    s = fmaf(xagg[(size_t)n * 56 + i * 8 + c], W0[(i * 8 + c) * 128 + h], s);
  outq[(size_t)n * 896 + f] = (f16)fmaxf(s, 0.f);
}

// ---------------- fused link MLP: gather + 3 MFMA layers + output, H in LDS ----
// Block: 256 threads (4 waves) owns 32 test-pairs = 64 H-rows (dir 0/1 adjacent).
// H kept as fp16 hi/lo planes in LDS (precision-preserving); per-layer W staged
// padded. Wave w computes rows w*16..w*16+15 only (no cross-wave H deps).
__global__ __launch_bounds__(256) void k_link_fused(
    const float* __restrict__ UV, const int* __restrict__ eit,
    const float* __restrict__ lb0, const f16* __restrict__ lwht,
    const float* __restrict__ lbh, const float* __restrict__ lw4,
    const float* __restrict__ lb4, float* __restrict__ out) {
  __shared__ f16 Hhi[64 * HP];
  __shared__ f16 Hlo[64 * HP];
  __shared__ f16 Wt[128 * HP];
  __shared__ float ob[64][4];
  const int tid = threadIdx.x;
  const int t0 = blockIdx.x * 32;
  // build H0: 64 rows; rr = 2*pair + dir. Coalesced 512B UV row reads.
  {
    int c = tid & 127;
    int rbase = tid >> 7;  // 0 or 1
    for (int it = 0; it < 32; it++) {
      int rr = rbase + it * 2;
      int tp = t0 + (rr >> 1), dir = rr & 1;
      int s = eit[tp], d = eit[NT + tp];
      int a = dir ? d : s, b = dir ? s : d;
      float v = UV[(size_t)a * 256 + c] + UV[(size_t)b * 256 + 128 + c] + lb0[c];
      v = fmaxf(v, 0.f);
      f16 h = (f16)v;
      Hhi[rr * HP + c] = h;
      Hlo[rr * HP + c] = (f16)(v - (float)h);
    }
  }
  const int w = tid >> 6, lane = tid & 63;
  const int quad = lane >> 4, lc = lane & 15;
  for (int l = 0; l < 3; l++) {
    __syncthreads();  // prior Wt reads + H writes complete
    {                 // stage W(l): [n][k] fp16 -> padded LDS
      const f16* src = lwht + (size_t)l * 128 * 128;
#pragma unroll
      for (int it = 0; it < 8; it++) {
        int idx = (tid + it * 256) * 8;
        int n = idx >> 7, k = idx & 127;
        *(float4*)&Wt[n * HP + k] = *(const float4*)&src[idx];
      }
    }
    __syncthreads();
    f32x4 acc[8] = {};
    const int arow = w * 16 + lc;
#pragma unroll
    for (int k0 = 0; k0 < 128; k0 += 32) {
      f16x8 ah = *(const f16x8*)&Hhi[arow * HP + k0 + quad * 8];
      f16x8 al = *(const f16x8*)&Hlo[arow * HP + k0 + quad * 8];
#pragma unroll
      for (int nt = 0; nt < 8; nt++) {
        f16x8 bf = *(const f16x8*)&Wt[(nt * 16 + lc) * HP + k0 + quad * 8];
        acc[nt] = __builtin_amdgcn_mfma_f32_16x16x32_f16(ah, bf, acc[nt], 0, 0, 0);
        acc[nt] = __builtin_amdgcn_mfma_f32_16x16x32_f16(al, bf, acc[nt], 0, 0, 0);
      }
    }
    // write back own rows (C-layout: row=quad*4+r, col=nt*16+lc); per-wave
    // in-order LDS ops make read-before-write safe within the wave.
#pragma unroll
    for (int nt = 0; nt < 8; nt++) {
      int col = nt * 16 + lc;
      float bb = lbh[l * 128 + col];
#pragma unroll
      for (int r = 0; r < 4; r++) {
        int rrow = w * 16 + quad * 4 + r;
        float v = fmaxf(acc[nt][r] + bb, 0.f);
        f16 h = (f16)v;
        Hhi[rrow * HP + col] = h;
        Hlo[rrow * HP + col] = (f16)(v - (float)h);
      }
    }
  }
  __syncthreads();
  // final dot: o[rr][j] = lb4[j] + sum_k H[rr][k] * lw4[k*4+j]
  {
    int rr = tid >> 2, j = tid & 3;
    float o = lb4[j];
    for (int k = 0; k < 128; k++) {
      float hv = (float)Hhi[rr * HP + k] + (float)Hlo[rr * HP + k];
      o = fmaf(hv, lw4[k * 4 + j], o);
    }
    ob[rr][j] = o;
  }
  __syncthreads();
  if (tid < 128) {
    int tp = tid >> 2, j = tid & 3;
    const int perm[4] = {0, 2, 1, 3};  // t2 column permutation
    out[(size_t)(t0 + tp) * 4 + j] = 0.5f * (ob[2 * tp][j] + ob[2 * tp + 1][perm[j]]);
  }
}

// ---------------- host ----------------
extern "C" void kernel_launch(void* const* d_in, const int* in_sizes, int n_in,
                              void* d_out, int out_size, void* d_ws, size_t ws_size,
                              hipStream_t stream) {
  const float* x   = (const float*)d_in[0];
  const int*   ei  = (const int*)d_in[1];
  const float* ea  = (const float*)d_in[2];
  const int*   eit = (const int*)d_in[3];
  const float* W0  = (const float*)d_in[4];
  const float* b0  = (const float*)d_in[5];
  const float* W1  = (const float*)d_in[6];
  const float* b1  = (const float*)d_in[7];
  const float* W2  = (const float*)d_in[8];
  const float* b2  = (const float*)d_in[9];
  const float* W3  = (const float*)d_in[10];
  const float* b3  = (const float*)d_in[11];
  const float* ew1 = (const float*)d_in[12];
  const float* eb1 = (const float*)d_in[13];
  const float* ew2 = (const float*)d_in[14];
  const float* eb2 = (const float*)d_in[15];
  const float* ew3 = (const float*)d_in[16];
  const float* eb3 = (const float*)d_in[17];
  const float* lw0 = (const float*)d_in[18];
  const float* lb0 = (const float*)d_in[19];
  const float* lwh = (const float*)d_in[20];
  const float* lbh = (const float*)d_in[21];
  const float* lw4 = (const float*)d_in[22];
  const float* lb4 = (const float*)d_in[23];
  const int* row = ei;
  const int* col = ei + NE;
  float* out = (float*)d_out;

  char* ws = (char*)d_ws;
  size_t off = 0;
  auto alloc = [&](size_t bytes) -> char* {
    char* p = ws + off;
    off += (bytes + 255) & ~(size_t)255;
    return p;
  };
  f16*   xA     = (f16*)alloc((size_t)NN * 896 * 2);  // x1 -> x3 -> x4 (single plane)
  f16*   xB     = (f16*)alloc((size_t)NN * 896 * 2);  // hW1 -> xagg2 -> hW3
  float* x2f    = (float*)alloc((size_t)NN * 128 * 4);
  float* UV     = (float*)alloc((size_t)NN * 256 * 4);  // xagg overlays front
  float* csr_nrm= (float*)alloc((size_t)8 * NE * 4);
  float* dis    = (float*)alloc((size_t)8 * NN * 4);
  float* ewb    = (float*)alloc((size_t)NE * 4);
  int*   rowptr = (int*)alloc((size_t)(NN + 1) * 4);
  int*   cursor = (int*)alloc((size_t)NN * 4);
  int*   eid    = (int*)alloc((size_t)NE * 4);
  int*   csr_src= (int*)alloc((size_t)NE * 4);
  f16* w1t  = (f16*)alloc((size_t)128 * 896 * 2);
  f16* w2t  = (f16*)alloc((size_t)7 * 128 * 128 * 2);
  f16* w3t  = (f16*)alloc((size_t)7 * 128 * 896 * 2);
  f16* lw0t = (f16*)alloc((size_t)2 * 128 * 896 * 2);
  f16* lwht = (f16*)alloc((size_t)3 * 128 * 128 * 2);
  float* xagg = UV;  // [NN][56] fp32, dead before UV written
  (void)ws_size; (void)in_sizes; (void)n_in; (void)out_size;

  const int EB = (NE + 255) / 256;
  const int GX = (NN + 127) / 128;   // 157
  const int MC = (GX + 7) / 8;       // 20 row-tiles max per XCD

  // weight prep (independent)
  k_wprep<<<dim3(448, 1), 256, 0, stream>>>(W1, 128, 0, 896, w1t);
  k_wprep<<<dim3(64, 7), 256, 0, stream>>>(W2, 128, (size_t)128 * 128, 128, w2t);
  k_wprep<<<dim3(448, 7), 256, 0, stream>>>(W3, 128, (size_t)896 * 128, 896, w3t);
  // lw0 is [1792][128]: U = rows 0..895, V = rows 896..1791
  k_wprep<<<dim3(448, 2), 256, 0, stream>>>(lw0, 128, (size_t)896 * 128, 896, lw0t);
  k_wprep<<<dim3(64, 3), 256, 0, stream>>>(lwh, 128, (size_t)128 * 128, 128, lwht);

  // edge weight + CSR count (fused) -> scan (rowptr+cursor) -> fill -> degrees -> norms
  hipMemsetAsync(cursor, 0, (size_t)NN * 4, stream);
  k_edge_mlp<<<EB, 256, 0, stream>>>(ea, ew1, eb1, ew2, eb2, ew3, eb3, col, ewb, cursor);
  k_scan<<<1, 256, 0, stream>>>(cursor, rowptr);
  k_fill_csr<<<EB, 256, 0, stream>>>(col, cursor, eid);
  k_deg_csr<<<(NN + 7) / 8, 64, 0, stream>>>(rowptr, eid, ea, ewb, dis);
  k_csr_norms<<<EB, 256, 0, stream>>>(eid, row, col, ea, ewb, dis, csr_src, csr_nrm);

  // Layer 0 (aggregate-first): xagg [N,7,8] -> x1 fp16 (xA)
  k_agg_x<<<NN, 64, 0, stream>>>(x, csr_nrm, dis, rowptr, csr_src, xagg);
  k_gemm0<<<NN, 896, 0, stream>>>(xagg, W0, b0, xA);

  // Layer 1: x1 @ W1 -> hW1 fp16 (xB); agg1 (learned ew, bias+relu) -> x2f
  k_mgemm<1, false, false, false, false><<<dim3(GX, 1), 256, 0, stream>>>(
      xA, w1t, nullptr, nullptr, xB, 896, NN, 896, 1, GX);
  k_agg1<<<(NN + 3) / 4, 256, 0, stream>>>(xB, csr_nrm + (size_t)7 * NE,
                                           dis + (size_t)7 * NN, rowptr, csr_src, b1, x2f);

  // Layer 2 (aggregate-first): xagg2 = A_i * x2 (7 relations, fp16 into xB),
  // then x3 = relu(xagg2_i @ W2_i + b2_i) via GROUP_A GEMM -> xA fp16
  k_agg2<<<(NN + 3) / 4, 256, 0, stream>>>(x2f, csr_nrm, dis, rowptr, csr_src, xB);
  k_mgemm<1, true, true, true, false><<<dim3(GX, 7), 256, 0, stream>>>(
      xB, w2t, b2, nullptr, xA, 896, NN, 128, 7, GX);

  // Layer 3: x3 @ W3 (7 mats, K=896, XCD-swizzled) -> hW3 fp16 (xB);
  // agg7 -> x4 fp16 (xA)
  k_mgemm<1, false, false, false, true><<<dim3(8 * MC * 7), 256, 0, stream>>>(
      xA, w3t, nullptr, nullptr, xB, 896, NN, 896, 7, GX);
  k_agg7<<<NN, 448, 0, stream>>>(xB, csr_nrm, dis, rowptr, csr_src, b3, xA);

  // Link precompute: UV = x4 @ [lw0_top | lw0_bot]  (XCD-swizzled, NG=2)
  k_mgemm<0, false, false, false, true><<<dim3(8 * MC * 2), 256, 0, stream>>>(
      xA, lw0t, nullptr, UV, nullptr, 896, NN, 896, 2, GX);

  // Fused link MLP: gather + 3 layers + output dot, H resident in LDS
  k_link_fused<<<NT / 32, 256, 0, stream>>>(UV, eit, lb0, lwht, lbh, lw4, lb4, out);
}